// Round 15
// baseline (317.048 us; speedup 1.0000x reference)
//
#include <hip/hip_runtime.h>
#include <math.h>

#define PI_D 3.14159265358979323846
#define PI_F 3.14159265358979f

#define BATCH 128
#define NM1 19
#define NMP1 10
#define NM2 11
#define NMP2 6
#define NB_IN 60
#define NB1 20
#define NB2 12
#define NL1 10
#define NL2 6
#define F1C 20
#define F2C 40
#define NBC 10

#define GEMM_MH (BATCH*NMP2)  // 768
#define GEMM_N (F2C*NM2)      // 440
#define GEMM_K (F1C*NM2)      // 220
#define GM 64
#define GN 64
#define GK 20
#define ASTR 21

// twiddle table global layout (float2 offsets)
#define TW_SYNT 0       // [19][20]
#define TW_SYNA 380     // [20][10]
#define TW_ANAA 580     // [20][6]
#define TW_ANAG 700     // [20][12] col11=0
#define TW_S2   940     // [12][11]
#define TW_60   1072    // [60][10]
#define TW_TOT  1672

// constants counts
#define N_D1WC 40000    // [10l][20b][10mp][20]
#define N_D12WC 7920    // [6l][20b][6m2p][11]
#define N_WIGY 570      // [10l][3b][19m]
#define N_WIGD2 2178    // [6l][3b][121mn]
#define N_D2W  (NL2*NB2*NM2*NM2)   // 8712
#define N_WDS2C 6000    // [10l][60k][10mp]
#define N_W2N  (NB2)
#define N_CSMALL (N_WIGY+N_WIGD2+N_WDS2C+N_W2N)
#define N_CPREP (N_D1WC+N_D12WC+N_D2W)
#define PREP_BASE (BATCH + 1 + 120)
#define NBLK_CPREP ((N_CPREP + 255)/256)

// ---------------- fp32 Wigner-d helpers ----------------
__device__ __forceinline__ float ipow_f(float x, int e) {
  float r = 1.f;
  for (int i = 0; i < e; ++i) r *= x;
  return r;
}

__device__ float wigdf(const float* lf, int l, int m, int n, float beta) {
  if (m < -l || m > l || n < -l || n > l) return 0.f;
  float cb = cosf(0.5f*beta), sb = sinf(0.5f*beta);
  float pref = 0.5f*(lf[l+m]+lf[l-m]+lf[l+n]+lf[l-n]);
  int s0 = (n-m) > 0 ? (n-m) : 0;
  int s1 = (l+n) < (l-m) ? (l+n) : (l-m);
  float acc = 0.f;
  for (int s = s0; s <= s1; ++s) {
    float lc = pref - (lf[l+n-s]+lf[s]+lf[m-n+s]+lf[l-m-s]);
    float tt = expf(lc) * ipow_f(cb, 2*l+n-m-2*s) * ipow_f(sb, m-n+2*s);
    acc += ((m-n+s) & 1) ? -tt : tt;
  }
  return acc;
}

__device__ __forceinline__ float dh_beta_f(int b, int k) {
  return (float)(PI_D*(2*k+1)/(4.0*b));
}

__device__ float dh_w_f(int b, int k) {
  float beta = dh_beta_f(b, k), s = 0.f;
  for (int j = 0; j < b; ++j) s += sinf((2.f*(float)j+1.f)*beta)/(2.f*(float)j+1.f);
  return (2.f/(float)b)*sinf(beta)*s;
}

// ---------------- consts_small ----------------
__global__ __launch_bounds__(256) void k_consts1(float2* __restrict__ Tg,
                         float* __restrict__ wigY, float* __restrict__ wigD2,
                         float* __restrict__ wd_s2c, float* __restrict__ w2n) {
  __shared__ float lf[41];
  __shared__ float dhw30[60], dhw6[12];
  int t = threadIdx.x;
  if (t < 41) lf[t] = (float)lgamma((double)t + 1.0);
  else if (t < 101) dhw30[t-41] = dh_w_f(30, t-41);
  else if (t < 113) dhw6[t-101] = dh_w_f(6, t-101);
  __syncthreads();

  if (blockIdx.x == 0) {
    for (int i = t; i < TW_TOT; i += 256) {
      float2 v;
      if (i < TW_SYNA) {
        int j = i, n = j/NB1, g = j%NB1;
        int r = (g*(n-9)) % NB1; if (r < 0) r += NB1;
        float s, c; sincosf(2.f*PI_F*(float)r/(float)NB1, &s, &c);
        v = make_float2(c, s);
      } else if (i < TW_ANAA) {
        int j = i - TW_SYNA, a = j/NMP1, mp = j%NMP1;
        int r = (a*mp) % NB1;
        float s, c; sincosf(2.f*PI_F*(float)r/(float)NB1, &s, &c);
        v = make_float2(c, s);
      } else if (i < TW_ANAG) {
        int j = i - TW_ANAA, a = j/NMP2, m2p = j%NMP2;
        int r = (a*m2p) % NB1;
        float s, c; sincosf(2.f*PI_F*(float)r/(float)NB1, &s, &c);
        v = make_float2(c, -s);
      } else if (i < TW_S2) {
        int j = i - TW_ANAG, g = j/12, cI = j%12;
        if (cI == 11) v = make_float2(0.f, 0.f);
        else {
          int r = (g*(cI-5)) % NB1; if (r < 0) r += NB1;
          float s, c; sincosf(2.f*PI_F*(float)r/(float)NB1, &s, &c);
          v = make_float2(c, -s);
        }
      } else if (i < TW_60) {
        int j = i - TW_S2, k = j/NM2, mi = j%NM2;
        int r = (k*(mi-5)) % NB2; if (r < 0) r += NB2;
        float s, c; sincosf(2.f*PI_F*(float)r/(float)NB2, &s, &c);
        v = make_float2(c, s);
      } else {
        int j = i - TW_60, a = j/NMP1, mp = j%NMP1;
        int r = (a*mp) % NB_IN;
        float s, c; sincosf(2.f*PI_F*(float)r/(float)NB_IN, &s, &c);
        v = make_float2(c, -s);
      }
      Tg[i] = v;
    }
  }

  int gid = blockIdx.x*blockDim.x + t;

  if (gid < N_WIGY) {
    int l = gid/57; int r = gid%57; int bidx = r/19; int mi = r%19;
    float beta = (float)((double)(bidx + 1) * PI_D/24.0);
    wigY[gid] = wigdf(lf, l, mi-9, 0, beta);
    return;
  }
  gid -= N_WIGY;
  if (gid < N_WIGD2) {
    int l = gid/363; int r = gid%363; int bidx = r/121; int mn = r%121;
    int m = mn/NM2 - 5, n = mn%NM2 - 5;
    float beta = (float)((double)(bidx + 1) * PI_D/24.0);
    wigD2[gid] = wigdf(lf, l, m, n, beta);
    return;
  }
  gid -= N_WIGD2;
  if (gid < N_WDS2C) {
    int l = gid/600; int r = gid%600; int k = r/10; int mp = r%10;
    wd_s2c[gid] = dhw30[k] * wigdf(lf, l, mp, 0, dh_beta_f(30,k));
    return;
  }
  gid -= N_WDS2C;
  if (gid < N_W2N) {
    float s = 0.f;
    for (int j = 0; j < NB2; ++j) s += dhw6[j];
    w2n[gid] = dhw6[gid]/s;
    return;
  }
}

// ---------------- K_prep: s2fft + psi1 + psi2 + heavy consts ----------------
#define P2IO 40
#define P2GC 24
__global__ __launch_bounds__(256) void k_prep(const float* __restrict__ x,
                                              const float* __restrict__ wd_s2c,
                                              const float2* __restrict__ Tg,
                                              const float* __restrict__ wigY,
                                              const float* __restrict__ wigD2,
                                              const float* __restrict__ psi1,
                                              const float* __restrict__ psi2,
                                              float2* __restrict__ X,
                                              float2* __restrict__ Psi1p,
                                              float2* __restrict__ Bm,
                                              float* __restrict__ d1wc,
                                              float* __restrict__ d12wc,
                                              float* __restrict__ d2w) {
  __shared__ __align__(16) float smem[6912];
  const int bid = blockIdx.x, t = threadIdx.x;

  if (bid < BATCH) {
    const int z = bid;
    float*  xs   = smem;
    float2* xf   = (float2*)(smem + 3600);
    float2* tw60 = (float2*)(smem + 4800);
    for (int i = t; i < NB_IN*NMP1; i += 256) tw60[i] = Tg[TW_60 + i];
    for (int i = t; i < 3600; i += 256) xs[i] = x[z*3600 + i];
    __syncthreads();
    for (int i = t; i < NB_IN*NMP1; i += 256) {
      int k = i/NMP1, mp = i%NMP1;
      float re = 0.f, im = 0.f;
      const float* xrow = &xs[k*NB_IN];
      for (int a = 0; a < NB_IN; ++a) {
        float v = xrow[a];
        float2 e = tw60[a*NMP1 + mp];
        re = fmaf(v, e.x, re);
        im = fmaf(v, e.y, im);
      }
      xf[i] = make_float2(re, im);
    }
    __syncthreads();
    for (int i = t; i < NL1*NMP1; i += 256) {
      int l = i/NMP1, mp = i%NMP1;
      float re = 0.f, im = 0.f;
      for (int k = 0; k < NB_IN; ++k) {
        float w = wd_s2c[(l*NB_IN+k)*NMP1 + mp];
        float2 v = xf[k*NMP1 + mp];
        re = fmaf(w, v.x, re); im = fmaf(w, v.y, im);
      }
      X[(l*BATCH + z)*NMP1 + mp] = make_float2(re, im);
    }
    return;
  }

  if (bid == BATCH) {
    float*  wigYs = smem;
    float*  psis  = smem + 576;
    float2* ph8   = (float2*)(smem + 1056);
    for (int i = t; i < N_WIGY; i += 256) wigYs[i] = wigY[i];
    for (int i = t; i < F1C*24; i += 256) psis[i] = psi1[i];
    if (t < 8) {
      float s, c; sincosf(2.f*PI_F*(float)t/8.f, &s, &c);
      ph8[t] = make_float2(c, s);
    }
    __syncthreads();
    for (int i = t; i < NL1*F1C*NM1; i += 256) {
      int l = i/(F1C*NM1); int r = i%(F1C*NM1); int o = r/NM1; int mi = r%NM1;
      int m = mi - 9;
      float re = 0.f, im = 0.f;
      for (int g = 0; g < 24; ++g) {
        float w = psis[o*24 + g];
        float d = wigYs[(l*3 + (g >> 3))*NM1 + mi];
        int pa = g & 7;
        int rr = (-(m*pa)) % 8; if (rr < 0) rr += 8;
        float2 ph = ph8[rr];
        re = fmaf(w, d*ph.x, re); im = fmaf(w, d*ph.y, im);
      }
      Psi1p[i] = make_float2(re, im);
    }
    return;
  }

  if (bid < PREP_BASE) {
    const int j = bid - (BATCH + 1);
    const int io0 = (j/NL2)*P2IO, l = j%NL2;
    float2* Ds   = (float2*)smem;
    float*  Ws   = smem + 5856;
    float2* ph24 = (float2*)(smem + 6816);
    const int tio = t/31, tmn = t%31;
    const int mn0 = tmn*4;
    if (t < 24) {
      float s, c; sincosf(2.f*PI_F*(float)t/24.f, &s, &c);
      ph24[t] = make_float2(c, s);
    }
    __syncthreads();
    float2 acc[5][4];
    #pragma unroll
    for (int i = 0; i < 5; ++i)
      #pragma unroll
      for (int jj = 0; jj < 4; ++jj) acc[i][jj] = make_float2(0.f, 0.f);

    for (int gc = 0; gc < 144; gc += P2GC) {
      for (int i = t; i < P2GC*121; i += 256) {
        int g = i/121, mn = i%121;
        int p = gc + g;
        int m = mn/NM2 - 5, n = mn%NM2 - 5;
        float d = wigD2[(l*3 + p/48)*121 + mn];
        int pa = (p/6)%8, pg = p%6;
        int rr24 = (-(3*m*pa + 4*n*pg)) % 24; if (rr24 < 0) rr24 += 24;
        float2 ph = ph24[rr24];
        Ds[g*122 + mn] = make_float2(d*ph.x, d*ph.y);
      }
      for (int i = t; i < P2IO*P2GC; i += 256) {
        int io = i/P2GC, g = i%P2GC;
        Ws[i] = psi2[(io0 + io)*144 + gc + g];
      }
      __syncthreads();
      if (tio < 8) {
        for (int g = 0; g < P2GC; ++g) {
          float4 d01 = *(const float4*)&Ds[g*122 + mn0];
          float4 d23 = *(const float4*)&Ds[g*122 + mn0 + 2];
          float w0 = Ws[(tio*5 + 0)*P2GC + g];
          float w1 = Ws[(tio*5 + 1)*P2GC + g];
          float w2 = Ws[(tio*5 + 2)*P2GC + g];
          float w3 = Ws[(tio*5 + 3)*P2GC + g];
          float w4 = Ws[(tio*5 + 4)*P2GC + g];
          float dx[4] = {d01.x, d01.z, d23.x, d23.z};
          float dy[4] = {d01.y, d01.w, d23.y, d23.w};
          float wv[5] = {w0, w1, w2, w3, w4};
          #pragma unroll
          for (int i = 0; i < 5; ++i)
            #pragma unroll
            for (int jj = 0; jj < 4; ++jj) {
              acc[i][jj].x = fmaf(wv[i], dx[jj], acc[i][jj].x);
              acc[i][jj].y = fmaf(wv[i], dy[jj], acc[i][jj].y);
            }
        }
      }
      __syncthreads();
    }
    if (tio < 8) {
      #pragma unroll
      for (int i = 0; i < 5; ++i) {
        int io = io0 + tio*5 + i;
        int ii = io/F2C, oo = io%F2C;
        #pragma unroll
        for (int jj = 0; jj < 4; ++jj) {
          int mn = mn0 + jj;
          if (mn < 121) {
            int k = mn/NM2, n = mn%NM2;
            Bm[(size_t)l*GEMM_K*GEMM_N + (ii*NM2 + k)*GEMM_N + oo*NM2 + n] = acc[i][jj];
          }
        }
      }
    }
    return;
  }

  // heavy consts branch
  {
    float* lf     = smem;
    float* dhw10l = smem + 48;
    if (t < 41) lf[t] = (float)lgamma((double)t + 1.0);
    else if (t >= 64 && t < 84) dhw10l[t-64] = dh_w_f(10, t-64);
    __syncthreads();
    int idx = (bid - PREP_BASE)*256 + t;
    if (idx < N_D1WC) {
      int l = idx/4000; int r = idx%4000; int b = r/200; int r2 = r%200;
      int mp = r2/20, nn = r2%20;
      d1wc[idx] = (nn < NM1) ? (float)(2*l+1) * wigdf(lf, l, mp, nn-9, dh_beta_f(10,b)) : 0.f;
      return;
    }
    idx -= N_D1WC;
    if (idx < N_D12WC) {
      int l2 = idx/1320; int r = idx%1320; int b = r/66; int r2 = r%66;
      int m2p = r2/11, n2i = r2%11;
      d12wc[idx] = dhw10l[b] * wigdf(lf, l2, m2p, n2i-5, dh_beta_f(10,b));
      return;
    }
    idx -= N_D12WC;
    if (idx < N_D2W) {
      int l = idx/(NB2*NM2*NM2); int r = idx%(NB2*NM2*NM2); int j = r/(NM2*NM2); int rr = r%(NM2*NM2);
      int m = rr/NM2 - 5, n = rr%NM2 - 5;
      d2w[idx] = (float)(2*l+1) * wigdf(lf, l, m, n, dh_beta_f(6,j));
      return;
    }
  }
}

// ---------------- K4: fused stage 1, 512 threads, NBC=10 (2 chunks) ----------------
__global__ __launch_bounds__(512) void k_stage1(const float2* __restrict__ X,
                                                const float2* __restrict__ Psi1,
                                                const float* __restrict__ d1wc,
                                                const float* __restrict__ d12wc,
                                                const float2* __restrict__ Tg,
                                                float2* __restrict__ Am) {
  __shared__ __align__(16) float2 XPp[NL1*NMP1*20];   // 2000
  __shared__ __align__(16) float2 Etab[940];          // same layout as Tg[0..940)
  __shared__ __align__(16) float2 bufA[2000];         // setup: Ps[0..190),Xs[190..290); loop: Fh/yb
  __shared__ __align__(16) float2 bufB[2000];         // Tt [bb][mp][20] / Uu [bb][m2p][20]
  __shared__ float2 yfs[NBC*NMP2*NM2];                // 660
  __shared__ float2 Fxa[NL2*NMP2*NM2];                // 396

  const int z = blockIdx.x, o = blockIdx.y, t = threadIdx.x;
  const float2* EsynT = Etab;            // [n][20]
  const float2* EsynA = Etab + 380;      // [a][10]
  const float2* EanaA = Etab + 580;      // [a][6]
  const float2* EanaG = Etab + 700;      // [g][12]
  float2* Ps = bufA;
  float2* Xs = bufA + 190;

  for (int i = t; i < 940; i += 512) Etab[i] = Tg[i];
  for (int i = t; i < NL1*NMP1; i += 512) {
    int l = i/NMP1, mp = i%NMP1;
    Xs[i] = X[(l*BATCH + z)*NMP1 + mp];
  }
  for (int i = t; i < NL1*NM1; i += 512) {
    int l = i/NM1, mi = i%NM1;
    Ps[i] = Psi1[(l*F1C + o)*NM1 + mi];
  }
  for (int i = t; i < NL2*NMP2*NM2; i += 512) Fxa[i] = make_float2(0.f, 0.f);
  __syncthreads();

  for (int i = t; i < NL1*NMP1*20; i += 512) {
    int n = i % 20; int r = i/20; int mp = r % NMP1; int l = r/NMP1;
    float2 v = make_float2(0.f, 0.f);
    if (n < NM1) {
      float2 xa = Xs[l*NMP1+mp], pp = Ps[l*NM1+n];
      v = make_float2(xa.x*pp.x - xa.y*pp.y, xa.x*pp.y + xa.y*pp.x);
    }
    XPp[i] = v;
  }
  __syncthreads();

  float2* Fh = bufA;           // [bb][mp][19]  (1900)
  float2* Tt = bufB;           // [bb][mp][20]  (2000)
  float*  yb = (float*)bufA;   // [bb][a=20][20] floats (4000)
  float2* Uu = bufB;           // [bb][m2p][20] (1200)

  for (int c = 0; c < NB1/NBC; ++c) {
    const int b0 = c*NBC;
    // ph1: Fh[bb][mp][n0..n0+3] = sum_l XPp * d1wc   (500 items)
    if (t < 500) {
      int q = t % 5; int r = t/5; int mp = r % NMP1; int bb = r/NMP1;
      int n0 = q*4;
      const float* dw = &d1wc[((b0+bb)*NMP1 + mp)*20 + n0];
      const float2* xp = &XPp[mp*20 + n0];
      float2 a0 = {0.f,0.f}, a1 = {0.f,0.f}, a2 = {0.f,0.f}, a3 = {0.f,0.f};
      #pragma unroll
      for (int l = 0; l < NL1; ++l) {
        float4 w4 = *(const float4*)&dw[l*4000];
        float4 xa = *(const float4*)&xp[l*(NMP1*20)];
        float4 xb = *(const float4*)&xp[l*(NMP1*20) + 2];
        a0.x = fmaf(w4.x, xa.x, a0.x); a0.y = fmaf(w4.x, xa.y, a0.y);
        a1.x = fmaf(w4.y, xa.z, a1.x); a1.y = fmaf(w4.y, xa.w, a1.y);
        a2.x = fmaf(w4.z, xb.x, a2.x); a2.y = fmaf(w4.z, xb.y, a2.y);
        a3.x = fmaf(w4.w, xb.z, a3.x); a3.y = fmaf(w4.w, xb.w, a3.y);
      }
      float2* fr = &Fh[(bb*NMP1 + mp)*NM1 + n0];
      fr[0] = a0; fr[1] = a1; fr[2] = a2;
      if (n0 + 3 < NM1) fr[3] = a3;
    }
    __syncthreads();
    // ph2: Tt[bb][mp][g0..+3] = sum_n Fh*EsynT  (500 items)
    if (t < 500) {
      int gq = t % 5; int r = t / 5; int mp = r % NMP1; int bb = r / NMP1;
      int g0 = gq*4;
      const float2* fh = &Fh[(bb*NMP1 + mp)*NM1];
      float2 a0 = {0.f,0.f}, a1 = {0.f,0.f}, a2 = {0.f,0.f}, a3 = {0.f,0.f};
      #pragma unroll
      for (int n = 0; n < NM1; ++n) {
        float2 f = fh[n];
        float4 e01 = *(const float4*)&EsynT[n*NB1 + g0];
        float4 e23 = *(const float4*)&EsynT[n*NB1 + g0 + 2];
        a0.x += f.x*e01.x - f.y*e01.y; a0.y += f.x*e01.y + f.y*e01.x;
        a1.x += f.x*e01.z - f.y*e01.w; a1.y += f.x*e01.w + f.y*e01.z;
        a2.x += f.x*e23.x - f.y*e23.y; a2.y += f.x*e23.y + f.y*e23.x;
        a3.x += f.x*e23.z - f.y*e23.w; a3.y += f.x*e23.w + f.y*e23.z;
      }
      float2* tr = &Tt[(bb*NMP1 + mp)*NB1 + g0];
      tr[0] = a0; tr[1] = a1; tr[2] = a2; tr[3] = a3;
    }
    __syncthreads();
    // ph3: y[bb][a][g] = relu(Tt[0][g].x + 2*sum Re(EsynA*Tt))  (500 items, 2a x 4g)
    if (t < 500) {
      int gq = t % 5; int r = t / 5; int ap = r % 10; int bb = r / 10;
      int a0 = ap*2, g0 = gq*4;
      float4 t01 = *(const float4*)&Tt[(bb*NMP1)*NB1 + g0];
      float4 t23 = *(const float4*)&Tt[(bb*NMP1)*NB1 + g0 + 2];
      float s00=0.f,s01=0.f,s02=0.f,s03=0.f, s10=0.f,s11=0.f,s12=0.f,s13=0.f;
      #pragma unroll
      for (int mp = 1; mp < NMP1; ++mp) {
        float4 u01 = *(const float4*)&Tt[(bb*NMP1 + mp)*NB1 + g0];
        float4 u23 = *(const float4*)&Tt[(bb*NMP1 + mp)*NB1 + g0 + 2];
        float2 e0 = EsynA[a0*NMP1 + mp];
        float2 e1 = EsynA[(a0+1)*NMP1 + mp];
        s00 += e0.x*u01.x - e0.y*u01.y;
        s01 += e0.x*u01.z - e0.y*u01.w;
        s02 += e0.x*u23.x - e0.y*u23.y;
        s03 += e0.x*u23.z - e0.y*u23.w;
        s10 += e1.x*u01.x - e1.y*u01.y;
        s11 += e1.x*u01.z - e1.y*u01.w;
        s12 += e1.x*u23.x - e1.y*u23.y;
        s13 += e1.x*u23.z - e1.y*u23.w;
      }
      float* y0 = &yb[(bb*NB1 + a0)*NB1 + g0];
      float* y1 = &yb[(bb*NB1 + a0 + 1)*NB1 + g0];
      y0[0]=fmaxf(fmaf(2.f,s00,t01.x),0.f); y0[1]=fmaxf(fmaf(2.f,s01,t01.z),0.f);
      y0[2]=fmaxf(fmaf(2.f,s02,t23.x),0.f); y0[3]=fmaxf(fmaf(2.f,s03,t23.z),0.f);
      y1[0]=fmaxf(fmaf(2.f,s10,t01.x),0.f); y1[1]=fmaxf(fmaf(2.f,s11,t01.z),0.f);
      y1[2]=fmaxf(fmaf(2.f,s12,t23.x),0.f); y1[3]=fmaxf(fmaf(2.f,s13,t23.z),0.f);
    }
    __syncthreads();
    // ph4: U[bb][m2p][g0..+3] = sum_a y*EanaA  (300 items)
    if (t < 300) {
      int gq = t % 5; int r = t / 5; int m2p = r % NMP2; int bb = r / NMP2;
      int g0 = gq*4;
      float2 u0 = {0.f,0.f}, u1 = {0.f,0.f}, u2 = {0.f,0.f}, u3 = {0.f,0.f};
      #pragma unroll
      for (int aa = 0; aa < NB1; ++aa) {
        float4 y4 = *(const float4*)&yb[(bb*NB1 + aa)*NB1 + g0];
        float2 e = EanaA[aa*NMP2 + m2p];
        u0.x = fmaf(y4.x, e.x, u0.x); u0.y = fmaf(y4.x, e.y, u0.y);
        u1.x = fmaf(y4.y, e.x, u1.x); u1.y = fmaf(y4.y, e.y, u1.y);
        u2.x = fmaf(y4.z, e.x, u2.x); u2.y = fmaf(y4.z, e.y, u2.y);
        u3.x = fmaf(y4.w, e.x, u3.x); u3.y = fmaf(y4.w, e.y, u3.y);
      }
      float2* ur = &Uu[(bb*NMP2 + m2p)*NB1 + g0];
      ur[0] = u0; ur[1] = u1; ur[2] = u2; ur[3] = u3;
    }
    __syncthreads();
    // ph5: yf[bb][m2p][n0..n0+1] = sum_g U*EanaG  (360 items)
    if (t < 360) {
      int p = t % 6; int r = t / 6; int m2p = r % NMP2; int bb = r / NMP2;
      int n0 = p*2;
      const float2* ur = &Uu[(bb*NMP2 + m2p)*NB1];
      float2 acc0 = {0.f,0.f}, acc1 = {0.f,0.f};
      #pragma unroll
      for (int g = 0; g < NB1; ++g) {
        float2 u = ur[g];
        float4 e = *(const float4*)&EanaG[g*12 + n0];
        acc0.x += u.x*e.x - u.y*e.y; acc0.y += u.x*e.y + u.y*e.x;
        acc1.x += u.x*e.z - u.y*e.w; acc1.y += u.x*e.w + u.y*e.z;
      }
      yfs[(bb*NMP2 + m2p)*NM2 + n0] = acc0;
      if (n0 + 1 < NM2) yfs[(bb*NMP2 + m2p)*NM2 + n0 + 1] = acc1;
    }
    __syncthreads();
    // ph6: Fxa += sum_bb d12wc*yf  (396 items, bb loop 10)
    if (t < NL2*NMP2*NM2) {
      int l2 = t/(NMP2*NM2); int r = t%(NMP2*NM2);
      float2 acc = Fxa[t];
      #pragma unroll
      for (int bb = 0; bb < NBC; ++bb) {
        float w = d12wc[(l2*NB1 + b0 + bb)*66 + r];
        float2 v = yfs[bb*(NMP2*NM2) + r];
        acc.x = fmaf(w, v.x, acc.x); acc.y = fmaf(w, v.y, acc.y);
      }
      Fxa[t] = acc;
    }
    __syncthreads();
  }
  for (int i = t; i < NL2*NMP2*NM2; i += 512) {
    int l2 = i/(NMP2*NM2); int r = i%(NMP2*NM2);
    int mp = r/NM2, n = r%NM2;
    Am[(size_t)l2*GEMM_MH*GEMM_K + (z*NMP2 + mp)*GEMM_K + o*NM2 + n] = Fxa[i];
  }
}

// ---------------- K5: per-l complex GEMM, 4-way split-K ----------------
__global__ __launch_bounds__(256) void k_so3mm(const float2* __restrict__ A,
                                               const float2* __restrict__ B,
                                               float2* __restrict__ C0,
                                               float2* __restrict__ C1,
                                               float2* __restrict__ C2,
                                               float2* __restrict__ C3) {
  __shared__ float2 As[GM*ASTR];
  __shared__ float2 Bs[GK*GN];
  const int lz = blockIdx.z;
  const int l = lz >> 2, q = lz & 3;
  const int kbeg = q*60, klim = (q == 3) ? 220 : (kbeg + 60);
  const int row0 = blockIdx.x*GM, col0 = blockIdx.y*GN;
  const int t = threadIdx.x;
  const float2* Ag = A + (size_t)l*GEMM_MH*GEMM_K;
  const float2* Bg = B + (size_t)l*GEMM_K*GEMM_N;
  float2* Cg = (q == 0 ? C0 : (q == 1 ? C1 : (q == 2 ? C2 : C3))) + (size_t)l*GEMM_MH*GEMM_N;
  const int tn = t & 15, tm = t >> 4;
  float2 acc[4][4];
  #pragma unroll
  for (int i = 0; i < 4; ++i)
    #pragma unroll
    for (int j = 0; j < 4; ++j) acc[i][j] = make_float2(0.f, 0.f);

  for (int k0 = kbeg; k0 < klim; k0 += GK) {
    for (int i = t; i < GM*GK; i += 256) {
      int r = i/GK, kk = i%GK;
      As[r*ASTR + kk] = Ag[(size_t)(row0 + r)*GEMM_K + k0 + kk];
    }
    for (int i = t; i < GK*GN; i += 256) {
      int kk = i/GN, cc = i%GN;
      int col = col0 + cc;
      float2 v = (col < GEMM_N) ? Bg[(size_t)(k0 + kk)*GEMM_N + col] : make_float2(0.f, 0.f);
      Bs[(kk*4 + (cc & 3))*16 + (cc >> 2)] = v;
    }
    __syncthreads();
    #pragma unroll
    for (int kk = 0; kk < GK; ++kk) {
      float2 a[4], b[4];
      #pragma unroll
      for (int i = 0; i < 4; ++i) a[i] = As[(tm*4 + i)*ASTR + kk];
      #pragma unroll
      for (int j = 0; j < 4; ++j) b[j] = Bs[(kk*4 + j)*16 + tn];
      #pragma unroll
      for (int i = 0; i < 4; ++i)
        #pragma unroll
        for (int j = 0; j < 4; ++j) {
          acc[i][j].x = fmaf(a[i].x, b[j].x, acc[i][j].x);
          acc[i][j].x = fmaf(-a[i].y, b[j].y, acc[i][j].x);
          acc[i][j].y = fmaf(a[i].x, b[j].y, acc[i][j].y);
          acc[i][j].y = fmaf(a[i].y, b[j].x, acc[i][j].y);
        }
    }
    __syncthreads();
  }
  #pragma unroll
  for (int i = 0; i < 4; ++i) {
    int r = row0 + tm*4 + i;
    int c0 = col0 + tn*4;
    if (c0 < GEMM_N) {
      float4 v0 = make_float4(acc[i][0].x, acc[i][0].y, acc[i][1].x, acc[i][1].y);
      float4 v1 = make_float4(acc[i][2].x, acc[i][2].y, acc[i][3].x, acc[i][3].y);
      *(float4*)&Cg[(size_t)r*GEMM_N + c0] = v0;
      *(float4*)&Cg[(size_t)r*GEMM_N + c0 + 2] = v1;
    }
  }
}

// ---------------- K6: fused stage 2 tail (sums 4 split-K parts) ----------------
__global__ __launch_bounds__(256) void k_stage2(const float2* __restrict__ C0,
                                                const float2* __restrict__ C1,
                                                const float2* __restrict__ C2,
                                                const float2* __restrict__ C3,
                                                const float* __restrict__ d2w,
                                                const float* __restrict__ w2n,
                                                const float2* __restrict__ Tg,
                                                float* __restrict__ feat) {
  __shared__ float2 Fos[NL2*NM2*NM2];
  __shared__ float2 Fh2[NB2*NM2*NM2];
  __shared__ float2 T2[NB2*NB2*NM2];
  __shared__ float2 Esyn2[NB2*NM2];
  __shared__ float w2s[NB2];
  __shared__ float wred[4];
  const int z = blockIdx.x, o = blockIdx.y, t = threadIdx.x;
  for (int i = t; i < NB2*NM2; i += 256) Esyn2[i] = Tg[TW_S2 + i];
  if (t < NB2) w2s[t] = w2n[t];
  for (int i = t; i < NL2*NM2*NM2; i += 256) {
    int l = i/(NM2*NM2); int mn = i%(NM2*NM2);
    int m = mn/NM2, n = mn%NM2;
    size_t idx;
    float sgn = 1.f;
    bool mirror = (m < 5);
    if (!mirror) {
      idx = (size_t)l*GEMM_MH*GEMM_N + (size_t)(z*NMP2 + m - 5)*GEMM_N + o*NM2 + n;
    } else {
      idx = (size_t)l*GEMM_MH*GEMM_N + (size_t)(z*NMP2 + 5 - m)*GEMM_N + o*NM2 + (10 - n);
      sgn = ((m - n) & 1) ? -1.f : 1.f;
    }
    float2 a = C0[idx], b2 = C1[idx], c2 = C2[idx], d2 = C3[idx];
    float re = a.x + b2.x + c2.x + d2.x;
    float im = a.y + b2.y + c2.y + d2.y;
    Fos[i] = mirror ? make_float2(sgn*re, -sgn*im) : make_float2(re, im);
  }
  __syncthreads();
  for (int i = t; i < NB2*NM2*NM2; i += 256) {
    int b = i/(NM2*NM2); int mn = i%(NM2*NM2);
    float re = 0.f, im = 0.f;
    #pragma unroll
    for (int l = 0; l < NL2; ++l) {
      float w = d2w[(l*NB2 + b)*(NM2*NM2) + mn];
      float2 v = Fos[l*(NM2*NM2) + mn];
      re = fmaf(w, v.x, re); im = fmaf(w, v.y, im);
    }
    Fh2[i] = make_float2(re, im);
  }
  __syncthreads();
  for (int i = t; i < NB2*NB2*NM2; i += 256) {
    int ni = i % NM2; int r = i / NM2; int aa = r % NB2; int b = r / NB2;
    const float2* fh = &Fh2[b*(NM2*NM2) + ni];
    float re = 0.f, im = 0.f;
    #pragma unroll
    for (int mi = 0; mi < NM2; ++mi) {
      float2 f = fh[mi*NM2]; float2 e = Esyn2[aa*NM2+mi];
      re += e.x*f.x - e.y*f.y;
      im += e.x*f.y + e.y*f.x;
    }
    T2[i] = make_float2(re, im);
  }
  __syncthreads();
  float accT = 0.f;
  for (int i = t; i < NB2*NB2*NB2; i += 256) {
    int g = i % NB2; int r = i / NB2; int aa = r % NB2; int b = r / NB2;
    const float2* trow = &T2[(b*NB2 + aa)*NM2];
    float v = 0.f;
    #pragma unroll
    for (int ni = 0; ni < NM2; ++ni) {
      float2 tv = trow[ni]; float2 e = Esyn2[g*NM2+ni];
      v += e.x*tv.x - e.y*tv.y;
    }
    accT += w2s[b]*fmaxf(v, 0.f);
  }
  #pragma unroll
  for (int off = 32; off > 0; off >>= 1) accT += __shfl_down(accT, off);
  if ((t & 63) == 0) wred[t >> 6] = accT;
  __syncthreads();
  if (t == 0) feat[z*F2C + o] = (wred[0]+wred[1]+wred[2]+wred[3]) / (float)(NB2*NB2);
}

// ---------------- K7: linear head ----------------
__global__ void k_head(const float* __restrict__ feat, const float* __restrict__ w_lin,
                       const float* __restrict__ b_lin, float* __restrict__ out) {
  int idx = blockIdx.x*blockDim.x + threadIdx.x;
  if (idx >= BATCH*10) return;
  int z = idx/10, f = idx%10;
  float acc = b_lin[f];
  for (int o = 0; o < F2C; ++o) acc = fmaf(feat[z*F2C + o], w_lin[f*F2C + o], acc);
  out[idx] = acc;
}

extern "C" void kernel_launch(void* const* d_in, const int* in_sizes, int n_in,
                              void* d_out, int out_size, void* d_ws, size_t ws_size,
                              hipStream_t stream) {
  const float* x     = (const float*)d_in[0];
  const float* psi1  = (const float*)d_in[1];
  const float* psi2  = (const float*)d_in[2];
  const float* w_lin = (const float*)d_in[3];
  const float* b_lin = (const float*)d_in[4];
  float* out = (float*)d_out;
  float* ws  = (float*)d_ws;

  size_t off = 0;
  auto alloc = [&](size_t nfloats) { size_t o = off; off += (nfloats + 15) & ~(size_t)15; return o; };
  float2* Tglob = (float2*)(ws + alloc(2*TW_TOT));
  float*  d1wc  = ws + alloc(N_D1WC);
  float*  d12wc = ws + alloc(N_D12WC);
  float*  wigY  = ws + alloc(N_WIGY);
  float*  wigD2 = ws + alloc(N_WIGD2);
  float*  d2w   = ws + alloc(N_D2W);
  float*  wd_s2c= ws + alloc(N_WDS2C);
  float*  w2n   = ws + alloc(N_W2N);
  float2* X     = (float2*)(ws + alloc(2*(size_t)NL1*BATCH*NMP1));
  float2* Psi1p = (float2*)(ws + alloc(2*(size_t)NL1*F1C*NM1));
  float2* Bmat  = (float2*)(ws + alloc(2*(size_t)NL2*GEMM_K*GEMM_N));
  float2* Amat  = (float2*)(ws + alloc(2*(size_t)NL2*GEMM_MH*GEMM_K));
  float2* Cmat0 = (float2*)(ws + alloc(2*(size_t)NL2*GEMM_MH*GEMM_N));
  float2* Cmat1 = (float2*)(ws + alloc(2*(size_t)NL2*GEMM_MH*GEMM_N));
  float2* Cmat2 = (float2*)(ws + alloc(2*(size_t)NL2*GEMM_MH*GEMM_N));
  float2* Cmat3 = (float2*)(ws + alloc(2*(size_t)NL2*GEMM_MH*GEMM_N));
  float*  featp = ws + alloc((size_t)BATCH*F2C);
  if (ws_size < off*sizeof(float)) return;

  k_consts1<<<(N_CSMALL + 255)/256, 256, 0, stream>>>(Tglob, wigY, wigD2, wd_s2c, w2n);
  k_prep<<<PREP_BASE + NBLK_CPREP, 256, 0, stream>>>(x, wd_s2c, Tglob, wigY, wigD2,
                                                     psi1, psi2, X, Psi1p, Bmat,
                                                     d1wc, d12wc, d2w);
  k_stage1<<<dim3(BATCH, F1C), 512, 0, stream>>>(X, Psi1p, d1wc, d12wc, Tglob, Amat);
  k_so3mm<<<dim3(GEMM_MH/GM, (GEMM_N + GN - 1)/GN, 4*NL2), 256, 0, stream>>>(Amat, Bmat,
                                                                             Cmat0, Cmat1, Cmat2, Cmat3);
  k_stage2<<<dim3(BATCH, F2C), 256, 0, stream>>>(Cmat0, Cmat1, Cmat2, Cmat3,
                                                 d2w, w2n, Tglob, featp);
  k_head<<<(BATCH*10 + 255)/256, 256, 0, stream>>>(featp, w_lin, b_lin, out);
}

// Round 16
// 284.423 us; speedup vs baseline: 1.1147x; 1.1147x over previous
//
#include <hip/hip_runtime.h>
#include <math.h>

#define PI_D 3.14159265358979323846
#define PI_F 3.14159265358979f

#define BATCH 128
#define NM1 19
#define NMP1 10
#define NM2 11
#define NMP2 6
#define NB_IN 60
#define NB1 20
#define NB2 12
#define NL1 10
#define NL2 6
#define F1C 20
#define F2C 40
#define NBC 5

#define GEMM_MH (BATCH*NMP2)  // 768
#define GEMM_N (F2C*NM2)      // 440
#define GEMM_K (F1C*NM2)      // 220
#define GM 64
#define GN 64
#define GK 20
#define ASTR 21

// twiddle table global layout (float2 offsets)
#define TW_SYNT 0       // [19][20]
#define TW_SYNA 380     // [20][10]
#define TW_ANAA 580     // [20][6]
#define TW_ANAG 700     // [20][12] col11=0
#define TW_S2   940     // [12][11]
#define TW_60   1072    // [60][10]
#define TW_TOT  1672

#define TTS 22          // padded EsynT/Tt/Uu row stride (float2)

// constants counts
#define N_D1WC 40000    // [10l][20b][10mp][20]
#define N_D12WC 7920    // [6l][20b][6m2p][11]
#define N_WIGY 570      // [10l][3b][19m]
#define N_WIGD2 2178    // [6l][3b][121mn]
#define N_D2W  (NL2*NB2*NM2*NM2)   // 8712
#define N_WDS2C 6000    // [10l][60k][10mp]
#define N_W2N  (NB2)
#define N_CSMALL (N_WIGY+N_WIGD2+N_WDS2C+N_W2N)
#define N_CPREP (N_D1WC+N_D12WC+N_D2W)
#define PREP_BASE (BATCH + 1 + 120)
#define NBLK_CPREP ((N_CPREP + 255)/256)

// ---------------- fp32 Wigner-d helpers ----------------
__device__ __forceinline__ float ipow_f(float x, int e) {
  float r = 1.f;
  for (int i = 0; i < e; ++i) r *= x;
  return r;
}

__device__ float wigdf(const float* lf, int l, int m, int n, float beta) {
  if (m < -l || m > l || n < -l || n > l) return 0.f;
  float cb = cosf(0.5f*beta), sb = sinf(0.5f*beta);
  float pref = 0.5f*(lf[l+m]+lf[l-m]+lf[l+n]+lf[l-n]);
  int s0 = (n-m) > 0 ? (n-m) : 0;
  int s1 = (l+n) < (l-m) ? (l+n) : (l-m);
  float acc = 0.f;
  for (int s = s0; s <= s1; ++s) {
    float lc = pref - (lf[l+n-s]+lf[s]+lf[m-n+s]+lf[l-m-s]);
    float tt = expf(lc) * ipow_f(cb, 2*l+n-m-2*s) * ipow_f(sb, m-n+2*s);
    acc += ((m-n+s) & 1) ? -tt : tt;
  }
  return acc;
}

__device__ __forceinline__ float dh_beta_f(int b, int k) {
  return (float)(PI_D*(2*k+1)/(4.0*b));
}

__device__ float dh_w_f(int b, int k) {
  float beta = dh_beta_f(b, k), s = 0.f;
  for (int j = 0; j < b; ++j) s += sinf((2.f*(float)j+1.f)*beta)/(2.f*(float)j+1.f);
  return (2.f/(float)b)*sinf(beta)*s;
}

// ---------------- consts_small: twiddles + prep-prerequisite tables ----------------
__global__ __launch_bounds__(256) void k_consts1(float2* __restrict__ Tg,
                         float* __restrict__ wigY, float* __restrict__ wigD2,
                         float* __restrict__ wd_s2c, float* __restrict__ w2n) {
  __shared__ float lf[41];
  __shared__ float dhw30[60], dhw6[12];
  int t = threadIdx.x;
  if (t < 41) lf[t] = (float)lgamma((double)t + 1.0);
  else if (t < 101) dhw30[t-41] = dh_w_f(30, t-41);
  else if (t < 113) dhw6[t-101] = dh_w_f(6, t-101);
  __syncthreads();

  if (blockIdx.x == 0) {
    for (int i = t; i < TW_TOT; i += 256) {
      float2 v;
      if (i < TW_SYNA) {
        int j = i, n = j/NB1, g = j%NB1;
        int r = (g*(n-9)) % NB1; if (r < 0) r += NB1;
        float s, c; sincosf(2.f*PI_F*(float)r/(float)NB1, &s, &c);
        v = make_float2(c, s);
      } else if (i < TW_ANAA) {
        int j = i - TW_SYNA, a = j/NMP1, mp = j%NMP1;
        int r = (a*mp) % NB1;
        float s, c; sincosf(2.f*PI_F*(float)r/(float)NB1, &s, &c);
        v = make_float2(c, s);
      } else if (i < TW_ANAG) {
        int j = i - TW_ANAA, a = j/NMP2, m2p = j%NMP2;
        int r = (a*m2p) % NB1;
        float s, c; sincosf(2.f*PI_F*(float)r/(float)NB1, &s, &c);
        v = make_float2(c, -s);
      } else if (i < TW_S2) {
        int j = i - TW_ANAG, g = j/12, cI = j%12;
        if (cI == 11) v = make_float2(0.f, 0.f);
        else {
          int r = (g*(cI-5)) % NB1; if (r < 0) r += NB1;
          float s, c; sincosf(2.f*PI_F*(float)r/(float)NB1, &s, &c);
          v = make_float2(c, -s);
        }
      } else if (i < TW_60) {
        int j = i - TW_S2, k = j/NM2, mi = j%NM2;
        int r = (k*(mi-5)) % NB2; if (r < 0) r += NB2;
        float s, c; sincosf(2.f*PI_F*(float)r/(float)NB2, &s, &c);
        v = make_float2(c, s);
      } else {
        int j = i - TW_60, a = j/NMP1, mp = j%NMP1;
        int r = (a*mp) % NB_IN;
        float s, c; sincosf(2.f*PI_F*(float)r/(float)NB_IN, &s, &c);
        v = make_float2(c, -s);
      }
      Tg[i] = v;
    }
  }

  int gid = blockIdx.x*blockDim.x + t;

  if (gid < N_WIGY) {
    int l = gid/57; int r = gid%57; int bidx = r/19; int mi = r%19;
    float beta = (float)((double)(bidx + 1) * PI_D/24.0);
    wigY[gid] = wigdf(lf, l, mi-9, 0, beta);
    return;
  }
  gid -= N_WIGY;
  if (gid < N_WIGD2) {
    int l = gid/363; int r = gid%363; int bidx = r/121; int mn = r%121;
    int m = mn/NM2 - 5, n = mn%NM2 - 5;
    float beta = (float)((double)(bidx + 1) * PI_D/24.0);
    wigD2[gid] = wigdf(lf, l, m, n, beta);
    return;
  }
  gid -= N_WIGD2;
  if (gid < N_WDS2C) {
    int l = gid/600; int r = gid%600; int k = r/10; int mp = r%10;
    wd_s2c[gid] = dhw30[k] * wigdf(lf, l, mp, 0, dh_beta_f(30,k));
    return;
  }
  gid -= N_WDS2C;
  if (gid < N_W2N) {
    float s = 0.f;
    for (int j = 0; j < NB2; ++j) s += dhw6[j];
    w2n[gid] = dhw6[gid]/s;
    return;
  }
}

// ---------------- K_prep: s2fft (0..127) + psi1 (128) + psi2 (129..248) + heavy consts (249..470) ----------------
#define P2IO 40
#define P2GC 24
__global__ __launch_bounds__(256) void k_prep(const float* __restrict__ x,
                                              const float* __restrict__ wd_s2c,
                                              const float2* __restrict__ Tg,
                                              const float* __restrict__ wigY,
                                              const float* __restrict__ wigD2,
                                              const float* __restrict__ psi1,
                                              const float* __restrict__ psi2,
                                              float2* __restrict__ X,
                                              float2* __restrict__ Psi1p,
                                              float2* __restrict__ Bm,
                                              float* __restrict__ d1wc,
                                              float* __restrict__ d12wc,
                                              float* __restrict__ d2w) {
  __shared__ __align__(16) float smem[6912];
  const int bid = blockIdx.x, t = threadIdx.x;

  if (bid < BATCH) {
    // ---- s2fft for z = bid ----
    const int z = bid;
    float*  xs   = smem;                       // 3600
    float2* xf   = (float2*)(smem + 3600);     // 600 f2
    float2* tw60 = (float2*)(smem + 4800);     // 600 f2
    for (int i = t; i < NB_IN*NMP1; i += 256) tw60[i] = Tg[TW_60 + i];
    for (int i = t; i < 3600; i += 256) xs[i] = x[z*3600 + i];
    __syncthreads();
    for (int i = t; i < NB_IN*NMP1; i += 256) {
      int k = i/NMP1, mp = i%NMP1;
      float re = 0.f, im = 0.f;
      const float* xrow = &xs[k*NB_IN];
      for (int a = 0; a < NB_IN; ++a) {
        float v = xrow[a];
        float2 e = tw60[a*NMP1 + mp];
        re = fmaf(v, e.x, re);
        im = fmaf(v, e.y, im);
      }
      xf[i] = make_float2(re, im);
    }
    __syncthreads();
    for (int i = t; i < NL1*NMP1; i += 256) {
      int l = i/NMP1, mp = i%NMP1;
      float re = 0.f, im = 0.f;
      for (int k = 0; k < NB_IN; ++k) {
        float w = wd_s2c[(l*NB_IN+k)*NMP1 + mp];
        float2 v = xf[k*NMP1 + mp];
        re = fmaf(w, v.x, re); im = fmaf(w, v.y, im);
      }
      X[(l*BATCH + z)*NMP1 + mp] = make_float2(re, im);
    }
    return;
  }

  if (bid == BATCH) {
    // ---- psi1 ----
    float*  wigYs = smem;                      // 570
    float*  psis  = smem + 576;                // 480
    float2* ph8   = (float2*)(smem + 1056);
    for (int i = t; i < N_WIGY; i += 256) wigYs[i] = wigY[i];
    for (int i = t; i < F1C*24; i += 256) psis[i] = psi1[i];
    if (t < 8) {
      float s, c; sincosf(2.f*PI_F*(float)t/8.f, &s, &c);
      ph8[t] = make_float2(c, s);
    }
    __syncthreads();
    for (int i = t; i < NL1*F1C*NM1; i += 256) {
      int l = i/(F1C*NM1); int r = i%(F1C*NM1); int o = r/NM1; int mi = r%NM1;
      int m = mi - 9;
      float re = 0.f, im = 0.f;
      for (int g = 0; g < 24; ++g) {
        float w = psis[o*24 + g];
        float d = wigYs[(l*3 + (g >> 3))*NM1 + mi];
        int pa = g & 7;
        int rr = (-(m*pa)) % 8; if (rr < 0) rr += 8;
        float2 ph = ph8[rr];
        re = fmaf(w, d*ph.x, re); im = fmaf(w, d*ph.y, im);
      }
      Psi1p[i] = make_float2(re, im);
    }
    return;
  }

  if (bid < PREP_BASE) {
    // ---- psi2 (120 blocks) ----
    const int j = bid - (BATCH + 1);
    const int io0 = (j/NL2)*P2IO, l = j%NL2;
    float2* Ds   = (float2*)smem;              // 2928 f2
    float*  Ws   = smem + 5856;                // 960 f
    float2* ph24 = (float2*)(smem + 6816);     // 24 f2
    const int tio = t/31, tmn = t%31;
    const int mn0 = tmn*4;
    if (t < 24) {
      float s, c; sincosf(2.f*PI_F*(float)t/24.f, &s, &c);
      ph24[t] = make_float2(c, s);
    }
    __syncthreads();
    float2 acc[5][4];
    #pragma unroll
    for (int i = 0; i < 5; ++i)
      #pragma unroll
      for (int jj = 0; jj < 4; ++jj) acc[i][jj] = make_float2(0.f, 0.f);

    for (int gc = 0; gc < 144; gc += P2GC) {
      for (int i = t; i < P2GC*121; i += 256) {
        int g = i/121, mn = i%121;
        int p = gc + g;
        int m = mn/NM2 - 5, n = mn%NM2 - 5;
        float d = wigD2[(l*3 + p/48)*121 + mn];
        int pa = (p/6)%8, pg = p%6;
        int rr24 = (-(3*m*pa + 4*n*pg)) % 24; if (rr24 < 0) rr24 += 24;
        float2 ph = ph24[rr24];
        Ds[g*122 + mn] = make_float2(d*ph.x, d*ph.y);
      }
      for (int i = t; i < P2IO*P2GC; i += 256) {
        int io = i/P2GC, g = i%P2GC;
        Ws[i] = psi2[(io0 + io)*144 + gc + g];
      }
      __syncthreads();
      if (tio < 8) {
        for (int g = 0; g < P2GC; ++g) {
          float4 d01 = *(const float4*)&Ds[g*122 + mn0];
          float4 d23 = *(const float4*)&Ds[g*122 + mn0 + 2];
          float w0 = Ws[(tio*5 + 0)*P2GC + g];
          float w1 = Ws[(tio*5 + 1)*P2GC + g];
          float w2 = Ws[(tio*5 + 2)*P2GC + g];
          float w3 = Ws[(tio*5 + 3)*P2GC + g];
          float w4 = Ws[(tio*5 + 4)*P2GC + g];
          float dx[4] = {d01.x, d01.z, d23.x, d23.z};
          float dy[4] = {d01.y, d01.w, d23.y, d23.w};
          float wv[5] = {w0, w1, w2, w3, w4};
          #pragma unroll
          for (int i = 0; i < 5; ++i)
            #pragma unroll
            for (int jj = 0; jj < 4; ++jj) {
              acc[i][jj].x = fmaf(wv[i], dx[jj], acc[i][jj].x);
              acc[i][jj].y = fmaf(wv[i], dy[jj], acc[i][jj].y);
            }
        }
      }
      __syncthreads();
    }
    if (tio < 8) {
      #pragma unroll
      for (int i = 0; i < 5; ++i) {
        int io = io0 + tio*5 + i;
        int ii = io/F2C, oo = io%F2C;
        #pragma unroll
        for (int jj = 0; jj < 4; ++jj) {
          int mn = mn0 + jj;
          if (mn < 121) {
            int k = mn/NM2, n = mn%NM2;
            Bm[(size_t)l*GEMM_K*GEMM_N + (ii*NM2 + k)*GEMM_N + oo*NM2 + n] = acc[i][jj];
          }
        }
      }
    }
    return;
  }

  // ---- heavy consts branch (222 blocks): d1wc, d12wc, d2w ----
  {
    float* lf     = smem;        // 41
    float* dhw10l = smem + 48;   // 20
    if (t < 41) lf[t] = (float)lgamma((double)t + 1.0);
    else if (t >= 64 && t < 84) dhw10l[t-64] = dh_w_f(10, t-64);
    __syncthreads();
    int idx = (bid - PREP_BASE)*256 + t;
    if (idx < N_D1WC) {
      int l = idx/4000; int r = idx%4000; int b = r/200; int r2 = r%200;
      int mp = r2/20, nn = r2%20;
      d1wc[idx] = (nn < NM1) ? (float)(2*l+1) * wigdf(lf, l, mp, nn-9, dh_beta_f(10,b)) : 0.f;
      return;
    }
    idx -= N_D1WC;
    if (idx < N_D12WC) {
      int l2 = idx/1320; int r = idx%1320; int b = r/66; int r2 = r%66;
      int m2p = r2/11, n2i = r2%11;
      d12wc[idx] = dhw10l[b] * wigdf(lf, l2, m2p, n2i-5, dh_beta_f(10,b));
      return;
    }
    idx -= N_D12WC;
    if (idx < N_D2W) {
      int l = idx/(NB2*NM2*NM2); int r = idx%(NB2*NM2*NM2); int j = r/(NM2*NM2); int rr = r%(NM2*NM2);
      int m = rr/NM2 - 5, n = rr%NM2 - 5;
      d2w[idx] = (float)(2*l+1) * wigdf(lf, l, m, n, dh_beta_f(6,j));
      return;
    }
  }
}

// ---------------- K4: fused stage 1 (round-13/14 proven version) ----------------
__global__ __launch_bounds__(256) void k_stage1(const float2* __restrict__ X,
                                                const float2* __restrict__ Psi1,
                                                const float* __restrict__ d1wc,
                                                const float* __restrict__ d12wc,
                                                const float2* __restrict__ Tg,
                                                float2* __restrict__ Am) {
  __shared__ float2 Xs[NL1*NMP1];
  __shared__ float2 Ps[NL1*NM1];
  __shared__ __align__(16) float2 XPp[NL1*NMP1*20];
  __shared__ __align__(16) float2 Etab[978];
  __shared__ __align__(16) float2 bufA[NBC*200];
  __shared__ __align__(16) float2 bufB[NBC*220];
  __shared__ float2 yfs[NBC*NMP2*NM2];
  __shared__ float2 Fxa[NL2*NMP2*NM2];

  const int z = blockIdx.x, o = blockIdx.y, t = threadIdx.x;
  const float2* EsynTp = Etab;
  const float2* EsynA  = Etab + 418;
  const float2* EanaA  = Etab + 618;
  const float2* EanaG  = Etab + 738;

  for (int i = t; i < 978; i += 256) {
    float2 v;
    if (i < 418) {
      int n = i/TTS, g = i%TTS;
      v = (g < NB1) ? Tg[TW_SYNT + n*NB1 + g] : make_float2(0.f, 0.f);
    } else {
      v = Tg[TW_SYNA + (i - 418)];
    }
    Etab[i] = v;
  }
  for (int i = t; i < NL1*NMP1; i += 256) {
    int l = i/NMP1, mp = i%NMP1;
    Xs[i] = X[(l*BATCH + z)*NMP1 + mp];
  }
  for (int i = t; i < NL1*NM1; i += 256) {
    int l = i/NM1, mi = i%NM1;
    Ps[i] = Psi1[(l*F1C + o)*NM1 + mi];
  }
  for (int i = t; i < NL2*NMP2*NM2; i += 256) Fxa[i] = make_float2(0.f, 0.f);
  __syncthreads();

  for (int i = t; i < NL1*NMP1*20; i += 256) {
    int n = i % 20; int r = i/20; int mp = r % NMP1; int l = r/NMP1;
    float2 v = make_float2(0.f, 0.f);
    if (n < NM1) {
      float2 xa = Xs[l*NMP1+mp], pp = Ps[l*NM1+n];
      v = make_float2(xa.x*pp.x - xa.y*pp.y, xa.x*pp.y + xa.y*pp.x);
    }
    XPp[i] = v;
  }
  __syncthreads();

  float2* Fh = bufA;
  float2* Tt = bufB;
  float*  yb = (float*)bufA;
  float2* Uu = bufB;

  for (int c = 0; c < NB1/NBC; ++c) {
    const int b0 = c*NBC;
    for (int i = t; i < NBC*NMP1*5; i += 256) {
      int q = i % 5; int r = i/5; int mp = r % NMP1; int bb = r/NMP1;
      int n0 = q*4;
      const float* dw = &d1wc[((b0+bb)*NMP1 + mp)*20 + n0];
      const float2* xp = &XPp[mp*20 + n0];
      float2 a0 = {0.f,0.f}, a1 = {0.f,0.f}, a2 = {0.f,0.f}, a3 = {0.f,0.f};
      #pragma unroll
      for (int l = 0; l < NL1; ++l) {
        float4 w4 = *(const float4*)&dw[l*4000];
        float4 xa = *(const float4*)&xp[l*(NMP1*20)];
        float4 xb = *(const float4*)&xp[l*(NMP1*20) + 2];
        a0.x = fmaf(w4.x, xa.x, a0.x); a0.y = fmaf(w4.x, xa.y, a0.y);
        a1.x = fmaf(w4.y, xa.z, a1.x); a1.y = fmaf(w4.y, xa.w, a1.y);
        a2.x = fmaf(w4.z, xb.x, a2.x); a2.y = fmaf(w4.z, xb.y, a2.y);
        a3.x = fmaf(w4.w, xb.z, a3.x); a3.y = fmaf(w4.w, xb.w, a3.y);
      }
      float2* fr = &Fh[(bb*NMP1 + mp)*NM1 + n0];
      fr[0] = a0; fr[1] = a1; fr[2] = a2;
      if (n0 + 3 < NM1) fr[3] = a3;
    }
    __syncthreads();
    for (int i = t; i < NBC*NMP1*5; i += 256) {
      int gq = i % 5; int r = i / 5; int mp = r % NMP1; int bb = r / NMP1;
      int g0 = gq*4;
      const float2* fh = &Fh[(bb*NMP1 + mp)*NM1];
      float2 a0 = {0.f,0.f}, a1 = {0.f,0.f}, a2 = {0.f,0.f}, a3 = {0.f,0.f};
      #pragma unroll
      for (int n = 0; n < NM1; ++n) {
        float2 f = fh[n];
        float4 e01 = *(const float4*)&EsynTp[n*TTS + g0];
        float4 e23 = *(const float4*)&EsynTp[n*TTS + g0 + 2];
        a0.x += f.x*e01.x - f.y*e01.y; a0.y += f.x*e01.y + f.y*e01.x;
        a1.x += f.x*e01.z - f.y*e01.w; a1.y += f.x*e01.w + f.y*e01.z;
        a2.x += f.x*e23.x - f.y*e23.y; a2.y += f.x*e23.y + f.y*e23.x;
        a3.x += f.x*e23.z - f.y*e23.w; a3.y += f.x*e23.w + f.y*e23.z;
      }
      float2* tr = &Tt[(bb*NMP1 + mp)*TTS + g0];
      tr[0] = a0; tr[1] = a1; tr[2] = a2; tr[3] = a3;
    }
    __syncthreads();
    for (int i = t; i < NBC*10*5; i += 256) {
      int gq = i % 5; int r = i / 5; int ap = r % 10; int bb = r / 10;
      int a0 = ap*2, g0 = gq*4;
      float4 t01 = *(const float4*)&Tt[(bb*NMP1)*TTS + g0];
      float4 t23 = *(const float4*)&Tt[(bb*NMP1)*TTS + g0 + 2];
      float s00=0.f,s01=0.f,s02=0.f,s03=0.f, s10=0.f,s11=0.f,s12=0.f,s13=0.f;
      #pragma unroll
      for (int mp = 1; mp < NMP1; ++mp) {
        float4 u01 = *(const float4*)&Tt[(bb*NMP1 + mp)*TTS + g0];
        float4 u23 = *(const float4*)&Tt[(bb*NMP1 + mp)*TTS + g0 + 2];
        float2 e0 = EsynA[a0*NMP1 + mp];
        float2 e1 = EsynA[(a0+1)*NMP1 + mp];
        s00 += e0.x*u01.x - e0.y*u01.y;
        s01 += e0.x*u01.z - e0.y*u01.w;
        s02 += e0.x*u23.x - e0.y*u23.y;
        s03 += e0.x*u23.z - e0.y*u23.w;
        s10 += e1.x*u01.x - e1.y*u01.y;
        s11 += e1.x*u01.z - e1.y*u01.w;
        s12 += e1.x*u23.x - e1.y*u23.y;
        s13 += e1.x*u23.z - e1.y*u23.w;
      }
      float* y0 = &yb[(bb*NB1 + a0)*NB1 + g0];
      float* y1 = &yb[(bb*NB1 + a0 + 1)*NB1 + g0];
      y0[0]=fmaxf(fmaf(2.f,s00,t01.x),0.f); y0[1]=fmaxf(fmaf(2.f,s01,t01.z),0.f);
      y0[2]=fmaxf(fmaf(2.f,s02,t23.x),0.f); y0[3]=fmaxf(fmaf(2.f,s03,t23.z),0.f);
      y1[0]=fmaxf(fmaf(2.f,s10,t01.x),0.f); y1[1]=fmaxf(fmaf(2.f,s11,t01.z),0.f);
      y1[2]=fmaxf(fmaf(2.f,s12,t23.x),0.f); y1[3]=fmaxf(fmaf(2.f,s13,t23.z),0.f);
    }
    __syncthreads();
    for (int i = t; i < NBC*NMP2*5; i += 256) {
      int gq = i % 5; int r = i / 5; int m2p = r % NMP2; int bb = r / NMP2;
      int g0 = gq*4;
      float2 u0 = {0.f,0.f}, u1 = {0.f,0.f}, u2 = {0.f,0.f}, u3 = {0.f,0.f};
      #pragma unroll
      for (int aa = 0; aa < NB1; ++aa) {
        float4 y4 = *(const float4*)&yb[(bb*NB1 + aa)*NB1 + g0];
        float2 e = EanaA[aa*NMP2 + m2p];
        u0.x = fmaf(y4.x, e.x, u0.x); u0.y = fmaf(y4.x, e.y, u0.y);
        u1.x = fmaf(y4.y, e.x, u1.x); u1.y = fmaf(y4.y, e.y, u1.y);
        u2.x = fmaf(y4.z, e.x, u2.x); u2.y = fmaf(y4.z, e.y, u2.y);
        u3.x = fmaf(y4.w, e.x, u3.x); u3.y = fmaf(y4.w, e.y, u3.y);
      }
      float2* ur = &Uu[(bb*NMP2 + m2p)*TTS + g0];
      ur[0] = u0; ur[1] = u1; ur[2] = u2; ur[3] = u3;
    }
    __syncthreads();
    for (int i = t; i < NBC*NMP2*6; i += 256) {
      int p = i % 6; int r = i / 6; int m2p = r % NMP2; int bb = r / NMP2;
      int n0 = p*2;
      const float2* ur = &Uu[(bb*NMP2 + m2p)*TTS];
      float2 acc0 = {0.f,0.f}, acc1 = {0.f,0.f};
      #pragma unroll
      for (int g = 0; g < NB1; ++g) {
        float2 u = ur[g];
        float4 e = *(const float4*)&EanaG[g*12 + n0];
        acc0.x += u.x*e.x - u.y*e.y; acc0.y += u.x*e.y + u.y*e.x;
        acc1.x += u.x*e.z - u.y*e.w; acc1.y += u.x*e.w + u.y*e.z;
      }
      yfs[(bb*NMP2 + m2p)*NM2 + n0] = acc0;
      if (n0 + 1 < NM2) yfs[(bb*NMP2 + m2p)*NM2 + n0 + 1] = acc1;
    }
    __syncthreads();
    for (int i = t; i < NL2*NMP2*NM2; i += 256) {
      int l2 = i/(NMP2*NM2); int r = i%(NMP2*NM2);
      float2 acc = Fxa[i];
      #pragma unroll
      for (int bb = 0; bb < NBC; ++bb) {
        float w = d12wc[(l2*NB1 + b0 + bb)*66 + r];
        float2 v = yfs[bb*(NMP2*NM2) + r];
        acc.x = fmaf(w, v.x, acc.x); acc.y = fmaf(w, v.y, acc.y);
      }
      Fxa[i] = acc;
    }
    __syncthreads();
  }
  for (int i = t; i < NL2*NMP2*NM2; i += 256) {
    int l2 = i/(NMP2*NM2); int r = i%(NMP2*NM2);
    int mp = r/NM2, n = r%NM2;
    Am[(size_t)l2*GEMM_MH*GEMM_K + (z*NMP2 + mp)*GEMM_K + o*NM2 + n] = Fxa[i];
  }
}

// ---------------- K5: per-l complex GEMM, split-K (half 0: k<120, half 1: k>=120) ----------------
__global__ __launch_bounds__(256) void k_so3mm(const float2* __restrict__ A,
                                               const float2* __restrict__ B,
                                               float2* __restrict__ C0,
                                               float2* __restrict__ C1) {
  __shared__ float2 As[GM*ASTR];
  __shared__ float2 Bs[GK*GN];
  const int lz = blockIdx.z;
  const int l = lz >> 1, half = lz & 1;
  const int kbeg = half ? 120 : 0, klim = half ? 220 : 120;
  const int row0 = blockIdx.x*GM, col0 = blockIdx.y*GN;
  const int t = threadIdx.x;
  const float2* Ag = A + (size_t)l*GEMM_MH*GEMM_K;
  const float2* Bg = B + (size_t)l*GEMM_K*GEMM_N;
  float2* Cg = (half ? C1 : C0) + (size_t)l*GEMM_MH*GEMM_N;
  const int tn = t & 15, tm = t >> 4;
  float2 acc[4][4];
  #pragma unroll
  for (int i = 0; i < 4; ++i)
    #pragma unroll
    for (int j = 0; j < 4; ++j) acc[i][j] = make_float2(0.f, 0.f);

  for (int k0 = kbeg; k0 < klim; k0 += GK) {
    for (int i = t; i < GM*GK; i += 256) {
      int r = i/GK, kk = i%GK;
      As[r*ASTR + kk] = Ag[(size_t)(row0 + r)*GEMM_K + k0 + kk];
    }
    for (int i = t; i < GK*GN; i += 256) {
      int kk = i/GN, cc = i%GN;
      int col = col0 + cc;
      float2 v = (col < GEMM_N) ? Bg[(size_t)(k0 + kk)*GEMM_N + col] : make_float2(0.f, 0.f);
      Bs[(kk*4 + (cc & 3))*16 + (cc >> 2)] = v;
    }
    __syncthreads();
    #pragma unroll
    for (int kk = 0; kk < GK; ++kk) {
      float2 a[4], b[4];
      #pragma unroll
      for (int i = 0; i < 4; ++i) a[i] = As[(tm*4 + i)*ASTR + kk];
      #pragma unroll
      for (int j = 0; j < 4; ++j) b[j] = Bs[(kk*4 + j)*16 + tn];
      #pragma unroll
      for (int i = 0; i < 4; ++i)
        #pragma unroll
        for (int j = 0; j < 4; ++j) {
          acc[i][j].x = fmaf(a[i].x, b[j].x, acc[i][j].x);
          acc[i][j].x = fmaf(-a[i].y, b[j].y, acc[i][j].x);
          acc[i][j].y = fmaf(a[i].x, b[j].y, acc[i][j].y);
          acc[i][j].y = fmaf(a[i].y, b[j].x, acc[i][j].y);
        }
    }
    __syncthreads();
  }
  #pragma unroll
  for (int i = 0; i < 4; ++i) {
    int r = row0 + tm*4 + i;
    int c0 = col0 + tn*4;
    if (c0 < GEMM_N) {
      float4 v0 = make_float4(acc[i][0].x, acc[i][0].y, acc[i][1].x, acc[i][1].y);
      float4 v1 = make_float4(acc[i][2].x, acc[i][2].y, acc[i][3].x, acc[i][3].y);
      *(float4*)&Cg[(size_t)r*GEMM_N + c0] = v0;
      *(float4*)&Cg[(size_t)r*GEMM_N + c0 + 2] = v1;
    }
  }
}

// ---------------- K6: fused stage 2 tail (adds split-K halves) ----------------
__global__ __launch_bounds__(256) void k_stage2(const float2* __restrict__ C0,
                                                const float2* __restrict__ C1,
                                                const float* __restrict__ d2w,
                                                const float* __restrict__ w2n,
                                                const float2* __restrict__ Tg,
                                                float* __restrict__ feat) {
  __shared__ float2 Fos[NL2*NM2*NM2];
  __shared__ float2 Fh2[NB2*NM2*NM2];
  __shared__ float2 T2[NB2*NB2*NM2];
  __shared__ float2 Esyn2[NB2*NM2];
  __shared__ float w2s[NB2];
  __shared__ float wred[4];
  const int z = blockIdx.x, o = blockIdx.y, t = threadIdx.x;
  for (int i = t; i < NB2*NM2; i += 256) Esyn2[i] = Tg[TW_S2 + i];
  if (t < NB2) w2s[t] = w2n[t];
  for (int i = t; i < NL2*NM2*NM2; i += 256) {
    int l = i/(NM2*NM2); int mn = i%(NM2*NM2);
    int m = mn/NM2, n = mn%NM2;
    float2 v;
    if (m >= 5) {
      size_t idx = (size_t)l*GEMM_MH*GEMM_N + (size_t)(z*NMP2 + m - 5)*GEMM_N + o*NM2 + n;
      float2 a = C0[idx], b2 = C1[idx];
      v = make_float2(a.x + b2.x, a.y + b2.y);
    } else {
      size_t idx = (size_t)l*GEMM_MH*GEMM_N + (size_t)(z*NMP2 + 5 - m)*GEMM_N + o*NM2 + (10 - n);
      float2 a = C0[idx], b2 = C1[idx];
      float s = ((m - n) & 1) ? -1.f : 1.f;
      v = make_float2(s*(a.x + b2.x), -s*(a.y + b2.y));
    }
    Fos[i] = v;
  }
  __syncthreads();
  for (int i = t; i < NB2*NM2*NM2; i += 256) {
    int b = i/(NM2*NM2); int mn = i%(NM2*NM2);
    float re = 0.f, im = 0.f;
    #pragma unroll
    for (int l = 0; l < NL2; ++l) {
      float w = d2w[(l*NB2 + b)*(NM2*NM2) + mn];
      float2 v = Fos[l*(NM2*NM2) + mn];
      re = fmaf(w, v.x, re); im = fmaf(w, v.y, im);
    }
    Fh2[i] = make_float2(re, im);
  }
  __syncthreads();
  for (int i = t; i < NB2*NB2*NM2; i += 256) {
    int ni = i % NM2; int r = i / NM2; int aa = r % NB2; int b = r / NB2;
    const float2* fh = &Fh2[b*(NM2*NM2) + ni];
    float re = 0.f, im = 0.f;
    #pragma unroll
    for (int mi = 0; mi < NM2; ++mi) {
      float2 f = fh[mi*NM2]; float2 e = Esyn2[aa*NM2+mi];
      re += e.x*f.x - e.y*f.y;
      im += e.x*f.y + e.y*f.x;
    }
    T2[i] = make_float2(re, im);
  }
  __syncthreads();
  float accT = 0.f;
  for (int i = t; i < NB2*NB2*NB2; i += 256) {
    int g = i % NB2; int r = i / NB2; int aa = r % NB2; int b = r / NB2;
    const float2* trow = &T2[(b*NB2 + aa)*NM2];
    float v = 0.f;
    #pragma unroll
    for (int ni = 0; ni < NM2; ++ni) {
      float2 tv = trow[ni]; float2 e = Esyn2[g*NM2+ni];
      v += e.x*tv.x - e.y*tv.y;
    }
    accT += w2s[b]*fmaxf(v, 0.f);
  }
  #pragma unroll
  for (int off = 32; off > 0; off >>= 1) accT += __shfl_down(accT, off);
  if ((t & 63) == 0) wred[t >> 6] = accT;
  __syncthreads();
  if (t == 0) feat[z*F2C + o] = (wred[0]+wred[1]+wred[2]+wred[3]) / (float)(NB2*NB2);
}

// ---------------- K7: linear head ----------------
__global__ void k_head(const float* __restrict__ feat, const float* __restrict__ w_lin,
                       const float* __restrict__ b_lin, float* __restrict__ out) {
  int idx = blockIdx.x*blockDim.x + threadIdx.x;
  if (idx >= BATCH*10) return;
  int z = idx/10, f = idx%10;
  float acc = b_lin[f];
  for (int o = 0; o < F2C; ++o) acc = fmaf(feat[z*F2C + o], w_lin[f*F2C + o], acc);
  out[idx] = acc;
}

extern "C" void kernel_launch(void* const* d_in, const int* in_sizes, int n_in,
                              void* d_out, int out_size, void* d_ws, size_t ws_size,
                              hipStream_t stream) {
  const float* x     = (const float*)d_in[0];
  const float* psi1  = (const float*)d_in[1];
  const float* psi2  = (const float*)d_in[2];
  const float* w_lin = (const float*)d_in[3];
  const float* b_lin = (const float*)d_in[4];
  float* out = (float*)d_out;
  float* ws  = (float*)d_ws;

  size_t off = 0;
  auto alloc = [&](size_t nfloats) { size_t o = off; off += (nfloats + 15) & ~(size_t)15; return o; };
  float2* Tglob = (float2*)(ws + alloc(2*TW_TOT));
  float*  d1wc  = ws + alloc(N_D1WC);
  float*  d12wc = ws + alloc(N_D12WC);
  float*  wigY  = ws + alloc(N_WIGY);
  float*  wigD2 = ws + alloc(N_WIGD2);
  float*  d2w   = ws + alloc(N_D2W);
  float*  wd_s2c= ws + alloc(N_WDS2C);
  float*  w2n   = ws + alloc(N_W2N);
  float2* X     = (float2*)(ws + alloc(2*(size_t)NL1*BATCH*NMP1));
  float2* Psi1p = (float2*)(ws + alloc(2*(size_t)NL1*F1C*NM1));
  float2* Bmat  = (float2*)(ws + alloc(2*(size_t)NL2*GEMM_K*GEMM_N));
  float2* Amat  = (float2*)(ws + alloc(2*(size_t)NL2*GEMM_MH*GEMM_K));
  float2* Cmat0 = (float2*)(ws + alloc(2*(size_t)NL2*GEMM_MH*GEMM_N));
  float2* Cmat1 = (float2*)(ws + alloc(2*(size_t)NL2*GEMM_MH*GEMM_N));
  float*  featp = ws + alloc((size_t)BATCH*F2C);
  if (ws_size < off*sizeof(float)) return;

  k_consts1<<<(N_CSMALL + 255)/256, 256, 0, stream>>>(Tglob, wigY, wigD2, wd_s2c, w2n);
  k_prep<<<PREP_BASE + NBLK_CPREP, 256, 0, stream>>>(x, wd_s2c, Tglob, wigY, wigD2,
                                                     psi1, psi2, X, Psi1p, Bmat,
                                                     d1wc, d12wc, d2w);
  k_stage1<<<dim3(BATCH, F1C), 256, 0, stream>>>(X, Psi1p, d1wc, d12wc, Tglob, Amat);
  k_so3mm<<<dim3(GEMM_MH/GM, (GEMM_N + GN - 1)/GN, 2*NL2), 256, 0, stream>>>(Amat, Bmat, Cmat0, Cmat1);
  k_stage2<<<dim3(BATCH, F2C), 256, 0, stream>>>(Cmat0, Cmat1, d2w, w2n, Tglob, featp);
  k_head<<<(BATCH*10 + 255)/256, 256, 0, stream>>>(featp, w_lin, b_lin, out);
}

// Round 17
// 263.957 us; speedup vs baseline: 1.2011x; 1.0775x over previous
//
#include <hip/hip_runtime.h>
#include <math.h>

#define PI_D 3.14159265358979323846
#define PI_F 3.14159265358979f

#define BATCH 128
#define NM1 19
#define NMP1 10
#define NM2 11
#define NMP2 6
#define NB_IN 60
#define NB1 20
#define NB2 12
#define NL1 10
#define NL2 6
#define F1C 20
#define F2C 40
#define NBC 5

#define GEMM_MH (BATCH*NMP2)  // 768
#define GEMM_N (F2C*NM2)      // 440
#define GEMM_K (F1C*NM2)      // 220
#define GM 64
#define GN 64
#define GK 20
#define ASTR 21

// twiddle table global layout (float2 offsets)
#define TW_SYNT 0       // [19][20]
#define TW_SYNA 380     // [20][10]
#define TW_ANAA 580     // [20][6]
#define TW_ANAG 700     // [20][12] col11=0
#define TW_S2   940     // [12][11]
#define TW_60   1072    // [60][10]
#define TW_TOT  1672

#define TTS 22          // padded EsynT/Tt/Uu row stride (float2)

// constants counts
#define N_D1WC 40000    // [10l][20b][10mp][20]
#define N_D12WC 7920    // [6l][20b][6m2p][11]
#define N_WIGY 570      // [10l][3b][19m]
#define N_WIGD2 2178    // [6l][3b][121mn]
#define N_D2W  (NL2*NB2*NM2*NM2)   // 8712
#define N_WDS2C 6000    // [10l][60k][10mp]
#define N_W2N  (NB2)
#define N_CSMALL (N_WIGY+N_WIGD2+N_WDS2C+N_W2N)
#define N_CPREP (N_D1WC+N_D12WC+N_D2W)
#define PREP_BASE (BATCH + 1 + 120)
#define NBLK_CPREP ((N_CPREP + 255)/256)

// ---------------- fp32 Wigner-d helpers ----------------
__device__ __forceinline__ float ipow_f(float x, int e) {
  float r = 1.f;
  for (int i = 0; i < e; ++i) r *= x;
  return r;
}

__device__ float wigdf(const float* lf, int l, int m, int n, float beta) {
  if (m < -l || m > l || n < -l || n > l) return 0.f;
  float cb = cosf(0.5f*beta), sb = sinf(0.5f*beta);
  float pref = 0.5f*(lf[l+m]+lf[l-m]+lf[l+n]+lf[l-n]);
  int s0 = (n-m) > 0 ? (n-m) : 0;
  int s1 = (l+n) < (l-m) ? (l+n) : (l-m);
  float acc = 0.f;
  for (int s = s0; s <= s1; ++s) {
    float lc = pref - (lf[l+n-s]+lf[s]+lf[m-n+s]+lf[l-m-s]);
    float tt = expf(lc) * ipow_f(cb, 2*l+n-m-2*s) * ipow_f(sb, m-n+2*s);
    acc += ((m-n+s) & 1) ? -tt : tt;
  }
  return acc;
}

__device__ __forceinline__ float dh_beta_f(int b, int k) {
  return (float)(PI_D*(2*k+1)/(4.0*b));
}

__device__ float dh_w_f(int b, int k) {
  float beta = dh_beta_f(b, k), s = 0.f;
  for (int j = 0; j < b; ++j) s += sinf((2.f*(float)j+1.f)*beta)/(2.f*(float)j+1.f);
  return (2.f/(float)b)*sinf(beta)*s;
}

// ---------------- consts_small: twiddles + prep-prerequisite tables ----------------
__global__ __launch_bounds__(256) void k_consts1(float2* __restrict__ Tg,
                         float* __restrict__ wigY, float* __restrict__ wigD2,
                         float* __restrict__ wd_s2c, float* __restrict__ w2n) {
  __shared__ float lf[41];
  __shared__ float dhw30[60], dhw6[12];
  int t = threadIdx.x;
  if (t < 41) lf[t] = (float)lgamma((double)t + 1.0);
  else if (t < 101) dhw30[t-41] = dh_w_f(30, t-41);
  else if (t < 113) dhw6[t-101] = dh_w_f(6, t-101);
  __syncthreads();

  if (blockIdx.x == 0) {
    for (int i = t; i < TW_TOT; i += 256) {
      float2 v;
      if (i < TW_SYNA) {
        int j = i, n = j/NB1, g = j%NB1;
        int r = (g*(n-9)) % NB1; if (r < 0) r += NB1;
        float s, c; sincosf(2.f*PI_F*(float)r/(float)NB1, &s, &c);
        v = make_float2(c, s);
      } else if (i < TW_ANAA) {
        int j = i - TW_SYNA, a = j/NMP1, mp = j%NMP1;
        int r = (a*mp) % NB1;
        float s, c; sincosf(2.f*PI_F*(float)r/(float)NB1, &s, &c);
        v = make_float2(c, s);
      } else if (i < TW_ANAG) {
        int j = i - TW_ANAA, a = j/NMP2, m2p = j%NMP2;
        int r = (a*m2p) % NB1;
        float s, c; sincosf(2.f*PI_F*(float)r/(float)NB1, &s, &c);
        v = make_float2(c, -s);
      } else if (i < TW_S2) {
        int j = i - TW_ANAG, g = j/12, cI = j%12;
        if (cI == 11) v = make_float2(0.f, 0.f);
        else {
          int r = (g*(cI-5)) % NB1; if (r < 0) r += NB1;
          float s, c; sincosf(2.f*PI_F*(float)r/(float)NB1, &s, &c);
          v = make_float2(c, -s);
        }
      } else if (i < TW_60) {
        int j = i - TW_S2, k = j/NM2, mi = j%NM2;
        int r = (k*(mi-5)) % NB2; if (r < 0) r += NB2;
        float s, c; sincosf(2.f*PI_F*(float)r/(float)NB2, &s, &c);
        v = make_float2(c, s);
      } else {
        int j = i - TW_60, a = j/NMP1, mp = j%NMP1;
        int r = (a*mp) % NB_IN;
        float s, c; sincosf(2.f*PI_F*(float)r/(float)NB_IN, &s, &c);
        v = make_float2(c, -s);
      }
      Tg[i] = v;
    }
  }

  int gid = blockIdx.x*blockDim.x + t;

  if (gid < N_WIGY) {
    int l = gid/57; int r = gid%57; int bidx = r/19; int mi = r%19;
    float beta = (float)((double)(bidx + 1) * PI_D/24.0);
    wigY[gid] = wigdf(lf, l, mi-9, 0, beta);
    return;
  }
  gid -= N_WIGY;
  if (gid < N_WIGD2) {
    int l = gid/363; int r = gid%363; int bidx = r/121; int mn = r%121;
    int m = mn/NM2 - 5, n = mn%NM2 - 5;
    float beta = (float)((double)(bidx + 1) * PI_D/24.0);
    wigD2[gid] = wigdf(lf, l, m, n, beta);
    return;
  }
  gid -= N_WIGD2;
  if (gid < N_WDS2C) {
    int l = gid/600; int r = gid%600; int k = r/10; int mp = r%10;
    wd_s2c[gid] = dhw30[k] * wigdf(lf, l, mp, 0, dh_beta_f(30,k));
    return;
  }
  gid -= N_WDS2C;
  if (gid < N_W2N) {
    float s = 0.f;
    for (int j = 0; j < NB2; ++j) s += dhw6[j];
    w2n[gid] = dhw6[gid]/s;
    return;
  }
}

// ---------------- K_prep: s2fft (0..127) + psi1 (128) + psi2 (129..248) + heavy consts (249..470) ----------------
#define P2IO 40
#define P2GC 24
__global__ __launch_bounds__(256) void k_prep(const float* __restrict__ x,
                                              const float* __restrict__ wd_s2c,
                                              const float2* __restrict__ Tg,
                                              const float* __restrict__ wigY,
                                              const float* __restrict__ wigD2,
                                              const float* __restrict__ psi1,
                                              const float* __restrict__ psi2,
                                              float2* __restrict__ X,
                                              float2* __restrict__ Psi1p,
                                              float2* __restrict__ Bm,
                                              float* __restrict__ d1wc,
                                              float* __restrict__ d12wc,
                                              float* __restrict__ d2w) {
  __shared__ __align__(16) float smem[6912];
  const int bid = blockIdx.x, t = threadIdx.x;

  if (bid < BATCH) {
    // ---- s2fft for z = bid ----
    const int z = bid;
    float*  xs   = smem;                       // 3600
    float2* xf   = (float2*)(smem + 3600);     // 600 f2
    float2* tw60 = (float2*)(smem + 4800);     // 600 f2
    for (int i = t; i < NB_IN*NMP1; i += 256) tw60[i] = Tg[TW_60 + i];
    for (int i = t; i < 3600; i += 256) xs[i] = x[z*3600 + i];
    __syncthreads();
    for (int i = t; i < NB_IN*NMP1; i += 256) {
      int k = i/NMP1, mp = i%NMP1;
      float re = 0.f, im = 0.f;
      const float* xrow = &xs[k*NB_IN];
      for (int a = 0; a < NB_IN; ++a) {
        float v = xrow[a];
        float2 e = tw60[a*NMP1 + mp];
        re = fmaf(v, e.x, re);
        im = fmaf(v, e.y, im);
      }
      xf[i] = make_float2(re, im);
    }
    __syncthreads();
    for (int i = t; i < NL1*NMP1; i += 256) {
      int l = i/NMP1, mp = i%NMP1;
      float re = 0.f, im = 0.f;
      for (int k = 0; k < NB_IN; ++k) {
        float w = wd_s2c[(l*NB_IN+k)*NMP1 + mp];
        float2 v = xf[k*NMP1 + mp];
        re = fmaf(w, v.x, re); im = fmaf(w, v.y, im);
      }
      X[(l*BATCH + z)*NMP1 + mp] = make_float2(re, im);
    }
    return;
  }

  if (bid == BATCH) {
    // ---- psi1 ----
    float*  wigYs = smem;                      // 570
    float*  psis  = smem + 576;                // 480
    float2* ph8   = (float2*)(smem + 1056);
    for (int i = t; i < N_WIGY; i += 256) wigYs[i] = wigY[i];
    for (int i = t; i < F1C*24; i += 256) psis[i] = psi1[i];
    if (t < 8) {
      float s, c; sincosf(2.f*PI_F*(float)t/8.f, &s, &c);
      ph8[t] = make_float2(c, s);
    }
    __syncthreads();
    for (int i = t; i < NL1*F1C*NM1; i += 256) {
      int l = i/(F1C*NM1); int r = i%(F1C*NM1); int o = r/NM1; int mi = r%NM1;
      int m = mi - 9;
      float re = 0.f, im = 0.f;
      for (int g = 0; g < 24; ++g) {
        float w = psis[o*24 + g];
        float d = wigYs[(l*3 + (g >> 3))*NM1 + mi];
        int pa = g & 7;
        int rr = (-(m*pa)) % 8; if (rr < 0) rr += 8;
        float2 ph = ph8[rr];
        re = fmaf(w, d*ph.x, re); im = fmaf(w, d*ph.y, im);
      }
      Psi1p[i] = make_float2(re, im);
    }
    return;
  }

  if (bid < PREP_BASE) {
    // ---- psi2 (120 blocks) ----
    const int j = bid - (BATCH + 1);
    const int io0 = (j/NL2)*P2IO, l = j%NL2;
    float2* Ds   = (float2*)smem;              // 2928 f2
    float*  Ws   = smem + 5856;                // 960 f
    float2* ph24 = (float2*)(smem + 6816);     // 24 f2
    const int tio = t/31, tmn = t%31;
    const int mn0 = tmn*4;
    if (t < 24) {
      float s, c; sincosf(2.f*PI_F*(float)t/24.f, &s, &c);
      ph24[t] = make_float2(c, s);
    }
    __syncthreads();
    float2 acc[5][4];
    #pragma unroll
    for (int i = 0; i < 5; ++i)
      #pragma unroll
      for (int jj = 0; jj < 4; ++jj) acc[i][jj] = make_float2(0.f, 0.f);

    for (int gc = 0; gc < 144; gc += P2GC) {
      for (int i = t; i < P2GC*121; i += 256) {
        int g = i/121, mn = i%121;
        int p = gc + g;
        int m = mn/NM2 - 5, n = mn%NM2 - 5;
        float d = wigD2[(l*3 + p/48)*121 + mn];
        int pa = (p/6)%8, pg = p%6;
        int rr24 = (-(3*m*pa + 4*n*pg)) % 24; if (rr24 < 0) rr24 += 24;
        float2 ph = ph24[rr24];
        Ds[g*122 + mn] = make_float2(d*ph.x, d*ph.y);
      }
      for (int i = t; i < P2IO*P2GC; i += 256) {
        int io = i/P2GC, g = i%P2GC;
        Ws[i] = psi2[(io0 + io)*144 + gc + g];
      }
      __syncthreads();
      if (tio < 8) {
        for (int g = 0; g < P2GC; ++g) {
          float4 d01 = *(const float4*)&Ds[g*122 + mn0];
          float4 d23 = *(const float4*)&Ds[g*122 + mn0 + 2];
          float w0 = Ws[(tio*5 + 0)*P2GC + g];
          float w1 = Ws[(tio*5 + 1)*P2GC + g];
          float w2 = Ws[(tio*5 + 2)*P2GC + g];
          float w3 = Ws[(tio*5 + 3)*P2GC + g];
          float w4 = Ws[(tio*5 + 4)*P2GC + g];
          float dx[4] = {d01.x, d01.z, d23.x, d23.z};
          float dy[4] = {d01.y, d01.w, d23.y, d23.w};
          float wv[5] = {w0, w1, w2, w3, w4};
          #pragma unroll
          for (int i = 0; i < 5; ++i)
            #pragma unroll
            for (int jj = 0; jj < 4; ++jj) {
              acc[i][jj].x = fmaf(wv[i], dx[jj], acc[i][jj].x);
              acc[i][jj].y = fmaf(wv[i], dy[jj], acc[i][jj].y);
            }
        }
      }
      __syncthreads();
    }
    if (tio < 8) {
      #pragma unroll
      for (int i = 0; i < 5; ++i) {
        int io = io0 + tio*5 + i;
        int ii = io/F2C, oo = io%F2C;
        #pragma unroll
        for (int jj = 0; jj < 4; ++jj) {
          int mn = mn0 + jj;
          if (mn < 121) {
            int k = mn/NM2, n = mn%NM2;
            Bm[(size_t)l*GEMM_K*GEMM_N + (ii*NM2 + k)*GEMM_N + oo*NM2 + n] = acc[i][jj];
          }
        }
      }
    }
    return;
  }

  // ---- heavy consts branch (222 blocks): d1wc, d12wc, d2w ----
  {
    float* lf     = smem;        // 41
    float* dhw10l = smem + 48;   // 20
    if (t < 41) lf[t] = (float)lgamma((double)t + 1.0);
    else if (t >= 64 && t < 84) dhw10l[t-64] = dh_w_f(10, t-64);
    __syncthreads();
    int idx = (bid - PREP_BASE)*256 + t;
    if (idx < N_D1WC) {
      int l = idx/4000; int r = idx%4000; int b = r/200; int r2 = r%200;
      int mp = r2/20, nn = r2%20;
      d1wc[idx] = (nn < NM1) ? (float)(2*l+1) * wigdf(lf, l, mp, nn-9, dh_beta_f(10,b)) : 0.f;
      return;
    }
    idx -= N_D1WC;
    if (idx < N_D12WC) {
      int l2 = idx/1320; int r = idx%1320; int b = r/66; int r2 = r%66;
      int m2p = r2/11, n2i = r2%11;
      d12wc[idx] = dhw10l[b] * wigdf(lf, l2, m2p, n2i-5, dh_beta_f(10,b));
      return;
    }
    idx -= N_D12WC;
    if (idx < N_D2W) {
      int l = idx/(NB2*NM2*NM2); int r = idx%(NB2*NM2*NM2); int j = r/(NM2*NM2); int rr = r%(NM2*NM2);
      int m = rr/NM2 - 5, n = rr%NM2 - 5;
      d2w[idx] = (float)(2*l+1) * wigdf(lf, l, m, n, dh_beta_f(6,j));
      return;
    }
  }
}

// ---------------- K4: fused stage 1 (radix-2 folded ph2/ph3) ----------------
__global__ __launch_bounds__(256) void k_stage1(const float2* __restrict__ X,
                                                const float2* __restrict__ Psi1,
                                                const float* __restrict__ d1wc,
                                                const float* __restrict__ d12wc,
                                                const float2* __restrict__ Tg,
                                                float2* __restrict__ Am) {
  __shared__ float2 Xs[NL1*NMP1];
  __shared__ float2 Ps[NL1*NM1];
  __shared__ __align__(16) float2 XPp[NL1*NMP1*20];
  __shared__ __align__(16) float2 Etab[978];
  __shared__ __align__(16) float2 bufA[NBC*200];
  __shared__ __align__(16) float2 bufB[NBC*220];
  __shared__ float2 yfs[NBC*NMP2*NM2];
  __shared__ float2 Fxa[NL2*NMP2*NM2];

  const int z = blockIdx.x, o = blockIdx.y, t = threadIdx.x;
  const float2* EsynTp = Etab;
  const float2* EsynA  = Etab + 418;
  const float2* EanaA  = Etab + 618;
  const float2* EanaG  = Etab + 738;

  for (int i = t; i < 978; i += 256) {
    float2 v;
    if (i < 418) {
      int n = i/TTS, g = i%TTS;
      v = (g < NB1) ? Tg[TW_SYNT + n*NB1 + g] : make_float2(0.f, 0.f);
    } else {
      v = Tg[TW_SYNA + (i - 418)];
    }
    Etab[i] = v;
  }
  for (int i = t; i < NL1*NMP1; i += 256) {
    int l = i/NMP1, mp = i%NMP1;
    Xs[i] = X[(l*BATCH + z)*NMP1 + mp];
  }
  for (int i = t; i < NL1*NM1; i += 256) {
    int l = i/NM1, mi = i%NM1;
    Ps[i] = Psi1[(l*F1C + o)*NM1 + mi];
  }
  for (int i = t; i < NL2*NMP2*NM2; i += 256) Fxa[i] = make_float2(0.f, 0.f);
  __syncthreads();

  for (int i = t; i < NL1*NMP1*20; i += 256) {
    int n = i % 20; int r = i/20; int mp = r % NMP1; int l = r/NMP1;
    float2 v = make_float2(0.f, 0.f);
    if (n < NM1) {
      float2 xa = Xs[l*NMP1+mp], pp = Ps[l*NM1+n];
      v = make_float2(xa.x*pp.x - xa.y*pp.y, xa.x*pp.y + xa.y*pp.x);
    }
    XPp[i] = v;
  }
  __syncthreads();

  float2* Fh = bufA;
  float2* Tt = bufB;
  float*  yb = (float*)bufA;
  float2* Uu = bufB;

  for (int c = 0; c < NB1/NBC; ++c) {
    const int b0 = c*NBC;
    // ph1: Fh[bb][mp][n0..n0+3] = sum_l XPp * d1wc
    for (int i = t; i < NBC*NMP1*5; i += 256) {
      int q = i % 5; int r = i/5; int mp = r % NMP1; int bb = r/NMP1;
      int n0 = q*4;
      const float* dw = &d1wc[((b0+bb)*NMP1 + mp)*20 + n0];
      const float2* xp = &XPp[mp*20 + n0];
      float2 a0 = {0.f,0.f}, a1 = {0.f,0.f}, a2 = {0.f,0.f}, a3 = {0.f,0.f};
      #pragma unroll
      for (int l = 0; l < NL1; ++l) {
        float4 w4 = *(const float4*)&dw[l*4000];
        float4 xa = *(const float4*)&xp[l*(NMP1*20)];
        float4 xb = *(const float4*)&xp[l*(NMP1*20) + 2];
        a0.x = fmaf(w4.x, xa.x, a0.x); a0.y = fmaf(w4.x, xa.y, a0.y);
        a1.x = fmaf(w4.y, xa.z, a1.x); a1.y = fmaf(w4.y, xa.w, a1.y);
        a2.x = fmaf(w4.z, xb.x, a2.x); a2.y = fmaf(w4.z, xb.y, a2.y);
        a3.x = fmaf(w4.w, xb.z, a3.x); a3.y = fmaf(w4.w, xb.w, a3.y);
      }
      float2* fr = &Fh[(bb*NMP1 + mp)*NM1 + n0];
      fr[0] = a0; fr[1] = a1; fr[2] = a2;
      if (n0 + 3 < NM1) fr[3] = a3;
    }
    __syncthreads();
    // ph2 (radix-2 fold): g0=2q; compute Tt[g0..g0+1] and Tt[g0+10..g0+11] from even/odd-n partials
    for (int i = t; i < NBC*NMP1*5; i += 256) {
      int q = i % 5; int r = i / 5; int mp = r % NMP1; int bb = r / NMP1;
      int g0 = q*2;
      const float2* fh = &Fh[(bb*NMP1 + mp)*NM1];
      float pe0x=0.f,pe0y=0.f,pe1x=0.f,pe1y=0.f;
      float po0x=0.f,po0y=0.f,po1x=0.f,po1y=0.f;
      #pragma unroll
      for (int n = 0; n < NM1; ++n) {
        float2 f = fh[n];
        float4 e = *(const float4*)&EsynTp[n*TTS + g0];
        float cr0 = f.x*e.x - f.y*e.y, ci0 = f.x*e.y + f.y*e.x;
        float cr1 = f.x*e.z - f.y*e.w, ci1 = f.x*e.w + f.y*e.z;
        if ((n & 1) == 0) { pe0x += cr0; pe0y += ci0; pe1x += cr1; pe1y += ci1; }
        else              { po0x += cr0; po0y += ci0; po1x += cr1; po1y += ci1; }
      }
      float2* tr = &Tt[(bb*NMP1 + mp)*TTS];
      *(float4*)&tr[g0]      = make_float4(pe0x+po0x, pe0y+po0y, pe1x+po1x, pe1y+po1y);
      *(float4*)&tr[g0+10]   = make_float4(po0x-pe0x, po0y-pe0y, po1x-pe1x, po1y-pe1y);
    }
    __syncthreads();
    // ph3 (radix-2 fold over a): y[a] and y[a+10] from even/odd-mp partials
    for (int i = t; i < NBC*10*5; i += 256) {
      int gq = i % 5; int r = i / 5; int a = r % 10; int bb = r / 10;
      int g0 = gq*4;
      float4 t01 = *(const float4*)&Tt[(bb*NMP1)*TTS + g0];
      float4 t23 = *(const float4*)&Tt[(bb*NMP1)*TTS + g0 + 2];
      float se0=0.f,se1=0.f,se2=0.f,se3=0.f, so0=0.f,so1=0.f,so2=0.f,so3=0.f;
      #pragma unroll
      for (int mp = 1; mp < NMP1; ++mp) {
        float4 u01 = *(const float4*)&Tt[(bb*NMP1 + mp)*TTS + g0];
        float4 u23 = *(const float4*)&Tt[(bb*NMP1 + mp)*TTS + g0 + 2];
        float2 e = EsynA[a*NMP1 + mp];
        float c0 = e.x*u01.x - e.y*u01.y;
        float c1 = e.x*u01.z - e.y*u01.w;
        float c2 = e.x*u23.x - e.y*u23.y;
        float c3 = e.x*u23.z - e.y*u23.w;
        if (mp & 1) { so0+=c0; so1+=c1; so2+=c2; so3+=c3; }
        else        { se0+=c0; se1+=c1; se2+=c2; se3+=c3; }
      }
      float* y0 = &yb[(bb*NB1 + a)*NB1 + g0];
      float* y1 = &yb[(bb*NB1 + a + 10)*NB1 + g0];
      y0[0]=fmaxf(fmaf(2.f, se0+so0, t01.x),0.f);
      y0[1]=fmaxf(fmaf(2.f, se1+so1, t01.z),0.f);
      y0[2]=fmaxf(fmaf(2.f, se2+so2, t23.x),0.f);
      y0[3]=fmaxf(fmaf(2.f, se3+so3, t23.z),0.f);
      y1[0]=fmaxf(fmaf(2.f, se0-so0, t01.x),0.f);
      y1[1]=fmaxf(fmaf(2.f, se1-so1, t01.z),0.f);
      y1[2]=fmaxf(fmaf(2.f, se2-so2, t23.x),0.f);
      y1[3]=fmaxf(fmaf(2.f, se3-so3, t23.z),0.f);
    }
    __syncthreads();
    // ph4: U[bb][m2p][g0..+3] = sum_a y*EanaA
    for (int i = t; i < NBC*NMP2*5; i += 256) {
      int gq = i % 5; int r = i / 5; int m2p = r % NMP2; int bb = r / NMP2;
      int g0 = gq*4;
      float2 u0 = {0.f,0.f}, u1 = {0.f,0.f}, u2 = {0.f,0.f}, u3 = {0.f,0.f};
      #pragma unroll
      for (int aa = 0; aa < NB1; ++aa) {
        float4 y4 = *(const float4*)&yb[(bb*NB1 + aa)*NB1 + g0];
        float2 e = EanaA[aa*NMP2 + m2p];
        u0.x = fmaf(y4.x, e.x, u0.x); u0.y = fmaf(y4.x, e.y, u0.y);
        u1.x = fmaf(y4.y, e.x, u1.x); u1.y = fmaf(y4.y, e.y, u1.y);
        u2.x = fmaf(y4.z, e.x, u2.x); u2.y = fmaf(y4.z, e.y, u2.y);
        u3.x = fmaf(y4.w, e.x, u3.x); u3.y = fmaf(y4.w, e.y, u3.y);
      }
      float2* ur = &Uu[(bb*NMP2 + m2p)*TTS + g0];
      ur[0] = u0; ur[1] = u1; ur[2] = u2; ur[3] = u3;
    }
    __syncthreads();
    // ph5: yf[bb][m2p][n0..n0+1] = sum_g U*EanaG
    for (int i = t; i < NBC*NMP2*6; i += 256) {
      int p = i % 6; int r = i / 6; int m2p = r % NMP2; int bb = r / NMP2;
      int n0 = p*2;
      const float2* ur = &Uu[(bb*NMP2 + m2p)*TTS];
      float2 acc0 = {0.f,0.f}, acc1 = {0.f,0.f};
      #pragma unroll
      for (int g = 0; g < NB1; ++g) {
        float2 u = ur[g];
        float4 e = *(const float4*)&EanaG[g*12 + n0];
        acc0.x += u.x*e.x - u.y*e.y; acc0.y += u.x*e.y + u.y*e.x;
        acc1.x += u.x*e.z - u.y*e.w; acc1.y += u.x*e.w + u.y*e.z;
      }
      yfs[(bb*NMP2 + m2p)*NM2 + n0] = acc0;
      if (n0 + 1 < NM2) yfs[(bb*NMP2 + m2p)*NM2 + n0 + 1] = acc1;
    }
    __syncthreads();
    // ph6: Fxa += sum_bb d12wc*yf
    for (int i = t; i < NL2*NMP2*NM2; i += 256) {
      int l2 = i/(NMP2*NM2); int r = i%(NMP2*NM2);
      float2 acc = Fxa[i];
      #pragma unroll
      for (int bb = 0; bb < NBC; ++bb) {
        float w = d12wc[(l2*NB1 + b0 + bb)*66 + r];
        float2 v = yfs[bb*(NMP2*NM2) + r];
        acc.x = fmaf(w, v.x, acc.x); acc.y = fmaf(w, v.y, acc.y);
      }
      Fxa[i] = acc;
    }
    __syncthreads();
  }
  for (int i = t; i < NL2*NMP2*NM2; i += 256) {
    int l2 = i/(NMP2*NM2); int r = i%(NMP2*NM2);
    int mp = r/NM2, n = r%NM2;
    Am[(size_t)l2*GEMM_MH*GEMM_K + (z*NMP2 + mp)*GEMM_K + o*NM2 + n] = Fxa[i];
  }
}

// ---------------- K5: per-l complex GEMM, split-K (half 0: k<120, half 1: k>=120) ----------------
__global__ __launch_bounds__(256) void k_so3mm(const float2* __restrict__ A,
                                               const float2* __restrict__ B,
                                               float2* __restrict__ C0,
                                               float2* __restrict__ C1) {
  __shared__ float2 As[GM*ASTR];
  __shared__ float2 Bs[GK*GN];
  const int lz = blockIdx.z;
  const int l = lz >> 1, half = lz & 1;
  const int kbeg = half ? 120 : 0, klim = half ? 220 : 120;
  const int row0 = blockIdx.x*GM, col0 = blockIdx.y*GN;
  const int t = threadIdx.x;
  const float2* Ag = A + (size_t)l*GEMM_MH*GEMM_K;
  const float2* Bg = B + (size_t)l*GEMM_K*GEMM_N;
  float2* Cg = (half ? C1 : C0) + (size_t)l*GEMM_MH*GEMM_N;
  const int tn = t & 15, tm = t >> 4;
  float2 acc[4][4];
  #pragma unroll
  for (int i = 0; i < 4; ++i)
    #pragma unroll
    for (int j = 0; j < 4; ++j) acc[i][j] = make_float2(0.f, 0.f);

  for (int k0 = kbeg; k0 < klim; k0 += GK) {
    for (int i = t; i < GM*GK; i += 256) {
      int r = i/GK, kk = i%GK;
      As[r*ASTR + kk] = Ag[(size_t)(row0 + r)*GEMM_K + k0 + kk];
    }
    for (int i = t; i < GK*GN; i += 256) {
      int kk = i/GN, cc = i%GN;
      int col = col0 + cc;
      float2 v = (col < GEMM_N) ? Bg[(size_t)(k0 + kk)*GEMM_N + col] : make_float2(0.f, 0.f);
      Bs[(kk*4 + (cc & 3))*16 + (cc >> 2)] = v;
    }
    __syncthreads();
    #pragma unroll
    for (int kk = 0; kk < GK; ++kk) {
      float2 a[4], b[4];
      #pragma unroll
      for (int i = 0; i < 4; ++i) a[i] = As[(tm*4 + i)*ASTR + kk];
      #pragma unroll
      for (int j = 0; j < 4; ++j) b[j] = Bs[(kk*4 + j)*16 + tn];
      #pragma unroll
      for (int i = 0; i < 4; ++i)
        #pragma unroll
        for (int j = 0; j < 4; ++j) {
          acc[i][j].x = fmaf(a[i].x, b[j].x, acc[i][j].x);
          acc[i][j].x = fmaf(-a[i].y, b[j].y, acc[i][j].x);
          acc[i][j].y = fmaf(a[i].x, b[j].y, acc[i][j].y);
          acc[i][j].y = fmaf(a[i].y, b[j].x, acc[i][j].y);
        }
    }
    __syncthreads();
  }
  #pragma unroll
  for (int i = 0; i < 4; ++i) {
    int r = row0 + tm*4 + i;
    int c0 = col0 + tn*4;
    if (c0 < GEMM_N) {
      float4 v0 = make_float4(acc[i][0].x, acc[i][0].y, acc[i][1].x, acc[i][1].y);
      float4 v1 = make_float4(acc[i][2].x, acc[i][2].y, acc[i][3].x, acc[i][3].y);
      *(float4*)&Cg[(size_t)r*GEMM_N + c0] = v0;
      *(float4*)&Cg[(size_t)r*GEMM_N + c0 + 2] = v1;
    }
  }
}

// ---------------- K6: fused stage 2 tail (adds split-K halves) ----------------
__global__ __launch_bounds__(256) void k_stage2(const float2* __restrict__ C0,
                                                const float2* __restrict__ C1,
                                                const float* __restrict__ d2w,
                                                const float* __restrict__ w2n,
                                                const float2* __restrict__ Tg,
                                                float* __restrict__ feat) {
  __shared__ float2 Fos[NL2*NM2*NM2];
  __shared__ float2 Fh2[NB2*NM2*NM2];
  __shared__ float2 T2[NB2*NB2*NM2];
  __shared__ float2 Esyn2[NB2*NM2];
  __shared__ float w2s[NB2];
  __shared__ float wred[4];
  const int z = blockIdx.x, o = blockIdx.y, t = threadIdx.x;
  for (int i = t; i < NB2*NM2; i += 256) Esyn2[i] = Tg[TW_S2 + i];
  if (t < NB2) w2s[t] = w2n[t];
  for (int i = t; i < NL2*NM2*NM2; i += 256) {
    int l = i/(NM2*NM2); int mn = i%(NM2*NM2);
    int m = mn/NM2, n = mn%NM2;
    float2 v;
    if (m >= 5) {
      size_t idx = (size_t)l*GEMM_MH*GEMM_N + (size_t)(z*NMP2 + m - 5)*GEMM_N + o*NM2 + n;
      float2 a = C0[idx], b2 = C1[idx];
      v = make_float2(a.x + b2.x, a.y + b2.y);
    } else {
      size_t idx = (size_t)l*GEMM_MH*GEMM_N + (size_t)(z*NMP2 + 5 - m)*GEMM_N + o*NM2 + (10 - n);
      float2 a = C0[idx], b2 = C1[idx];
      float s = ((m - n) & 1) ? -1.f : 1.f;
      v = make_float2(s*(a.x + b2.x), -s*(a.y + b2.y));
    }
    Fos[i] = v;
  }
  __syncthreads();
  for (int i = t; i < NB2*NM2*NM2; i += 256) {
    int b = i/(NM2*NM2); int mn = i%(NM2*NM2);
    float re = 0.f, im = 0.f;
    #pragma unroll
    for (int l = 0; l < NL2; ++l) {
      float w = d2w[(l*NB2 + b)*(NM2*NM2) + mn];
      float2 v = Fos[l*(NM2*NM2) + mn];
      re = fmaf(w, v.x, re); im = fmaf(w, v.y, im);
    }
    Fh2[i] = make_float2(re, im);
  }
  __syncthreads();
  for (int i = t; i < NB2*NB2*NM2; i += 256) {
    int ni = i % NM2; int r = i / NM2; int aa = r % NB2; int b = r / NB2;
    const float2* fh = &Fh2[b*(NM2*NM2) + ni];
    float re = 0.f, im = 0.f;
    #pragma unroll
    for (int mi = 0; mi < NM2; ++mi) {
      float2 f = fh[mi*NM2]; float2 e = Esyn2[aa*NM2+mi];
      re += e.x*f.x - e.y*f.y;
      im += e.x*f.y + e.y*f.x;
    }
    T2[i] = make_float2(re, im);
  }
  __syncthreads();
  float accT = 0.f;
  for (int i = t; i < NB2*NB2*NB2; i += 256) {
    int g = i % NB2; int r = i / NB2; int aa = r % NB2; int b = r / NB2;
    const float2* trow = &T2[(b*NB2 + aa)*NM2];
    float v = 0.f;
    #pragma unroll
    for (int ni = 0; ni < NM2; ++ni) {
      float2 tv = trow[ni]; float2 e = Esyn2[g*NM2+ni];
      v += e.x*tv.x - e.y*tv.y;
    }
    accT += w2s[b]*fmaxf(v, 0.f);
  }
  #pragma unroll
  for (int off = 32; off > 0; off >>= 1) accT += __shfl_down(accT, off);
  if ((t & 63) == 0) wred[t >> 6] = accT;
  __syncthreads();
  if (t == 0) feat[z*F2C + o] = (wred[0]+wred[1]+wred[2]+wred[3]) / (float)(NB2*NB2);
}

// ---------------- K7: linear head ----------------
__global__ void k_head(const float* __restrict__ feat, const float* __restrict__ w_lin,
                       const float* __restrict__ b_lin, float* __restrict__ out) {
  int idx = blockIdx.x*blockDim.x + threadIdx.x;
  if (idx >= BATCH*10) return;
  int z = idx/10, f = idx%10;
  float acc = b_lin[f];
  for (int o = 0; o < F2C; ++o) acc = fmaf(feat[z*F2C + o], w_lin[f*F2C + o], acc);
  out[idx] = acc;
}

extern "C" void kernel_launch(void* const* d_in, const int* in_sizes, int n_in,
                              void* d_out, int out_size, void* d_ws, size_t ws_size,
                              hipStream_t stream) {
  const float* x     = (const float*)d_in[0];
  const float* psi1  = (const float*)d_in[1];
  const float* psi2  = (const float*)d_in[2];
  const float* w_lin = (const float*)d_in[3];
  const float* b_lin = (const float*)d_in[4];
  float* out = (float*)d_out;
  float* ws  = (float*)d_ws;

  size_t off = 0;
  auto alloc = [&](size_t nfloats) { size_t o = off; off += (nfloats + 15) & ~(size_t)15; return o; };
  float2* Tglob = (float2*)(ws + alloc(2*TW_TOT));
  float*  d1wc  = ws + alloc(N_D1WC);
  float*  d12wc = ws + alloc(N_D12WC);
  float*  wigY  = ws + alloc(N_WIGY);
  float*  wigD2 = ws + alloc(N_WIGD2);
  float*  d2w   = ws + alloc(N_D2W);
  float*  wd_s2c= ws + alloc(N_WDS2C);
  float*  w2n   = ws + alloc(N_W2N);
  float2* X     = (float2*)(ws + alloc(2*(size_t)NL1*BATCH*NMP1));
  float2* Psi1p = (float2*)(ws + alloc(2*(size_t)NL1*F1C*NM1));
  float2* Bmat  = (float2*)(ws + alloc(2*(size_t)NL2*GEMM_K*GEMM_N));
  float2* Amat  = (float2*)(ws + alloc(2*(size_t)NL2*GEMM_MH*GEMM_K));
  float2* Cmat0 = (float2*)(ws + alloc(2*(size_t)NL2*GEMM_MH*GEMM_N));
  float2* Cmat1 = (float2*)(ws + alloc(2*(size_t)NL2*GEMM_MH*GEMM_N));
  float*  featp = ws + alloc((size_t)BATCH*F2C);
  if (ws_size < off*sizeof(float)) return;

  k_consts1<<<(N_CSMALL + 255)/256, 256, 0, stream>>>(Tglob, wigY, wigD2, wd_s2c, w2n);
  k_prep<<<PREP_BASE + NBLK_CPREP, 256, 0, stream>>>(x, wd_s2c, Tglob, wigY, wigD2,
                                                     psi1, psi2, X, Psi1p, Bmat,
                                                     d1wc, d12wc, d2w);
  k_stage1<<<dim3(BATCH, F1C), 256, 0, stream>>>(X, Psi1p, d1wc, d12wc, Tglob, Amat);
  k_so3mm<<<dim3(GEMM_MH/GM, (GEMM_N + GN - 1)/GN, 2*NL2), 256, 0, stream>>>(Amat, Bmat, Cmat0, Cmat1);
  k_stage2<<<dim3(BATCH, F2C), 256, 0, stream>>>(Cmat0, Cmat1, d2w, w2n, Tglob, featp);
  k_head<<<(BATCH*10 + 255)/256, 256, 0, stream>>>(featp, w_lin, b_lin, out);
}

// Round 18
// 254.875 us; speedup vs baseline: 1.2439x; 1.0356x over previous
//
#include <hip/hip_runtime.h>
#include <math.h>

#define PI_D 3.14159265358979323846
#define PI_F 3.14159265358979f

#define BATCH 128
#define NM1 19
#define NMP1 10
#define NM2 11
#define NMP2 6
#define NB_IN 60
#define NB1 20
#define NB2 12
#define NL1 10
#define NL2 6
#define F1C 20
#define F2C 40
#define NBC 5

#define GEMM_MH (BATCH*NMP2)  // 768
#define GEMM_N (F2C*NM2)      // 440
#define GEMM_K (F1C*NM2)      // 220
#define GM 64
#define GN 64
#define GK 20
#define ASTR 21

// twiddle table global layout (float2 offsets)
#define TW_SYNT 0       // [19][20]
#define TW_SYNA 380     // [20][10]
#define TW_ANAA 580     // [20][6]
#define TW_ANAG 700     // [20][12] col11=0
#define TW_S2   940     // [12][11]
#define TW_60   1072    // [60][10]
#define TW_TOT  1672

#define TTS 22          // padded EsynT/Tt/Uu row stride (float2)

// constants counts
#define N_D1WC 40000    // [10l][20b][10mp][20]
#define N_D12WC 7920    // [6l][20b][6m2p][11]
#define N_WIGY 570      // [10l][3b][19m]
#define N_WIGD2 2178    // [6l][3b][121mn]
#define N_D2W  (NL2*NB2*NM2*NM2)   // 8712
#define N_WDS2C 6000    // [10l][60k][10mp]
#define N_W2N  (NB2)
#define N_CSMALL (N_WIGY+N_WIGD2+N_WDS2C+N_W2N)
#define N_CPREP (N_D1WC+N_D12WC+N_D2W)
#define PREP_BASE (BATCH + 1 + 120)
#define NBLK_CPREP ((N_CPREP + 255)/256)

// ---------------- fp32 Wigner-d helpers ----------------
__device__ __forceinline__ float ipow_f(float x, int e) {
  float r = 1.f;
  for (int i = 0; i < e; ++i) r *= x;
  return r;
}

__device__ float wigdf(const float* lf, int l, int m, int n, float beta) {
  if (m < -l || m > l || n < -l || n > l) return 0.f;
  float cb = cosf(0.5f*beta), sb = sinf(0.5f*beta);
  float pref = 0.5f*(lf[l+m]+lf[l-m]+lf[l+n]+lf[l-n]);
  int s0 = (n-m) > 0 ? (n-m) : 0;
  int s1 = (l+n) < (l-m) ? (l+n) : (l-m);
  float acc = 0.f;
  for (int s = s0; s <= s1; ++s) {
    float lc = pref - (lf[l+n-s]+lf[s]+lf[m-n+s]+lf[l-m-s]);
    float tt = expf(lc) * ipow_f(cb, 2*l+n-m-2*s) * ipow_f(sb, m-n+2*s);
    acc += ((m-n+s) & 1) ? -tt : tt;
  }
  return acc;
}

__device__ __forceinline__ float dh_beta_f(int b, int k) {
  return (float)(PI_D*(2*k+1)/(4.0*b));
}

__device__ float dh_w_f(int b, int k) {
  float beta = dh_beta_f(b, k), s = 0.f;
  for (int j = 0; j < b; ++j) s += sinf((2.f*(float)j+1.f)*beta)/(2.f*(float)j+1.f);
  return (2.f/(float)b)*sinf(beta)*s;
}

// ---------------- consts_small: twiddles + prep-prerequisite tables ----------------
__global__ __launch_bounds__(256) void k_consts1(float2* __restrict__ Tg,
                         float* __restrict__ wigY, float* __restrict__ wigD2,
                         float* __restrict__ wd_s2c, float* __restrict__ w2n) {
  __shared__ float lf[41];
  __shared__ float dhw30[60], dhw6[12];
  int t = threadIdx.x;
  if (t < 41) lf[t] = (float)lgamma((double)t + 1.0);
  else if (t < 101) dhw30[t-41] = dh_w_f(30, t-41);
  else if (t < 113) dhw6[t-101] = dh_w_f(6, t-101);
  __syncthreads();

  if (blockIdx.x == 0) {
    for (int i = t; i < TW_TOT; i += 256) {
      float2 v;
      if (i < TW_SYNA) {
        int j = i, n = j/NB1, g = j%NB1;
        int r = (g*(n-9)) % NB1; if (r < 0) r += NB1;
        float s, c; sincosf(2.f*PI_F*(float)r/(float)NB1, &s, &c);
        v = make_float2(c, s);
      } else if (i < TW_ANAA) {
        int j = i - TW_SYNA, a = j/NMP1, mp = j%NMP1;
        int r = (a*mp) % NB1;
        float s, c; sincosf(2.f*PI_F*(float)r/(float)NB1, &s, &c);
        v = make_float2(c, s);
      } else if (i < TW_ANAG) {
        int j = i - TW_ANAA, a = j/NMP2, m2p = j%NMP2;
        int r = (a*m2p) % NB1;
        float s, c; sincosf(2.f*PI_F*(float)r/(float)NB1, &s, &c);
        v = make_float2(c, -s);
      } else if (i < TW_S2) {
        int j = i - TW_ANAG, g = j/12, cI = j%12;
        if (cI == 11) v = make_float2(0.f, 0.f);
        else {
          int r = (g*(cI-5)) % NB1; if (r < 0) r += NB1;
          float s, c; sincosf(2.f*PI_F*(float)r/(float)NB1, &s, &c);
          v = make_float2(c, -s);
        }
      } else if (i < TW_60) {
        int j = i - TW_S2, k = j/NM2, mi = j%NM2;
        int r = (k*(mi-5)) % NB2; if (r < 0) r += NB2;
        float s, c; sincosf(2.f*PI_F*(float)r/(float)NB2, &s, &c);
        v = make_float2(c, s);
      } else {
        int j = i - TW_60, a = j/NMP1, mp = j%NMP1;
        int r = (a*mp) % NB_IN;
        float s, c; sincosf(2.f*PI_F*(float)r/(float)NB_IN, &s, &c);
        v = make_float2(c, -s);
      }
      Tg[i] = v;
    }
  }

  int gid = blockIdx.x*blockDim.x + t;

  if (gid < N_WIGY) {
    int l = gid/57; int r = gid%57; int bidx = r/19; int mi = r%19;
    float beta = (float)((double)(bidx + 1) * PI_D/24.0);
    wigY[gid] = wigdf(lf, l, mi-9, 0, beta);
    return;
  }
  gid -= N_WIGY;
  if (gid < N_WIGD2) {
    int l = gid/363; int r = gid%363; int bidx = r/121; int mn = r%121;
    int m = mn/NM2 - 5, n = mn%NM2 - 5;
    float beta = (float)((double)(bidx + 1) * PI_D/24.0);
    wigD2[gid] = wigdf(lf, l, m, n, beta);
    return;
  }
  gid -= N_WIGD2;
  if (gid < N_WDS2C) {
    int l = gid/600; int r = gid%600; int k = r/10; int mp = r%10;
    wd_s2c[gid] = dhw30[k] * wigdf(lf, l, mp, 0, dh_beta_f(30,k));
    return;
  }
  gid -= N_WDS2C;
  if (gid < N_W2N) {
    float s = 0.f;
    for (int j = 0; j < NB2; ++j) s += dhw6[j];
    w2n[gid] = dhw6[gid]/s;
    return;
  }
}

// ---------------- K_prep: s2fft (0..127) + psi1 (128) + psi2 (129..248) + heavy consts ----------------
#define P2IO 40
#define P2GC 24
__global__ __launch_bounds__(256) void k_prep(const float* __restrict__ x,
                                              const float* __restrict__ wd_s2c,
                                              const float2* __restrict__ Tg,
                                              const float* __restrict__ wigY,
                                              const float* __restrict__ wigD2,
                                              const float* __restrict__ psi1,
                                              const float* __restrict__ psi2,
                                              float2* __restrict__ X,
                                              float2* __restrict__ Psi1p,
                                              float2* __restrict__ Bm,
                                              float* __restrict__ d1wc,
                                              float* __restrict__ d12wc,
                                              float* __restrict__ d2w) {
  __shared__ __align__(16) float smem[6912];
  const int bid = blockIdx.x, t = threadIdx.x;

  if (bid < BATCH) {
    // ---- s2fft for z = bid (radix-2 folded over a) ----
    const int z = bid;
    float*  xs   = smem;                       // 3600
    float2* xf   = (float2*)(smem + 3600);     // 600 f2
    float2* tw60 = (float2*)(smem + 4800);     // 600 f2 (only a<30 rows used)
    for (int i = t; i < NB_IN*NMP1; i += 256) tw60[i] = Tg[TW_60 + i];
    for (int i = t; i < 3600; i += 256) xs[i] = x[z*3600 + i];
    __syncthreads();
    for (int i = t; i < NB_IN*NMP1; i += 256) {
      int k = i/NMP1, mp = i%NMP1;
      float sgn = (mp & 1) ? -1.f : 1.f;
      float re = 0.f, im = 0.f;
      const float* xrow = &xs[k*NB_IN];
      for (int a = 0; a < 30; ++a) {
        float v = fmaf(sgn, xrow[a+30], xrow[a]);
        float2 e = tw60[a*NMP1 + mp];
        re = fmaf(v, e.x, re);
        im = fmaf(v, e.y, im);
      }
      xf[i] = make_float2(re, im);
    }
    __syncthreads();
    for (int i = t; i < NL1*NMP1; i += 256) {
      int l = i/NMP1, mp = i%NMP1;
      float re = 0.f, im = 0.f;
      for (int k = 0; k < NB_IN; ++k) {
        float w = wd_s2c[(l*NB_IN+k)*NMP1 + mp];
        float2 v = xf[k*NMP1 + mp];
        re = fmaf(w, v.x, re); im = fmaf(w, v.y, im);
      }
      X[(l*BATCH + z)*NMP1 + mp] = make_float2(re, im);
    }
    return;
  }

  if (bid == BATCH) {
    // ---- psi1 ----
    float*  wigYs = smem;                      // 570
    float*  psis  = smem + 576;                // 480
    float2* ph8   = (float2*)(smem + 1056);
    for (int i = t; i < N_WIGY; i += 256) wigYs[i] = wigY[i];
    for (int i = t; i < F1C*24; i += 256) psis[i] = psi1[i];
    if (t < 8) {
      float s, c; sincosf(2.f*PI_F*(float)t/8.f, &s, &c);
      ph8[t] = make_float2(c, s);
    }
    __syncthreads();
    for (int i = t; i < NL1*F1C*NM1; i += 256) {
      int l = i/(F1C*NM1); int r = i%(F1C*NM1); int o = r/NM1; int mi = r%NM1;
      int m = mi - 9;
      float re = 0.f, im = 0.f;
      for (int g = 0; g < 24; ++g) {
        float w = psis[o*24 + g];
        float d = wigYs[(l*3 + (g >> 3))*NM1 + mi];
        int pa = g & 7;
        int rr = (-(m*pa)) % 8; if (rr < 0) rr += 8;
        float2 ph = ph8[rr];
        re = fmaf(w, d*ph.x, re); im = fmaf(w, d*ph.y, im);
      }
      Psi1p[i] = make_float2(re, im);
    }
    return;
  }

  if (bid < PREP_BASE) {
    // ---- psi2 (120 blocks) ----
    const int j = bid - (BATCH + 1);
    const int io0 = (j/NL2)*P2IO, l = j%NL2;
    float2* Ds   = (float2*)smem;              // 2928 f2
    float*  Ws   = smem + 5856;                // 960 f
    float2* ph24 = (float2*)(smem + 6816);     // 24 f2
    const int tio = t/31, tmn = t%31;
    const int mn0 = tmn*4;
    if (t < 24) {
      float s, c; sincosf(2.f*PI_F*(float)t/24.f, &s, &c);
      ph24[t] = make_float2(c, s);
    }
    __syncthreads();
    float2 acc[5][4];
    #pragma unroll
    for (int i = 0; i < 5; ++i)
      #pragma unroll
      for (int jj = 0; jj < 4; ++jj) acc[i][jj] = make_float2(0.f, 0.f);

    for (int gc = 0; gc < 144; gc += P2GC) {
      for (int i = t; i < P2GC*121; i += 256) {
        int g = i/121, mn = i%121;
        int p = gc + g;
        int m = mn/NM2 - 5, n = mn%NM2 - 5;
        float d = wigD2[(l*3 + p/48)*121 + mn];
        int pa = (p/6)%8, pg = p%6;
        int rr24 = (-(3*m*pa + 4*n*pg)) % 24; if (rr24 < 0) rr24 += 24;
        float2 ph = ph24[rr24];
        Ds[g*122 + mn] = make_float2(d*ph.x, d*ph.y);
      }
      for (int i = t; i < P2IO*P2GC; i += 256) {
        int io = i/P2GC, g = i%P2GC;
        Ws[i] = psi2[(io0 + io)*144 + gc + g];
      }
      __syncthreads();
      if (tio < 8) {
        for (int g = 0; g < P2GC; ++g) {
          float4 d01 = *(const float4*)&Ds[g*122 + mn0];
          float4 d23 = *(const float4*)&Ds[g*122 + mn0 + 2];
          float w0 = Ws[(tio*5 + 0)*P2GC + g];
          float w1 = Ws[(tio*5 + 1)*P2GC + g];
          float w2 = Ws[(tio*5 + 2)*P2GC + g];
          float w3 = Ws[(tio*5 + 3)*P2GC + g];
          float w4 = Ws[(tio*5 + 4)*P2GC + g];
          float dx[4] = {d01.x, d01.z, d23.x, d23.z};
          float dy[4] = {d01.y, d01.w, d23.y, d23.w};
          float wv[5] = {w0, w1, w2, w3, w4};
          #pragma unroll
          for (int i = 0; i < 5; ++i)
            #pragma unroll
            for (int jj = 0; jj < 4; ++jj) {
              acc[i][jj].x = fmaf(wv[i], dx[jj], acc[i][jj].x);
              acc[i][jj].y = fmaf(wv[i], dy[jj], acc[i][jj].y);
            }
        }
      }
      __syncthreads();
    }
    if (tio < 8) {
      #pragma unroll
      for (int i = 0; i < 5; ++i) {
        int io = io0 + tio*5 + i;
        int ii = io/F2C, oo = io%F2C;
        #pragma unroll
        for (int jj = 0; jj < 4; ++jj) {
          int mn = mn0 + jj;
          if (mn < 121) {
            int k = mn/NM2, n = mn%NM2;
            Bm[(size_t)l*GEMM_K*GEMM_N + (ii*NM2 + k)*GEMM_N + oo*NM2 + n] = acc[i][jj];
          }
        }
      }
    }
    return;
  }

  // ---- heavy consts branch (222 blocks): d1wc, d12wc, d2w ----
  {
    float* lf     = smem;        // 41
    float* dhw10l = smem + 48;   // 20
    if (t < 41) lf[t] = (float)lgamma((double)t + 1.0);
    else if (t >= 64 && t < 84) dhw10l[t-64] = dh_w_f(10, t-64);
    __syncthreads();
    int idx = (bid - PREP_BASE)*256 + t;
    if (idx < N_D1WC) {
      int l = idx/4000; int r = idx%4000; int b = r/200; int r2 = r%200;
      int mp = r2/20, nn = r2%20;
      d1wc[idx] = (nn < NM1) ? (float)(2*l+1) * wigdf(lf, l, mp, nn-9, dh_beta_f(10,b)) : 0.f;
      return;
    }
    idx -= N_D1WC;
    if (idx < N_D12WC) {
      int l2 = idx/1320; int r = idx%1320; int b = r/66; int r2 = r%66;
      int m2p = r2/11, n2i = r2%11;
      d12wc[idx] = dhw10l[b] * wigdf(lf, l2, m2p, n2i-5, dh_beta_f(10,b));
      return;
    }
    idx -= N_D12WC;
    if (idx < N_D2W) {
      int l = idx/(NB2*NM2*NM2); int r = idx%(NB2*NM2*NM2); int j = r/(NM2*NM2); int rr = r%(NM2*NM2);
      int m = rr/NM2 - 5, n = rr%NM2 - 5;
      d2w[idx] = (float)(2*l+1) * wigdf(lf, l, m, n, dh_beta_f(6,j));
      return;
    }
  }
}

// ---------------- K4: fused stage 1 (radix-2 folded ph2/ph3/ph4/ph5) ----------------
__global__ __launch_bounds__(256) void k_stage1(const float2* __restrict__ X,
                                                const float2* __restrict__ Psi1,
                                                const float* __restrict__ d1wc,
                                                const float* __restrict__ d12wc,
                                                const float2* __restrict__ Tg,
                                                float2* __restrict__ Am) {
  __shared__ float2 Xs[NL1*NMP1];
  __shared__ float2 Ps[NL1*NM1];
  __shared__ __align__(16) float2 XPp[NL1*NMP1*20];
  __shared__ __align__(16) float2 Etab[978];
  __shared__ __align__(16) float2 bufA[NBC*200];
  __shared__ __align__(16) float2 bufB[NBC*220];
  __shared__ float2 yfs[NBC*NMP2*NM2];
  __shared__ float2 Fxa[NL2*NMP2*NM2];

  const int z = blockIdx.x, o = blockIdx.y, t = threadIdx.x;
  const float2* EsynTp = Etab;
  const float2* EsynA  = Etab + 418;
  const float2* EanaA  = Etab + 618;
  const float2* EanaG  = Etab + 738;

  for (int i = t; i < 978; i += 256) {
    float2 v;
    if (i < 418) {
      int n = i/TTS, g = i%TTS;
      v = (g < NB1) ? Tg[TW_SYNT + n*NB1 + g] : make_float2(0.f, 0.f);
    } else {
      v = Tg[TW_SYNA + (i - 418)];
    }
    Etab[i] = v;
  }
  for (int i = t; i < NL1*NMP1; i += 256) {
    int l = i/NMP1, mp = i%NMP1;
    Xs[i] = X[(l*BATCH + z)*NMP1 + mp];
  }
  for (int i = t; i < NL1*NM1; i += 256) {
    int l = i/NM1, mi = i%NM1;
    Ps[i] = Psi1[(l*F1C + o)*NM1 + mi];
  }
  for (int i = t; i < NL2*NMP2*NM2; i += 256) Fxa[i] = make_float2(0.f, 0.f);
  __syncthreads();

  for (int i = t; i < NL1*NMP1*20; i += 256) {
    int n = i % 20; int r = i/20; int mp = r % NMP1; int l = r/NMP1;
    float2 v = make_float2(0.f, 0.f);
    if (n < NM1) {
      float2 xa = Xs[l*NMP1+mp], pp = Ps[l*NM1+n];
      v = make_float2(xa.x*pp.x - xa.y*pp.y, xa.x*pp.y + xa.y*pp.x);
    }
    XPp[i] = v;
  }
  __syncthreads();

  float2* Fh = bufA;
  float2* Tt = bufB;
  float*  yb = (float*)bufA;
  float2* Uu = bufB;

  for (int c = 0; c < NB1/NBC; ++c) {
    const int b0 = c*NBC;
    // ph1: Fh[bb][mp][n0..n0+3] = sum_l XPp * d1wc
    for (int i = t; i < NBC*NMP1*5; i += 256) {
      int q = i % 5; int r = i/5; int mp = r % NMP1; int bb = r/NMP1;
      int n0 = q*4;
      const float* dw = &d1wc[((b0+bb)*NMP1 + mp)*20 + n0];
      const float2* xp = &XPp[mp*20 + n0];
      float2 a0 = {0.f,0.f}, a1 = {0.f,0.f}, a2 = {0.f,0.f}, a3 = {0.f,0.f};
      #pragma unroll
      for (int l = 0; l < NL1; ++l) {
        float4 w4 = *(const float4*)&dw[l*4000];
        float4 xa = *(const float4*)&xp[l*(NMP1*20)];
        float4 xb = *(const float4*)&xp[l*(NMP1*20) + 2];
        a0.x = fmaf(w4.x, xa.x, a0.x); a0.y = fmaf(w4.x, xa.y, a0.y);
        a1.x = fmaf(w4.y, xa.z, a1.x); a1.y = fmaf(w4.y, xa.w, a1.y);
        a2.x = fmaf(w4.z, xb.x, a2.x); a2.y = fmaf(w4.z, xb.y, a2.y);
        a3.x = fmaf(w4.w, xb.z, a3.x); a3.y = fmaf(w4.w, xb.w, a3.y);
      }
      float2* fr = &Fh[(bb*NMP1 + mp)*NM1 + n0];
      fr[0] = a0; fr[1] = a1; fr[2] = a2;
      if (n0 + 3 < NM1) fr[3] = a3;
    }
    __syncthreads();
    // ph2 (radix-2 fold): compute Tt[g0..g0+1] and Tt[g0+10..g0+11]
    for (int i = t; i < NBC*NMP1*5; i += 256) {
      int q = i % 5; int r = i / 5; int mp = r % NMP1; int bb = r / NMP1;
      int g0 = q*2;
      const float2* fh = &Fh[(bb*NMP1 + mp)*NM1];
      float pe0x=0.f,pe0y=0.f,pe1x=0.f,pe1y=0.f;
      float po0x=0.f,po0y=0.f,po1x=0.f,po1y=0.f;
      #pragma unroll
      for (int n = 0; n < NM1; ++n) {
        float2 f = fh[n];
        float4 e = *(const float4*)&EsynTp[n*TTS + g0];
        float cr0 = f.x*e.x - f.y*e.y, ci0 = f.x*e.y + f.y*e.x;
        float cr1 = f.x*e.z - f.y*e.w, ci1 = f.x*e.w + f.y*e.z;
        if ((n & 1) == 0) { pe0x += cr0; pe0y += ci0; pe1x += cr1; pe1y += ci1; }
        else              { po0x += cr0; po0y += ci0; po1x += cr1; po1y += ci1; }
      }
      float2* tr = &Tt[(bb*NMP1 + mp)*TTS];
      *(float4*)&tr[g0]      = make_float4(pe0x+po0x, pe0y+po0y, pe1x+po1x, pe1y+po1y);
      *(float4*)&tr[g0+10]   = make_float4(po0x-pe0x, po0y-pe0y, po1x-pe1x, po1y-pe1y);
    }
    __syncthreads();
    // ph3 (radix-2 fold over a): y[a] and y[a+10]
    for (int i = t; i < NBC*10*5; i += 256) {
      int gq = i % 5; int r = i / 5; int a = r % 10; int bb = r / 10;
      int g0 = gq*4;
      float4 t01 = *(const float4*)&Tt[(bb*NMP1)*TTS + g0];
      float4 t23 = *(const float4*)&Tt[(bb*NMP1)*TTS + g0 + 2];
      float se0=0.f,se1=0.f,se2=0.f,se3=0.f, so0=0.f,so1=0.f,so2=0.f,so3=0.f;
      #pragma unroll
      for (int mp = 1; mp < NMP1; ++mp) {
        float4 u01 = *(const float4*)&Tt[(bb*NMP1 + mp)*TTS + g0];
        float4 u23 = *(const float4*)&Tt[(bb*NMP1 + mp)*TTS + g0 + 2];
        float2 e = EsynA[a*NMP1 + mp];
        float c0 = e.x*u01.x - e.y*u01.y;
        float c1 = e.x*u01.z - e.y*u01.w;
        float c2 = e.x*u23.x - e.y*u23.y;
        float c3 = e.x*u23.z - e.y*u23.w;
        if (mp & 1) { so0+=c0; so1+=c1; so2+=c2; so3+=c3; }
        else        { se0+=c0; se1+=c1; se2+=c2; se3+=c3; }
      }
      float* y0 = &yb[(bb*NB1 + a)*NB1 + g0];
      float* y1 = &yb[(bb*NB1 + a + 10)*NB1 + g0];
      y0[0]=fmaxf(fmaf(2.f, se0+so0, t01.x),0.f);
      y0[1]=fmaxf(fmaf(2.f, se1+so1, t01.z),0.f);
      y0[2]=fmaxf(fmaf(2.f, se2+so2, t23.x),0.f);
      y0[3]=fmaxf(fmaf(2.f, se3+so3, t23.z),0.f);
      y1[0]=fmaxf(fmaf(2.f, se0-so0, t01.x),0.f);
      y1[1]=fmaxf(fmaf(2.f, se1-so1, t01.z),0.f);
      y1[2]=fmaxf(fmaf(2.f, se2-so2, t23.x),0.f);
      y1[3]=fmaxf(fmaf(2.f, se3-so3, t23.z),0.f);
    }
    __syncthreads();
    // ph4 (radix-2 fold over a): U[bb][m2p][g] = sum_{a<10}(y[a] + sgn*y[a+10])*EanaA[a][m2p]
    for (int i = t; i < NBC*NMP2*5; i += 256) {
      int gq = i % 5; int r = i / 5; int m2p = r % NMP2; int bb = r / NMP2;
      int g0 = gq*4;
      const float sgn = (m2p & 1) ? -1.f : 1.f;
      float2 u0 = {0.f,0.f}, u1 = {0.f,0.f}, u2 = {0.f,0.f}, u3 = {0.f,0.f};
      #pragma unroll
      for (int aa = 0; aa < 10; ++aa) {
        float4 ya = *(const float4*)&yb[(bb*NB1 + aa)*NB1 + g0];
        float4 ybv = *(const float4*)&yb[(bb*NB1 + aa + 10)*NB1 + g0];
        float v0 = fmaf(sgn, ybv.x, ya.x);
        float v1 = fmaf(sgn, ybv.y, ya.y);
        float v2 = fmaf(sgn, ybv.z, ya.z);
        float v3 = fmaf(sgn, ybv.w, ya.w);
        float2 e = EanaA[aa*NMP2 + m2p];
        u0.x = fmaf(v0, e.x, u0.x); u0.y = fmaf(v0, e.y, u0.y);
        u1.x = fmaf(v1, e.x, u1.x); u1.y = fmaf(v1, e.y, u1.y);
        u2.x = fmaf(v2, e.x, u2.x); u2.y = fmaf(v2, e.y, u2.y);
        u3.x = fmaf(v3, e.x, u3.x); u3.y = fmaf(v3, e.y, u3.y);
      }
      float2* ur = &Uu[(bb*NMP2 + m2p)*TTS + g0];
      ur[0] = u0; ur[1] = u1; ur[2] = u2; ur[3] = u3;
    }
    __syncthreads();
    // ph5 (radix-2 fold over g): even n2i uses U[g]-U[g+10], odd uses U[g]+U[g+10]
    for (int i = t; i < NBC*NMP2*6; i += 256) {
      int p = i % 6; int r = i / 6; int m2p = r % NMP2; int bb = r / NMP2;
      int n0 = p*2;   // n0 even -> (n0-5) odd -> sign -1 ; n0+1 odd -> sign +1
      const float2* ur = &Uu[(bb*NMP2 + m2p)*TTS];
      float2 acc0 = {0.f,0.f}, acc1 = {0.f,0.f};
      #pragma unroll
      for (int g = 0; g < 10; ++g) {
        float2 ua = ur[g], ub = ur[g+10];
        float2 ud = make_float2(ua.x - ub.x, ua.y - ub.y);   // for even n2i
        float2 us = make_float2(ua.x + ub.x, ua.y + ub.y);   // for odd n2i
        float4 e = *(const float4*)&EanaG[g*12 + n0];
        acc0.x += ud.x*e.x - ud.y*e.y; acc0.y += ud.x*e.y + ud.y*e.x;
        acc1.x += us.x*e.z - us.y*e.w; acc1.y += us.x*e.w + us.y*e.z;
      }
      yfs[(bb*NMP2 + m2p)*NM2 + n0] = acc0;
      if (n0 + 1 < NM2) yfs[(bb*NMP2 + m2p)*NM2 + n0 + 1] = acc1;
    }
    __syncthreads();
    // ph6: Fxa += sum_bb d12wc*yf
    for (int i = t; i < NL2*NMP2*NM2; i += 256) {
      int l2 = i/(NMP2*NM2); int r = i%(NMP2*NM2);
      float2 acc = Fxa[i];
      #pragma unroll
      for (int bb = 0; bb < NBC; ++bb) {
        float w = d12wc[(l2*NB1 + b0 + bb)*66 + r];
        float2 v = yfs[bb*(NMP2*NM2) + r];
        acc.x = fmaf(w, v.x, acc.x); acc.y = fmaf(w, v.y, acc.y);
      }
      Fxa[i] = acc;
    }
    __syncthreads();
  }
  for (int i = t; i < NL2*NMP2*NM2; i += 256) {
    int l2 = i/(NMP2*NM2); int r = i%(NMP2*NM2);
    int mp = r/NM2, n = r%NM2;
    Am[(size_t)l2*GEMM_MH*GEMM_K + (z*NMP2 + mp)*GEMM_K + o*NM2 + n] = Fxa[i];
  }
}

// ---------------- K5: per-l complex GEMM, split-K ----------------
__global__ __launch_bounds__(256) void k_so3mm(const float2* __restrict__ A,
                                               const float2* __restrict__ B,
                                               float2* __restrict__ C0,
                                               float2* __restrict__ C1) {
  __shared__ float2 As[GM*ASTR];
  __shared__ float2 Bs[GK*GN];
  const int lz = blockIdx.z;
  const int l = lz >> 1, half = lz & 1;
  const int kbeg = half ? 120 : 0, klim = half ? 220 : 120;
  const int row0 = blockIdx.x*GM, col0 = blockIdx.y*GN;
  const int t = threadIdx.x;
  const float2* Ag = A + (size_t)l*GEMM_MH*GEMM_K;
  const float2* Bg = B + (size_t)l*GEMM_K*GEMM_N;
  float2* Cg = (half ? C1 : C0) + (size_t)l*GEMM_MH*GEMM_N;
  const int tn = t & 15, tm = t >> 4;
  float2 acc[4][4];
  #pragma unroll
  for (int i = 0; i < 4; ++i)
    #pragma unroll
    for (int j = 0; j < 4; ++j) acc[i][j] = make_float2(0.f, 0.f);

  for (int k0 = kbeg; k0 < klim; k0 += GK) {
    for (int i = t; i < GM*GK; i += 256) {
      int r = i/GK, kk = i%GK;
      As[r*ASTR + kk] = Ag[(size_t)(row0 + r)*GEMM_K + k0 + kk];
    }
    for (int i = t; i < GK*GN; i += 256) {
      int kk = i/GN, cc = i%GN;
      int col = col0 + cc;
      float2 v = (col < GEMM_N) ? Bg[(size_t)(k0 + kk)*GEMM_N + col] : make_float2(0.f, 0.f);
      Bs[(kk*4 + (cc & 3))*16 + (cc >> 2)] = v;
    }
    __syncthreads();
    #pragma unroll
    for (int kk = 0; kk < GK; ++kk) {
      float2 a[4], b[4];
      #pragma unroll
      for (int i = 0; i < 4; ++i) a[i] = As[(tm*4 + i)*ASTR + kk];
      #pragma unroll
      for (int j = 0; j < 4; ++j) b[j] = Bs[(kk*4 + j)*16 + tn];
      #pragma unroll
      for (int i = 0; i < 4; ++i)
        #pragma unroll
        for (int j = 0; j < 4; ++j) {
          acc[i][j].x = fmaf(a[i].x, b[j].x, acc[i][j].x);
          acc[i][j].x = fmaf(-a[i].y, b[j].y, acc[i][j].x);
          acc[i][j].y = fmaf(a[i].x, b[j].y, acc[i][j].y);
          acc[i][j].y = fmaf(a[i].y, b[j].x, acc[i][j].y);
        }
    }
    __syncthreads();
  }
  #pragma unroll
  for (int i = 0; i < 4; ++i) {
    int r = row0 + tm*4 + i;
    int c0 = col0 + tn*4;
    if (c0 < GEMM_N) {
      float4 v0 = make_float4(acc[i][0].x, acc[i][0].y, acc[i][1].x, acc[i][1].y);
      float4 v1 = make_float4(acc[i][2].x, acc[i][2].y, acc[i][3].x, acc[i][3].y);
      *(float4*)&Cg[(size_t)r*GEMM_N + c0] = v0;
      *(float4*)&Cg[(size_t)r*GEMM_N + c0 + 2] = v1;
    }
  }
}

// ---------------- K6: fused stage 2 tail (adds split-K halves) ----------------
__global__ __launch_bounds__(256) void k_stage2(const float2* __restrict__ C0,
                                                const float2* __restrict__ C1,
                                                const float* __restrict__ d2w,
                                                const float* __restrict__ w2n,
                                                const float2* __restrict__ Tg,
                                                float* __restrict__ feat) {
  __shared__ float2 Fos[NL2*NM2*NM2];
  __shared__ float2 Fh2[NB2*NM2*NM2];
  __shared__ float2 T2[NB2*NB2*NM2];
  __shared__ float2 Esyn2[NB2*NM2];
  __shared__ float w2s[NB2];
  __shared__ float wred[4];
  const int z = blockIdx.x, o = blockIdx.y, t = threadIdx.x;
  for (int i = t; i < NB2*NM2; i += 256) Esyn2[i] = Tg[TW_S2 + i];
  if (t < NB2) w2s[t] = w2n[t];
  for (int i = t; i < NL2*NM2*NM2; i += 256) {
    int l = i/(NM2*NM2); int mn = i%(NM2*NM2);
    int m = mn/NM2, n = mn%NM2;
    float2 v;
    if (m >= 5) {
      size_t idx = (size_t)l*GEMM_MH*GEMM_N + (size_t)(z*NMP2 + m - 5)*GEMM_N + o*NM2 + n;
      float2 a = C0[idx], b2 = C1[idx];
      v = make_float2(a.x + b2.x, a.y + b2.y);
    } else {
      size_t idx = (size_t)l*GEMM_MH*GEMM_N + (size_t)(z*NMP2 + 5 - m)*GEMM_N + o*NM2 + (10 - n);
      float2 a = C0[idx], b2 = C1[idx];
      float s = ((m - n) & 1) ? -1.f : 1.f;
      v = make_float2(s*(a.x + b2.x), -s*(a.y + b2.y));
    }
    Fos[i] = v;
  }
  __syncthreads();
  for (int i = t; i < NB2*NM2*NM2; i += 256) {
    int b = i/(NM2*NM2); int mn = i%(NM2*NM2);
    float re = 0.f, im = 0.f;
    #pragma unroll
    for (int l = 0; l < NL2; ++l) {
      float w = d2w[(l*NB2 + b)*(NM2*NM2) + mn];
      float2 v = Fos[l*(NM2*NM2) + mn];
      re = fmaf(w, v.x, re); im = fmaf(w, v.y, im);
    }
    Fh2[i] = make_float2(re, im);
  }
  __syncthreads();
  for (int i = t; i < NB2*NB2*NM2; i += 256) {
    int ni = i % NM2; int r = i / NM2; int aa = r % NB2; int b = r / NB2;
    const float2* fh = &Fh2[b*(NM2*NM2) + ni];
    float re = 0.f, im = 0.f;
    #pragma unroll
    for (int mi = 0; mi < NM2; ++mi) {
      float2 f = fh[mi*NM2]; float2 e = Esyn2[aa*NM2+mi];
      re += e.x*f.x - e.y*f.y;
      im += e.x*f.y + e.y*f.x;
    }
    T2[i] = make_float2(re, im);
  }
  __syncthreads();
  float accT = 0.f;
  for (int i = t; i < NB2*NB2*NB2; i += 256) {
    int g = i % NB2; int r = i / NB2; int aa = r % NB2; int b = r / NB2;
    const float2* trow = &T2[(b*NB2 + aa)*NM2];
    float v = 0.f;
    #pragma unroll
    for (int ni = 0; ni < NM2; ++ni) {
      float2 tv = trow[ni]; float2 e = Esyn2[g*NM2+ni];
      v += e.x*tv.x - e.y*tv.y;
    }
    accT += w2s[b]*fmaxf(v, 0.f);
  }
  #pragma unroll
  for (int off = 32; off > 0; off >>= 1) accT += __shfl_down(accT, off);
  if ((t & 63) == 0) wred[t >> 6] = accT;
  __syncthreads();
  if (t == 0) feat[z*F2C + o] = (wred[0]+wred[1]+wred[2]+wred[3]) / (float)(NB2*NB2);
}

// ---------------- K7: linear head ----------------
__global__ void k_head(const float* __restrict__ feat, const float* __restrict__ w_lin,
                       const float* __restrict__ b_lin, float* __restrict__ out) {
  int idx = blockIdx.x*blockDim.x + threadIdx.x;
  if (idx >= BATCH*10) return;
  int z = idx/10, f = idx%10;
  float acc = b_lin[f];
  for (int o = 0; o < F2C; ++o) acc = fmaf(feat[z*F2C + o], w_lin[f*F2C + o], acc);
  out[idx] = acc;
}

extern "C" void kernel_launch(void* const* d_in, const int* in_sizes, int n_in,
                              void* d_out, int out_size, void* d_ws, size_t ws_size,
                              hipStream_t stream) {
  const float* x     = (const float*)d_in[0];
  const float* psi1  = (const float*)d_in[1];
  const float* psi2  = (const float*)d_in[2];
  const float* w_lin = (const float*)d_in[3];
  const float* b_lin = (const float*)d_in[4];
  float* out = (float*)d_out;
  float* ws  = (float*)d_ws;

  size_t off = 0;
  auto alloc = [&](size_t nfloats) { size_t o = off; off += (nfloats + 15) & ~(size_t)15; return o; };
  float2* Tglob = (float2*)(ws + alloc(2*TW_TOT));
  float*  d1wc  = ws + alloc(N_D1WC);
  float*  d12wc = ws + alloc(N_D12WC);
  float*  wigY  = ws + alloc(N_WIGY);
  float*  wigD2 = ws + alloc(N_WIGD2);
  float*  d2w   = ws + alloc(N_D2W);
  float*  wd_s2c= ws + alloc(N_WDS2C);
  float*  w2n   = ws + alloc(N_W2N);
  float2* X     = (float2*)(ws + alloc(2*(size_t)NL1*BATCH*NMP1));
  float2* Psi1p = (float2*)(ws + alloc(2*(size_t)NL1*F1C*NM1));
  float2* Bmat  = (float2*)(ws + alloc(2*(size_t)NL2*GEMM_K*GEMM_N));
  float2* Amat  = (float2*)(ws + alloc(2*(size_t)NL2*GEMM_MH*GEMM_K));
  float2* Cmat0 = (float2*)(ws + alloc(2*(size_t)NL2*GEMM_MH*GEMM_N));
  float2* Cmat1 = (float2*)(ws + alloc(2*(size_t)NL2*GEMM_MH*GEMM_N));
  float*  featp = ws + alloc((size_t)BATCH*F2C);
  if (ws_size < off*sizeof(float)) return;

  k_consts1<<<(N_CSMALL + 255)/256, 256, 0, stream>>>(Tglob, wigY, wigD2, wd_s2c, w2n);
  k_prep<<<PREP_BASE + NBLK_CPREP, 256, 0, stream>>>(x, wd_s2c, Tglob, wigY, wigD2,
                                                     psi1, psi2, X, Psi1p, Bmat,
                                                     d1wc, d12wc, d2w);
  k_stage1<<<dim3(BATCH, F1C), 256, 0, stream>>>(X, Psi1p, d1wc, d12wc, Tglob, Amat);
  k_so3mm<<<dim3(GEMM_MH/GM, (GEMM_N + GN - 1)/GN, 2*NL2), 256, 0, stream>>>(Amat, Bmat, Cmat0, Cmat1);
  k_stage2<<<dim3(BATCH, F2C), 256, 0, stream>>>(Cmat0, Cmat1, d2w, w2n, Tglob, featp);
  k_head<<<(BATCH*10 + 255)/256, 256, 0, stream>>>(featp, w_lin, b_lin, out);
}

// Round 19
// 240.250 us; speedup vs baseline: 1.3197x; 1.0609x over previous
//
#include <hip/hip_runtime.h>
#include <math.h>

#define PI_D 3.14159265358979323846
#define PI_F 3.14159265358979f

#define BATCH 128
#define NM1 19
#define NMP1 10
#define NM2 11
#define NMP2 6
#define NB_IN 60
#define NB1 20
#define NB2 12
#define NL1 10
#define NL2 6
#define F1C 20
#define F2C 40
#define NBC 5

#define GEMM_MH (BATCH*NMP2)  // 768
#define GEMM_N (F2C*NM2)      // 440
#define GEMM_K (F1C*NM2)      // 220
#define GM 64
#define GN 64
#define GK 20
#define ASTR 21

// twiddle table global layout (float2 offsets)
#define TW_SYNT 0       // [19][20]
#define TW_SYNA 380     // [20][10]
#define TW_ANAA 580     // [20][6]
#define TW_ANAG 700     // [20][12] col11=0
#define TW_S2   940     // [12][11]
#define TW_60   1072    // [60][10]
#define TW_TOT  1672

#define TTS 22          // padded EsynT/Tt/Uu row stride (float2)

// constants counts
#define N_D1WC 40000    // [10l][20b][10mp][20]
#define N_D12WC 7920    // [6l][20b][6m2p][11]
#define N_WIGY 570      // [10l][3b][19m]
#define N_WIGD2 2178    // [6l][3b][121mn]
#define N_D2W  (NL2*NB2*NM2*NM2)   // 8712
#define N_WDS2C 6000    // [10l][60k][10mp]
#define N_W2N  (NB2)
#define N_CSMALL (N_WIGY+N_WIGD2+N_WDS2C+N_W2N)
#define N_CPREP (N_D1WC+N_D12WC+N_D2W)
#define PREP_BASE (BATCH + 1 + 120)
#define NBLK_CPREP ((N_CPREP + 255)/256)

// ---------------- fp32 Wigner-d helpers ----------------
__device__ __forceinline__ float ipow_f(float x, int e) {
  float r = 1.f;
  for (int i = 0; i < e; ++i) r *= x;
  return r;
}

__device__ float wigdf(const float* lf, int l, int m, int n, float beta) {
  if (m < -l || m > l || n < -l || n > l) return 0.f;
  float cb = cosf(0.5f*beta), sb = sinf(0.5f*beta);
  float pref = 0.5f*(lf[l+m]+lf[l-m]+lf[l+n]+lf[l-n]);
  int s0 = (n-m) > 0 ? (n-m) : 0;
  int s1 = (l+n) < (l-m) ? (l+n) : (l-m);
  float acc = 0.f;
  for (int s = s0; s <= s1; ++s) {
    float lc = pref - (lf[l+n-s]+lf[s]+lf[m-n+s]+lf[l-m-s]);
    float tt = expf(lc) * ipow_f(cb, 2*l+n-m-2*s) * ipow_f(sb, m-n+2*s);
    acc += ((m-n+s) & 1) ? -tt : tt;
  }
  return acc;
}

__device__ __forceinline__ float dh_beta_f(int b, int k) {
  return (float)(PI_D*(2*k+1)/(4.0*b));
}

__device__ float dh_w_f(int b, int k) {
  float beta = dh_beta_f(b, k), s = 0.f;
  for (int j = 0; j < b; ++j) s += sinf((2.f*(float)j+1.f)*beta)/(2.f*(float)j+1.f);
  return (2.f/(float)b)*sinf(beta)*s;
}

// ---------------- consts_small: twiddles + prep-prerequisite tables ----------------
__global__ __launch_bounds__(256) void k_consts1(float2* __restrict__ Tg,
                         float* __restrict__ wigY, float* __restrict__ wigD2,
                         float* __restrict__ wd_s2c, float* __restrict__ w2n) {
  __shared__ float lf[41];
  __shared__ float dhw30[60], dhw6[12];
  int t = threadIdx.x;
  if (t < 41) lf[t] = (float)lgamma((double)t + 1.0);
  else if (t < 101) dhw30[t-41] = dh_w_f(30, t-41);
  else if (t < 113) dhw6[t-101] = dh_w_f(6, t-101);
  __syncthreads();

  if (blockIdx.x == 0) {
    for (int i = t; i < TW_TOT; i += 256) {
      float2 v;
      if (i < TW_SYNA) {
        int j = i, n = j/NB1, g = j%NB1;
        int r = (g*(n-9)) % NB1; if (r < 0) r += NB1;
        float s, c; sincosf(2.f*PI_F*(float)r/(float)NB1, &s, &c);
        v = make_float2(c, s);
      } else if (i < TW_ANAA) {
        int j = i - TW_SYNA, a = j/NMP1, mp = j%NMP1;
        int r = (a*mp) % NB1;
        float s, c; sincosf(2.f*PI_F*(float)r/(float)NB1, &s, &c);
        v = make_float2(c, s);
      } else if (i < TW_ANAG) {
        int j = i - TW_ANAA, a = j/NMP2, m2p = j%NMP2;
        int r = (a*m2p) % NB1;
        float s, c; sincosf(2.f*PI_F*(float)r/(float)NB1, &s, &c);
        v = make_float2(c, -s);
      } else if (i < TW_S2) {
        int j = i - TW_ANAG, g = j/12, cI = j%12;
        if (cI == 11) v = make_float2(0.f, 0.f);
        else {
          int r = (g*(cI-5)) % NB1; if (r < 0) r += NB1;
          float s, c; sincosf(2.f*PI_F*(float)r/(float)NB1, &s, &c);
          v = make_float2(c, -s);
        }
      } else if (i < TW_60) {
        int j = i - TW_S2, k = j/NM2, mi = j%NM2;
        int r = (k*(mi-5)) % NB2; if (r < 0) r += NB2;
        float s, c; sincosf(2.f*PI_F*(float)r/(float)NB2, &s, &c);
        v = make_float2(c, s);
      } else {
        int j = i - TW_60, a = j/NMP1, mp = j%NMP1;
        int r = (a*mp) % NB_IN;
        float s, c; sincosf(2.f*PI_F*(float)r/(float)NB_IN, &s, &c);
        v = make_float2(c, -s);
      }
      Tg[i] = v;
    }
  }

  int gid = blockIdx.x*blockDim.x + t;

  if (gid < N_WIGY) {
    int l = gid/57; int r = gid%57; int bidx = r/19; int mi = r%19;
    float beta = (float)((double)(bidx + 1) * PI_D/24.0);
    wigY[gid] = wigdf(lf, l, mi-9, 0, beta);
    return;
  }
  gid -= N_WIGY;
  if (gid < N_WIGD2) {
    int l = gid/363; int r = gid%363; int bidx = r/121; int mn = r%121;
    int m = mn/NM2 - 5, n = mn%NM2 - 5;
    float beta = (float)((double)(bidx + 1) * PI_D/24.0);
    wigD2[gid] = wigdf(lf, l, m, n, beta);
    return;
  }
  gid -= N_WIGD2;
  if (gid < N_WDS2C) {
    int l = gid/600; int r = gid%600; int k = r/10; int mp = r%10;
    wd_s2c[gid] = dhw30[k] * wigdf(lf, l, mp, 0, dh_beta_f(30,k));
    return;
  }
  gid -= N_WDS2C;
  if (gid < N_W2N) {
    float s = 0.f;
    for (int j = 0; j < NB2; ++j) s += dhw6[j];
    w2n[gid] = dhw6[gid]/s;
    return;
  }
}

// ---------------- K_prep: s2fft (0..127) + psi1 (128) + psi2 (129..248) + heavy consts ----------------
#define P2IO 40
#define P2GC 24
__global__ __launch_bounds__(256) void k_prep(const float* __restrict__ x,
                                              const float* __restrict__ wd_s2c,
                                              const float2* __restrict__ Tg,
                                              const float* __restrict__ wigY,
                                              const float* __restrict__ wigD2,
                                              const float* __restrict__ psi1,
                                              const float* __restrict__ psi2,
                                              float2* __restrict__ X,
                                              float2* __restrict__ Psi1p,
                                              float2* __restrict__ Bm,
                                              float* __restrict__ d1wc,
                                              float* __restrict__ d12wc,
                                              float* __restrict__ d2w) {
  __shared__ __align__(16) float smem[6912];
  const int bid = blockIdx.x, t = threadIdx.x;

  if (bid < BATCH) {
    // ---- s2fft for z = bid (radix-2 folded over a) ----
    const int z = bid;
    float*  xs   = smem;                       // 3600
    float2* xf   = (float2*)(smem + 3600);     // 600 f2
    float2* tw60 = (float2*)(smem + 4800);     // 600 f2 (only a<30 rows used)
    for (int i = t; i < NB_IN*NMP1; i += 256) tw60[i] = Tg[TW_60 + i];
    for (int i = t; i < 3600; i += 256) xs[i] = x[z*3600 + i];
    __syncthreads();
    for (int i = t; i < NB_IN*NMP1; i += 256) {
      int k = i/NMP1, mp = i%NMP1;
      float sgn = (mp & 1) ? -1.f : 1.f;
      float re = 0.f, im = 0.f;
      const float* xrow = &xs[k*NB_IN];
      for (int a = 0; a < 30; ++a) {
        float v = fmaf(sgn, xrow[a+30], xrow[a]);
        float2 e = tw60[a*NMP1 + mp];
        re = fmaf(v, e.x, re);
        im = fmaf(v, e.y, im);
      }
      xf[i] = make_float2(re, im);
    }
    __syncthreads();
    for (int i = t; i < NL1*NMP1; i += 256) {
      int l = i/NMP1, mp = i%NMP1;
      float re = 0.f, im = 0.f;
      for (int k = 0; k < NB_IN; ++k) {
        float w = wd_s2c[(l*NB_IN+k)*NMP1 + mp];
        float2 v = xf[k*NMP1 + mp];
        re = fmaf(w, v.x, re); im = fmaf(w, v.y, im);
      }
      X[(l*BATCH + z)*NMP1 + mp] = make_float2(re, im);
    }
    return;
  }

  if (bid == BATCH) {
    // ---- psi1 ----
    float*  wigYs = smem;                      // 570
    float*  psis  = smem + 576;                // 480
    float2* ph8   = (float2*)(smem + 1056);
    for (int i = t; i < N_WIGY; i += 256) wigYs[i] = wigY[i];
    for (int i = t; i < F1C*24; i += 256) psis[i] = psi1[i];
    if (t < 8) {
      float s, c; sincosf(2.f*PI_F*(float)t/8.f, &s, &c);
      ph8[t] = make_float2(c, s);
    }
    __syncthreads();
    for (int i = t; i < NL1*F1C*NM1; i += 256) {
      int l = i/(F1C*NM1); int r = i%(F1C*NM1); int o = r/NM1; int mi = r%NM1;
      int m = mi - 9;
      float re = 0.f, im = 0.f;
      for (int g = 0; g < 24; ++g) {
        float w = psis[o*24 + g];
        float d = wigYs[(l*3 + (g >> 3))*NM1 + mi];
        int pa = g & 7;
        int rr = (-(m*pa)) % 8; if (rr < 0) rr += 8;
        float2 ph = ph8[rr];
        re = fmaf(w, d*ph.x, re); im = fmaf(w, d*ph.y, im);
      }
      Psi1p[i] = make_float2(re, im);
    }
    return;
  }

  if (bid < PREP_BASE) {
    // ---- psi2 (120 blocks) ----
    const int j = bid - (BATCH + 1);
    const int io0 = (j/NL2)*P2IO, l = j%NL2;
    float2* Ds   = (float2*)smem;              // 2928 f2
    float*  Ws   = smem + 5856;                // 960 f
    float2* ph24 = (float2*)(smem + 6816);     // 24 f2
    const int tio = t/31, tmn = t%31;
    const int mn0 = tmn*4;
    if (t < 24) {
      float s, c; sincosf(2.f*PI_F*(float)t/24.f, &s, &c);
      ph24[t] = make_float2(c, s);
    }
    __syncthreads();
    float2 acc[5][4];
    #pragma unroll
    for (int i = 0; i < 5; ++i)
      #pragma unroll
      for (int jj = 0; jj < 4; ++jj) acc[i][jj] = make_float2(0.f, 0.f);

    for (int gc = 0; gc < 144; gc += P2GC) {
      for (int i = t; i < P2GC*121; i += 256) {
        int g = i/121, mn = i%121;
        int p = gc + g;
        int m = mn/NM2 - 5, n = mn%NM2 - 5;
        float d = wigD2[(l*3 + p/48)*121 + mn];
        int pa = (p/6)%8, pg = p%6;
        int rr24 = (-(3*m*pa + 4*n*pg)) % 24; if (rr24 < 0) rr24 += 24;
        float2 ph = ph24[rr24];
        Ds[g*122 + mn] = make_float2(d*ph.x, d*ph.y);
      }
      for (int i = t; i < P2IO*P2GC; i += 256) {
        int io = i/P2GC, g = i%P2GC;
        Ws[i] = psi2[(io0 + io)*144 + gc + g];
      }
      __syncthreads();
      if (tio < 8) {
        for (int g = 0; g < P2GC; ++g) {
          float4 d01 = *(const float4*)&Ds[g*122 + mn0];
          float4 d23 = *(const float4*)&Ds[g*122 + mn0 + 2];
          float w0 = Ws[(tio*5 + 0)*P2GC + g];
          float w1 = Ws[(tio*5 + 1)*P2GC + g];
          float w2 = Ws[(tio*5 + 2)*P2GC + g];
          float w3 = Ws[(tio*5 + 3)*P2GC + g];
          float w4 = Ws[(tio*5 + 4)*P2GC + g];
          float dx[4] = {d01.x, d01.z, d23.x, d23.z};
          float dy[4] = {d01.y, d01.w, d23.y, d23.w};
          float wv[5] = {w0, w1, w2, w3, w4};
          #pragma unroll
          for (int i = 0; i < 5; ++i)
            #pragma unroll
            for (int jj = 0; jj < 4; ++jj) {
              acc[i][jj].x = fmaf(wv[i], dx[jj], acc[i][jj].x);
              acc[i][jj].y = fmaf(wv[i], dy[jj], acc[i][jj].y);
            }
        }
      }
      __syncthreads();
    }
    if (tio < 8) {
      #pragma unroll
      for (int i = 0; i < 5; ++i) {
        int io = io0 + tio*5 + i;
        int ii = io/F2C, oo = io%F2C;
        #pragma unroll
        for (int jj = 0; jj < 4; ++jj) {
          int mn = mn0 + jj;
          if (mn < 121) {
            int k = mn/NM2, n = mn%NM2;
            Bm[(size_t)l*GEMM_K*GEMM_N + (ii*NM2 + k)*GEMM_N + oo*NM2 + n] = acc[i][jj];
          }
        }
      }
    }
    return;
  }

  // ---- heavy consts branch (222 blocks): d1wc, d12wc, d2w ----
  {
    float* lf     = smem;        // 41
    float* dhw10l = smem + 48;   // 20
    if (t < 41) lf[t] = (float)lgamma((double)t + 1.0);
    else if (t >= 64 && t < 84) dhw10l[t-64] = dh_w_f(10, t-64);
    __syncthreads();
    int idx = (bid - PREP_BASE)*256 + t;
    if (idx < N_D1WC) {
      int l = idx/4000; int r = idx%4000; int b = r/200; int r2 = r%200;
      int mp = r2/20, nn = r2%20;
      d1wc[idx] = (nn < NM1) ? (float)(2*l+1) * wigdf(lf, l, mp, nn-9, dh_beta_f(10,b)) : 0.f;
      return;
    }
    idx -= N_D1WC;
    if (idx < N_D12WC) {
      int l2 = idx/1320; int r = idx%1320; int b = r/66; int r2 = r%66;
      int m2p = r2/11, n2i = r2%11;
      d12wc[idx] = dhw10l[b] * wigdf(lf, l2, m2p, n2i-5, dh_beta_f(10,b));
      return;
    }
    idx -= N_D12WC;
    if (idx < N_D2W) {
      int l = idx/(NB2*NM2*NM2); int r = idx%(NB2*NM2*NM2); int j = r/(NM2*NM2); int rr = r%(NM2*NM2);
      int m = rr/NM2 - 5, n = rr%NM2 - 5;
      d2w[idx] = (float)(2*l+1) * wigdf(lf, l, m, n, dh_beta_f(6,j));
      return;
    }
  }
}

// ---------------- K4: fused stage 1 (radix-2 folded ph2/ph3/ph4/ph5) ----------------
__global__ __launch_bounds__(256) void k_stage1(const float2* __restrict__ X,
                                                const float2* __restrict__ Psi1,
                                                const float* __restrict__ d1wc,
                                                const float* __restrict__ d12wc,
                                                const float2* __restrict__ Tg,
                                                float2* __restrict__ Am) {
  __shared__ float2 Xs[NL1*NMP1];
  __shared__ float2 Ps[NL1*NM1];
  __shared__ __align__(16) float2 XPp[NL1*NMP1*20];
  __shared__ __align__(16) float2 Etab[978];
  __shared__ __align__(16) float2 bufA[NBC*200];
  __shared__ __align__(16) float2 bufB[NBC*220];
  __shared__ float2 yfs[NBC*NMP2*NM2];
  __shared__ float2 Fxa[NL2*NMP2*NM2];

  const int z = blockIdx.x, o = blockIdx.y, t = threadIdx.x;
  const float2* EsynTp = Etab;
  const float2* EsynA  = Etab + 418;
  const float2* EanaA  = Etab + 618;
  const float2* EanaG  = Etab + 738;

  for (int i = t; i < 978; i += 256) {
    float2 v;
    if (i < 418) {
      int n = i/TTS, g = i%TTS;
      v = (g < NB1) ? Tg[TW_SYNT + n*NB1 + g] : make_float2(0.f, 0.f);
    } else {
      v = Tg[TW_SYNA + (i - 418)];
    }
    Etab[i] = v;
  }
  for (int i = t; i < NL1*NMP1; i += 256) {
    int l = i/NMP1, mp = i%NMP1;
    Xs[i] = X[(l*BATCH + z)*NMP1 + mp];
  }
  for (int i = t; i < NL1*NM1; i += 256) {
    int l = i/NM1, mi = i%NM1;
    Ps[i] = Psi1[(l*F1C + o)*NM1 + mi];
  }
  for (int i = t; i < NL2*NMP2*NM2; i += 256) Fxa[i] = make_float2(0.f, 0.f);
  __syncthreads();

  for (int i = t; i < NL1*NMP1*20; i += 256) {
    int n = i % 20; int r = i/20; int mp = r % NMP1; int l = r/NMP1;
    float2 v = make_float2(0.f, 0.f);
    if (n < NM1) {
      float2 xa = Xs[l*NMP1+mp], pp = Ps[l*NM1+n];
      v = make_float2(xa.x*pp.x - xa.y*pp.y, xa.x*pp.y + xa.y*pp.x);
    }
    XPp[i] = v;
  }
  __syncthreads();

  float2* Fh = bufA;
  float2* Tt = bufB;
  float*  yb = (float*)bufA;
  float2* Uu = bufB;

  for (int c = 0; c < NB1/NBC; ++c) {
    const int b0 = c*NBC;
    // ph1: Fh[bb][mp][n0..n0+3] = sum_l XPp * d1wc
    for (int i = t; i < NBC*NMP1*5; i += 256) {
      int q = i % 5; int r = i/5; int mp = r % NMP1; int bb = r/NMP1;
      int n0 = q*4;
      const float* dw = &d1wc[((b0+bb)*NMP1 + mp)*20 + n0];
      const float2* xp = &XPp[mp*20 + n0];
      float2 a0 = {0.f,0.f}, a1 = {0.f,0.f}, a2 = {0.f,0.f}, a3 = {0.f,0.f};
      #pragma unroll
      for (int l = 0; l < NL1; ++l) {
        float4 w4 = *(const float4*)&dw[l*4000];
        float4 xa = *(const float4*)&xp[l*(NMP1*20)];
        float4 xb = *(const float4*)&xp[l*(NMP1*20) + 2];
        a0.x = fmaf(w4.x, xa.x, a0.x); a0.y = fmaf(w4.x, xa.y, a0.y);
        a1.x = fmaf(w4.y, xa.z, a1.x); a1.y = fmaf(w4.y, xa.w, a1.y);
        a2.x = fmaf(w4.z, xb.x, a2.x); a2.y = fmaf(w4.z, xb.y, a2.y);
        a3.x = fmaf(w4.w, xb.z, a3.x); a3.y = fmaf(w4.w, xb.w, a3.y);
      }
      float2* fr = &Fh[(bb*NMP1 + mp)*NM1 + n0];
      fr[0] = a0; fr[1] = a1; fr[2] = a2;
      if (n0 + 3 < NM1) fr[3] = a3;
    }
    __syncthreads();
    // ph2 (radix-2 fold): compute Tt[g0..g0+1] and Tt[g0+10..g0+11]
    for (int i = t; i < NBC*NMP1*5; i += 256) {
      int q = i % 5; int r = i / 5; int mp = r % NMP1; int bb = r / NMP1;
      int g0 = q*2;
      const float2* fh = &Fh[(bb*NMP1 + mp)*NM1];
      float pe0x=0.f,pe0y=0.f,pe1x=0.f,pe1y=0.f;
      float po0x=0.f,po0y=0.f,po1x=0.f,po1y=0.f;
      #pragma unroll
      for (int n = 0; n < NM1; ++n) {
        float2 f = fh[n];
        float4 e = *(const float4*)&EsynTp[n*TTS + g0];
        float cr0 = f.x*e.x - f.y*e.y, ci0 = f.x*e.y + f.y*e.x;
        float cr1 = f.x*e.z - f.y*e.w, ci1 = f.x*e.w + f.y*e.z;
        if ((n & 1) == 0) { pe0x += cr0; pe0y += ci0; pe1x += cr1; pe1y += ci1; }
        else              { po0x += cr0; po0y += ci0; po1x += cr1; po1y += ci1; }
      }
      float2* tr = &Tt[(bb*NMP1 + mp)*TTS];
      *(float4*)&tr[g0]      = make_float4(pe0x+po0x, pe0y+po0y, pe1x+po1x, pe1y+po1y);
      *(float4*)&tr[g0+10]   = make_float4(po0x-pe0x, po0y-pe0y, po1x-pe1x, po1y-pe1y);
    }
    __syncthreads();
    // ph3 (radix-2 fold over a): y[a] and y[a+10]
    for (int i = t; i < NBC*10*5; i += 256) {
      int gq = i % 5; int r = i / 5; int a = r % 10; int bb = r / 10;
      int g0 = gq*4;
      float4 t01 = *(const float4*)&Tt[(bb*NMP1)*TTS + g0];
      float4 t23 = *(const float4*)&Tt[(bb*NMP1)*TTS + g0 + 2];
      float se0=0.f,se1=0.f,se2=0.f,se3=0.f, so0=0.f,so1=0.f,so2=0.f,so3=0.f;
      #pragma unroll
      for (int mp = 1; mp < NMP1; ++mp) {
        float4 u01 = *(const float4*)&Tt[(bb*NMP1 + mp)*TTS + g0];
        float4 u23 = *(const float4*)&Tt[(bb*NMP1 + mp)*TTS + g0 + 2];
        float2 e = EsynA[a*NMP1 + mp];
        float c0 = e.x*u01.x - e.y*u01.y;
        float c1 = e.x*u01.z - e.y*u01.w;
        float c2 = e.x*u23.x - e.y*u23.y;
        float c3 = e.x*u23.z - e.y*u23.w;
        if (mp & 1) { so0+=c0; so1+=c1; so2+=c2; so3+=c3; }
        else        { se0+=c0; se1+=c1; se2+=c2; se3+=c3; }
      }
      float* y0 = &yb[(bb*NB1 + a)*NB1 + g0];
      float* y1 = &yb[(bb*NB1 + a + 10)*NB1 + g0];
      y0[0]=fmaxf(fmaf(2.f, se0+so0, t01.x),0.f);
      y0[1]=fmaxf(fmaf(2.f, se1+so1, t01.z),0.f);
      y0[2]=fmaxf(fmaf(2.f, se2+so2, t23.x),0.f);
      y0[3]=fmaxf(fmaf(2.f, se3+so3, t23.z),0.f);
      y1[0]=fmaxf(fmaf(2.f, se0-so0, t01.x),0.f);
      y1[1]=fmaxf(fmaf(2.f, se1-so1, t01.z),0.f);
      y1[2]=fmaxf(fmaf(2.f, se2-so2, t23.x),0.f);
      y1[3]=fmaxf(fmaf(2.f, se3-so3, t23.z),0.f);
    }
    __syncthreads();
    // ph4 (radix-2 fold over a): U[bb][m2p][g] = sum_{a<10}(y[a] + sgn*y[a+10])*EanaA[a][m2p]
    for (int i = t; i < NBC*NMP2*5; i += 256) {
      int gq = i % 5; int r = i / 5; int m2p = r % NMP2; int bb = r / NMP2;
      int g0 = gq*4;
      const float sgn = (m2p & 1) ? -1.f : 1.f;
      float2 u0 = {0.f,0.f}, u1 = {0.f,0.f}, u2 = {0.f,0.f}, u3 = {0.f,0.f};
      #pragma unroll
      for (int aa = 0; aa < 10; ++aa) {
        float4 ya = *(const float4*)&yb[(bb*NB1 + aa)*NB1 + g0];
        float4 ybv = *(const float4*)&yb[(bb*NB1 + aa + 10)*NB1 + g0];
        float v0 = fmaf(sgn, ybv.x, ya.x);
        float v1 = fmaf(sgn, ybv.y, ya.y);
        float v2 = fmaf(sgn, ybv.z, ya.z);
        float v3 = fmaf(sgn, ybv.w, ya.w);
        float2 e = EanaA[aa*NMP2 + m2p];
        u0.x = fmaf(v0, e.x, u0.x); u0.y = fmaf(v0, e.y, u0.y);
        u1.x = fmaf(v1, e.x, u1.x); u1.y = fmaf(v1, e.y, u1.y);
        u2.x = fmaf(v2, e.x, u2.x); u2.y = fmaf(v2, e.y, u2.y);
        u3.x = fmaf(v3, e.x, u3.x); u3.y = fmaf(v3, e.y, u3.y);
      }
      float2* ur = &Uu[(bb*NMP2 + m2p)*TTS + g0];
      ur[0] = u0; ur[1] = u1; ur[2] = u2; ur[3] = u3;
    }
    __syncthreads();
    // ph5 (radix-2 fold over g): even n2i uses U[g]-U[g+10], odd uses U[g]+U[g+10]
    for (int i = t; i < NBC*NMP2*6; i += 256) {
      int p = i % 6; int r = i / 6; int m2p = r % NMP2; int bb = r / NMP2;
      int n0 = p*2;
      const float2* ur = &Uu[(bb*NMP2 + m2p)*TTS];
      float2 acc0 = {0.f,0.f}, acc1 = {0.f,0.f};
      #pragma unroll
      for (int g = 0; g < 10; ++g) {
        float2 ua = ur[g], ub = ur[g+10];
        float2 ud = make_float2(ua.x - ub.x, ua.y - ub.y);
        float2 us = make_float2(ua.x + ub.x, ua.y + ub.y);
        float4 e = *(const float4*)&EanaG[g*12 + n0];
        acc0.x += ud.x*e.x - ud.y*e.y; acc0.y += ud.x*e.y + ud.y*e.x;
        acc1.x += us.x*e.z - us.y*e.w; acc1.y += us.x*e.w + us.y*e.z;
      }
      yfs[(bb*NMP2 + m2p)*NM2 + n0] = acc0;
      if (n0 + 1 < NM2) yfs[(bb*NMP2 + m2p)*NM2 + n0 + 1] = acc1;
    }
    __syncthreads();
    // ph6: Fxa += sum_bb d12wc*yf
    for (int i = t; i < NL2*NMP2*NM2; i += 256) {
      int l2 = i/(NMP2*NM2); int r = i%(NMP2*NM2);
      float2 acc = Fxa[i];
      #pragma unroll
      for (int bb = 0; bb < NBC; ++bb) {
        float w = d12wc[(l2*NB1 + b0 + bb)*66 + r];
        float2 v = yfs[bb*(NMP2*NM2) + r];
        acc.x = fmaf(w, v.x, acc.x); acc.y = fmaf(w, v.y, acc.y);
      }
      Fxa[i] = acc;
    }
    __syncthreads();
  }
  for (int i = t; i < NL2*NMP2*NM2; i += 256) {
    int l2 = i/(NMP2*NM2); int r = i%(NMP2*NM2);
    int mp = r/NM2, n = r%NM2;
    Am[(size_t)l2*GEMM_MH*GEMM_K + (z*NMP2 + mp)*GEMM_K + o*NM2 + n] = Fxa[i];
  }
}

// ---------------- K5: per-l complex GEMM, split-K ----------------
__global__ __launch_bounds__(256) void k_so3mm(const float2* __restrict__ A,
                                               const float2* __restrict__ B,
                                               float2* __restrict__ C0,
                                               float2* __restrict__ C1) {
  __shared__ float2 As[GM*ASTR];
  __shared__ float2 Bs[GK*GN];
  const int lz = blockIdx.z;
  const int l = lz >> 1, half = lz & 1;
  const int kbeg = half ? 120 : 0, klim = half ? 220 : 120;
  const int row0 = blockIdx.x*GM, col0 = blockIdx.y*GN;
  const int t = threadIdx.x;
  const float2* Ag = A + (size_t)l*GEMM_MH*GEMM_K;
  const float2* Bg = B + (size_t)l*GEMM_K*GEMM_N;
  float2* Cg = (half ? C1 : C0) + (size_t)l*GEMM_MH*GEMM_N;
  const int tn = t & 15, tm = t >> 4;
  float2 acc[4][4];
  #pragma unroll
  for (int i = 0; i < 4; ++i)
    #pragma unroll
    for (int j = 0; j < 4; ++j) acc[i][j] = make_float2(0.f, 0.f);

  for (int k0 = kbeg; k0 < klim; k0 += GK) {
    for (int i = t; i < GM*GK; i += 256) {
      int r = i/GK, kk = i%GK;
      As[r*ASTR + kk] = Ag[(size_t)(row0 + r)*GEMM_K + k0 + kk];
    }
    for (int i = t; i < GK*GN; i += 256) {
      int kk = i/GN, cc = i%GN;
      int col = col0 + cc;
      float2 v = (col < GEMM_N) ? Bg[(size_t)(k0 + kk)*GEMM_N + col] : make_float2(0.f, 0.f);
      Bs[(kk*4 + (cc & 3))*16 + (cc >> 2)] = v;
    }
    __syncthreads();
    #pragma unroll
    for (int kk = 0; kk < GK; ++kk) {
      float2 a[4], b[4];
      #pragma unroll
      for (int i = 0; i < 4; ++i) a[i] = As[(tm*4 + i)*ASTR + kk];
      #pragma unroll
      for (int j = 0; j < 4; ++j) b[j] = Bs[(kk*4 + j)*16 + tn];
      #pragma unroll
      for (int i = 0; i < 4; ++i)
        #pragma unroll
        for (int j = 0; j < 4; ++j) {
          acc[i][j].x = fmaf(a[i].x, b[j].x, acc[i][j].x);
          acc[i][j].x = fmaf(-a[i].y, b[j].y, acc[i][j].x);
          acc[i][j].y = fmaf(a[i].x, b[j].y, acc[i][j].y);
          acc[i][j].y = fmaf(a[i].y, b[j].x, acc[i][j].y);
        }
    }
    __syncthreads();
  }
  #pragma unroll
  for (int i = 0; i < 4; ++i) {
    int r = row0 + tm*4 + i;
    int c0 = col0 + tn*4;
    if (c0 < GEMM_N) {
      float4 v0 = make_float4(acc[i][0].x, acc[i][0].y, acc[i][1].x, acc[i][1].y);
      float4 v1 = make_float4(acc[i][2].x, acc[i][2].y, acc[i][3].x, acc[i][3].y);
      *(float4*)&Cg[(size_t)r*GEMM_N + c0] = v0;
      *(float4*)&Cg[(size_t)r*GEMM_N + c0 + 2] = v1;
    }
  }
}

// ---------------- K6: fused stage 2 tail (radix-2 folded ph2/ph3) ----------------
__global__ __launch_bounds__(256) void k_stage2(const float2* __restrict__ C0,
                                                const float2* __restrict__ C1,
                                                const float* __restrict__ d2w,
                                                const float* __restrict__ w2n,
                                                const float2* __restrict__ Tg,
                                                float* __restrict__ feat) {
  __shared__ float2 Fos[NL2*NM2*NM2];
  __shared__ float2 Fh2[NB2*NM2*NM2];
  __shared__ float2 T2[NB2*NB2*NM2];
  __shared__ float2 Esyn2[NB2*NM2];
  __shared__ float w2s[NB2];
  __shared__ float wred[4];
  const int z = blockIdx.x, o = blockIdx.y, t = threadIdx.x;
  for (int i = t; i < NB2*NM2; i += 256) Esyn2[i] = Tg[TW_S2 + i];
  if (t < NB2) w2s[t] = w2n[t];
  for (int i = t; i < NL2*NM2*NM2; i += 256) {
    int l = i/(NM2*NM2); int mn = i%(NM2*NM2);
    int m = mn/NM2, n = mn%NM2;
    float2 v;
    if (m >= 5) {
      size_t idx = (size_t)l*GEMM_MH*GEMM_N + (size_t)(z*NMP2 + m - 5)*GEMM_N + o*NM2 + n;
      float2 a = C0[idx], b2 = C1[idx];
      v = make_float2(a.x + b2.x, a.y + b2.y);
    } else {
      size_t idx = (size_t)l*GEMM_MH*GEMM_N + (size_t)(z*NMP2 + 5 - m)*GEMM_N + o*NM2 + (10 - n);
      float2 a = C0[idx], b2 = C1[idx];
      float s = ((m - n) & 1) ? -1.f : 1.f;
      v = make_float2(s*(a.x + b2.x), -s*(a.y + b2.y));
    }
    Fos[i] = v;
  }
  __syncthreads();
  // ph1: Fh2[b][mn] = sum_l d2w*Fos  (no symmetry; unchanged)
  for (int i = t; i < NB2*NM2*NM2; i += 256) {
    int b = i/(NM2*NM2); int mn = i%(NM2*NM2);
    float re = 0.f, im = 0.f;
    #pragma unroll
    for (int l = 0; l < NL2; ++l) {
      float w = d2w[(l*NB2 + b)*(NM2*NM2) + mn];
      float2 v = Fos[l*(NM2*NM2) + mn];
      re = fmaf(w, v.x, re); im = fmaf(w, v.y, im);
    }
    Fh2[i] = make_float2(re, im);
  }
  __syncthreads();
  // ph2 (radix-2 fold over a): T2[b][a][ni] and T2[b][a+6][ni] from even/odd-mi partials
  for (int i = t; i < NB2*6*NM2; i += 256) {
    int ni = i % NM2; int r = i / NM2; int aa = r % 6; int b = r / 6;
    const float2* fh = &Fh2[b*(NM2*NM2) + ni];
    float ex = 0.f, ey = 0.f, ox = 0.f, oy = 0.f;
    #pragma unroll
    for (int mi = 0; mi < NM2; ++mi) {
      float2 f = fh[mi*NM2]; float2 e = Esyn2[aa*NM2+mi];
      float cr = e.x*f.x - e.y*f.y;
      float ci = e.x*f.y + e.y*f.x;
      if (mi & 1) { ox += cr; oy += ci; }
      else        { ex += cr; ey += ci; }
    }
    T2[(b*NB2 + aa)*NM2 + ni]     = make_float2(ex + ox, ey + oy);
    T2[(b*NB2 + aa + 6)*NM2 + ni] = make_float2(ox - ex, oy - ey);
  }
  __syncthreads();
  // ph3 (radix-2 fold over g): v(g)=Se+So, v(g+6)=So-Se
  float accT = 0.f;
  for (int i = t; i < NB2*NB2*6; i += 256) {
    int g = i % 6; int r = i / 6; int aa = r % NB2; int b = r / NB2;
    const float2* trow = &T2[(b*NB2 + aa)*NM2];
    float se = 0.f, so = 0.f;
    #pragma unroll
    for (int ni = 0; ni < NM2; ++ni) {
      float2 tv = trow[ni]; float2 e = Esyn2[g*NM2+ni];
      float cc = e.x*tv.x - e.y*tv.y;
      if (ni & 1) so += cc; else se += cc;
    }
    accT += w2s[b]*(fmaxf(se + so, 0.f) + fmaxf(so - se, 0.f));
  }
  #pragma unroll
  for (int off = 32; off > 0; off >>= 1) accT += __shfl_down(accT, off);
  if ((t & 63) == 0) wred[t >> 6] = accT;
  __syncthreads();
  if (t == 0) feat[z*F2C + o] = (wred[0]+wred[1]+wred[2]+wred[3]) / (float)(NB2*NB2);
}

// ---------------- K7: linear head ----------------
__global__ void k_head(const float* __restrict__ feat, const float* __restrict__ w_lin,
                       const float* __restrict__ b_lin, float* __restrict__ out) {
  int idx = blockIdx.x*blockDim.x + threadIdx.x;
  if (idx >= BATCH*10) return;
  int z = idx/10, f = idx%10;
  float acc = b_lin[f];
  for (int o = 0; o < F2C; ++o) acc = fmaf(feat[z*F2C + o], w_lin[f*F2C + o], acc);
  out[idx] = acc;
}

extern "C" void kernel_launch(void* const* d_in, const int* in_sizes, int n_in,
                              void* d_out, int out_size, void* d_ws, size_t ws_size,
                              hipStream_t stream) {
  const float* x     = (const float*)d_in[0];
  const float* psi1  = (const float*)d_in[1];
  const float* psi2  = (const float*)d_in[2];
  const float* w_lin = (const float*)d_in[3];
  const float* b_lin = (const float*)d_in[4];
  float* out = (float*)d_out;
  float* ws  = (float*)d_ws;

  size_t off = 0;
  auto alloc = [&](size_t nfloats) { size_t o = off; off += (nfloats + 15) & ~(size_t)15; return o; };
  float2* Tglob = (float2*)(ws + alloc(2*TW_TOT));
  float*  d1wc  = ws + alloc(N_D1WC);
  float*  d12wc = ws + alloc(N_D12WC);
  float*  wigY  = ws + alloc(N_WIGY);
  float*  wigD2 = ws + alloc(N_WIGD2);
  float*  d2w   = ws + alloc(N_D2W);
  float*  wd_s2c= ws + alloc(N_WDS2C);
  float*  w2n   = ws + alloc(N_W2N);
  float2* X     = (float2*)(ws + alloc(2*(size_t)NL1*BATCH*NMP1));
  float2* Psi1p = (float2*)(ws + alloc(2*(size_t)NL1*F1C*NM1));
  float2* Bmat  = (float2*)(ws + alloc(2*(size_t)NL2*GEMM_K*GEMM_N));
  float2* Amat  = (float2*)(ws + alloc(2*(size_t)NL2*GEMM_MH*GEMM_K));
  float2* Cmat0 = (float2*)(ws + alloc(2*(size_t)NL2*GEMM_MH*GEMM_N));
  float2* Cmat1 = (float2*)(ws + alloc(2*(size_t)NL2*GEMM_MH*GEMM_N));
  float*  featp = ws + alloc((size_t)BATCH*F2C);
  if (ws_size < off*sizeof(float)) return;

  k_consts1<<<(N_CSMALL + 255)/256, 256, 0, stream>>>(Tglob, wigY, wigD2, wd_s2c, w2n);
  k_prep<<<PREP_BASE + NBLK_CPREP, 256, 0, stream>>>(x, wd_s2c, Tglob, wigY, wigD2,
                                                     psi1, psi2, X, Psi1p, Bmat,
                                                     d1wc, d12wc, d2w);
  k_stage1<<<dim3(BATCH, F1C), 256, 0, stream>>>(X, Psi1p, d1wc, d12wc, Tglob, Amat);
  k_so3mm<<<dim3(GEMM_MH/GM, (GEMM_N + GN - 1)/GN, 2*NL2), 256, 0, stream>>>(Amat, Bmat, Cmat0, Cmat1);
  k_stage2<<<dim3(BATCH, F2C), 256, 0, stream>>>(Cmat0, Cmat1, d2w, w2n, Tglob, featp);
  k_head<<<(BATCH*10 + 255)/256, 256, 0, stream>>>(featp, w_lin, b_lin, out);
}

// Round 20
// 240.194 us; speedup vs baseline: 1.3200x; 1.0002x over previous
//
#include <hip/hip_runtime.h>
#include <math.h>

#define PI_D 3.14159265358979323846
#define PI_F 3.14159265358979f

#define BATCH 128
#define NM1 19
#define NMP1 10
#define NM2 11
#define NMP2 6
#define NB_IN 60
#define NB1 20
#define NB2 12
#define NL1 10
#define NL2 6
#define F1C 20
#define F2C 40
#define NBC 5

#define GEMM_MH (BATCH*NMP2)  // 768
#define GEMM_N (F2C*NM2)      // 440
#define GEMM_K (F1C*NM2)      // 220
#define GM 64
#define GN 64
#define GK 20
#define ASTR 21

// twiddle table global layout (float2 offsets)
#define TW_SYNT 0       // [19][20]
#define TW_SYNA 380     // [20][10]
#define TW_ANAA 580     // [20][6]
#define TW_ANAG 700     // [20][12] col11=0
#define TW_S2   940     // [12][11]
#define TW_60   1072    // [60][10]
#define TW_TOT  1672

#define TTS 22          // padded EsynT/Tt/Uu row stride (float2)

// constants counts
#define N_D1WC 40000    // [10l][20b][10mp][20]
#define N_D12WC 7920    // [6l][20b][6m2p][11]
#define N_WIGY 570      // [10l][3b][19m]
#define N_WIGD2 2178    // [6l][3b][121mn]
#define N_D2W  (NL2*NB2*NM2*NM2)   // 8712
#define N_WDS2C 6000    // [10l][60k][10mp]
#define N_W2N  (NB2)
#define N_CSMALL (N_WIGY+N_WIGD2+N_WDS2C+N_W2N)
#define N_CPREP (N_D1WC+N_D12WC+N_D2W)
#define PREP_BASE (BATCH + 1 + 120)
#define NBLK_CPREP ((N_CPREP + 255)/256)

// ---------------- fp32 Wigner-d helpers ----------------
__device__ __forceinline__ float ipow_f(float x, int e) {
  float r = 1.f;
  for (int i = 0; i < e; ++i) r *= x;
  return r;
}

__device__ float wigdf(const float* lf, int l, int m, int n, float beta) {
  if (m < -l || m > l || n < -l || n > l) return 0.f;
  float cb = cosf(0.5f*beta), sb = sinf(0.5f*beta);
  float pref = 0.5f*(lf[l+m]+lf[l-m]+lf[l+n]+lf[l-n]);
  int s0 = (n-m) > 0 ? (n-m) : 0;
  int s1 = (l+n) < (l-m) ? (l+n) : (l-m);
  float acc = 0.f;
  for (int s = s0; s <= s1; ++s) {
    float lc = pref - (lf[l+n-s]+lf[s]+lf[m-n+s]+lf[l-m-s]);
    float tt = expf(lc) * ipow_f(cb, 2*l+n-m-2*s) * ipow_f(sb, m-n+2*s);
    acc += ((m-n+s) & 1) ? -tt : tt;
  }
  return acc;
}

__device__ __forceinline__ float dh_beta_f(int b, int k) {
  return (float)(PI_D*(2*k+1)/(4.0*b));
}

__device__ float dh_w_f(int b, int k) {
  float beta = dh_beta_f(b, k), s = 0.f;
  for (int j = 0; j < b; ++j) s += sinf((2.f*(float)j+1.f)*beta)/(2.f*(float)j+1.f);
  return (2.f/(float)b)*sinf(beta)*s;
}

// ---------------- consts_small: twiddles + prep-prerequisite tables ----------------
__global__ __launch_bounds__(256) void k_consts1(float2* __restrict__ Tg,
                         float* __restrict__ wigY, float* __restrict__ wigD2,
                         float* __restrict__ wd_s2c, float* __restrict__ w2n) {
  __shared__ float lf[41];
  __shared__ float dhw30[60], dhw6[12];
  int t = threadIdx.x;
  if (t < 41) lf[t] = (float)lgamma((double)t + 1.0);
  else if (t < 101) dhw30[t-41] = dh_w_f(30, t-41);
  else if (t < 113) dhw6[t-101] = dh_w_f(6, t-101);
  __syncthreads();

  if (blockIdx.x == 0) {
    for (int i = t; i < TW_TOT; i += 256) {
      float2 v;
      if (i < TW_SYNA) {
        int j = i, n = j/NB1, g = j%NB1;
        int r = (g*(n-9)) % NB1; if (r < 0) r += NB1;
        float s, c; sincosf(2.f*PI_F*(float)r/(float)NB1, &s, &c);
        v = make_float2(c, s);
      } else if (i < TW_ANAA) {
        int j = i - TW_SYNA, a = j/NMP1, mp = j%NMP1;
        int r = (a*mp) % NB1;
        float s, c; sincosf(2.f*PI_F*(float)r/(float)NB1, &s, &c);
        v = make_float2(c, s);
      } else if (i < TW_ANAG) {
        int j = i - TW_ANAA, a = j/NMP2, m2p = j%NMP2;
        int r = (a*m2p) % NB1;
        float s, c; sincosf(2.f*PI_F*(float)r/(float)NB1, &s, &c);
        v = make_float2(c, -s);
      } else if (i < TW_S2) {
        int j = i - TW_ANAG, g = j/12, cI = j%12;
        if (cI == 11) v = make_float2(0.f, 0.f);
        else {
          int r = (g*(cI-5)) % NB1; if (r < 0) r += NB1;
          float s, c; sincosf(2.f*PI_F*(float)r/(float)NB1, &s, &c);
          v = make_float2(c, -s);
        }
      } else if (i < TW_60) {
        int j = i - TW_S2, k = j/NM2, mi = j%NM2;
        int r = (k*(mi-5)) % NB2; if (r < 0) r += NB2;
        float s, c; sincosf(2.f*PI_F*(float)r/(float)NB2, &s, &c);
        v = make_float2(c, s);
      } else {
        int j = i - TW_60, a = j/NMP1, mp = j%NMP1;
        int r = (a*mp) % NB_IN;
        float s, c; sincosf(2.f*PI_F*(float)r/(float)NB_IN, &s, &c);
        v = make_float2(c, -s);
      }
      Tg[i] = v;
    }
  }

  int gid = blockIdx.x*blockDim.x + t;

  if (gid < N_WIGY) {
    int l = gid/57; int r = gid%57; int bidx = r/19; int mi = r%19;
    float beta = (float)((double)(bidx + 1) * PI_D/24.0);
    wigY[gid] = wigdf(lf, l, mi-9, 0, beta);
    return;
  }
  gid -= N_WIGY;
  if (gid < N_WIGD2) {
    int l = gid/363; int r = gid%363; int bidx = r/121; int mn = r%121;
    int m = mn/NM2 - 5, n = mn%NM2 - 5;
    float beta = (float)((double)(bidx + 1) * PI_D/24.0);
    wigD2[gid] = wigdf(lf, l, m, n, beta);
    return;
  }
  gid -= N_WIGD2;
  if (gid < N_WDS2C) {
    int l = gid/600; int r = gid%600; int k = r/10; int mp = r%10;
    wd_s2c[gid] = dhw30[k] * wigdf(lf, l, mp, 0, dh_beta_f(30,k));
    return;
  }
  gid -= N_WDS2C;
  if (gid < N_W2N) {
    float s = 0.f;
    for (int j = 0; j < NB2; ++j) s += dhw6[j];
    w2n[gid] = dhw6[gid]/s;
    return;
  }
}

// ---------------- K_prep: s2fft (0..127) + psi1 (128) + psi2 (129..248) + heavy consts ----------------
#define P2IO 40
#define P2GC 24
__global__ __launch_bounds__(256) void k_prep(const float* __restrict__ x,
                                              const float* __restrict__ wd_s2c,
                                              const float2* __restrict__ Tg,
                                              const float* __restrict__ wigY,
                                              const float* __restrict__ wigD2,
                                              const float* __restrict__ psi1,
                                              const float* __restrict__ psi2,
                                              float2* __restrict__ X,
                                              float2* __restrict__ Psi1p,
                                              float2* __restrict__ Bm,
                                              float* __restrict__ d1wc,
                                              float* __restrict__ d12wc,
                                              float* __restrict__ d2w) {
  __shared__ __align__(16) float smem[6912];
  const int bid = blockIdx.x, t = threadIdx.x;

  if (bid < BATCH) {
    // ---- s2fft for z = bid (radix-2 folded over a; Legendre folded over k) ----
    const int z = bid;
    float*  xs   = smem;                       // 3600
    float2* xf   = (float2*)(smem + 3600);     // 600 f2
    float2* tw60 = (float2*)(smem + 4800);     // 600 f2 (only a<30 rows used)
    for (int i = t; i < NB_IN*NMP1; i += 256) tw60[i] = Tg[TW_60 + i];
    for (int i = t; i < 3600; i += 256) xs[i] = x[z*3600 + i];
    __syncthreads();
    for (int i = t; i < NB_IN*NMP1; i += 256) {
      int k = i/NMP1, mp = i%NMP1;
      float sgn = (mp & 1) ? -1.f : 1.f;
      float re = 0.f, im = 0.f;
      const float* xrow = &xs[k*NB_IN];
      for (int a = 0; a < 30; ++a) {
        float v = fmaf(sgn, xrow[a+30], xrow[a]);
        float2 e = tw60[a*NMP1 + mp];
        re = fmaf(v, e.x, re);
        im = fmaf(v, e.y, im);
      }
      xf[i] = make_float2(re, im);
    }
    __syncthreads();
    // Legendre fold: wd_s2c[l][59-k][mp] = (-1)^(l+mp) * wd_s2c[l][k][mp]; dhw symmetric
    for (int i = t; i < NL1*NMP1; i += 256) {
      int l = i/NMP1, mp = i%NMP1;
      float s = ((l + mp) & 1) ? -1.f : 1.f;
      float re = 0.f, im = 0.f;
      for (int k = 0; k < 30; ++k) {
        float w = wd_s2c[(l*NB_IN+k)*NMP1 + mp];
        float2 va = xf[k*NMP1 + mp];
        float2 vb = xf[(59-k)*NMP1 + mp];
        float vx = fmaf(s, vb.x, va.x);
        float vy = fmaf(s, vb.y, va.y);
        re = fmaf(w, vx, re); im = fmaf(w, vy, im);
      }
      X[(l*BATCH + z)*NMP1 + mp] = make_float2(re, im);
    }
    return;
  }

  if (bid == BATCH) {
    // ---- psi1 ----
    float*  wigYs = smem;                      // 570
    float*  psis  = smem + 576;                // 480
    float2* ph8   = (float2*)(smem + 1056);
    for (int i = t; i < N_WIGY; i += 256) wigYs[i] = wigY[i];
    for (int i = t; i < F1C*24; i += 256) psis[i] = psi1[i];
    if (t < 8) {
      float s, c; sincosf(2.f*PI_F*(float)t/8.f, &s, &c);
      ph8[t] = make_float2(c, s);
    }
    __syncthreads();
    for (int i = t; i < NL1*F1C*NM1; i += 256) {
      int l = i/(F1C*NM1); int r = i%(F1C*NM1); int o = r/NM1; int mi = r%NM1;
      int m = mi - 9;
      float re = 0.f, im = 0.f;
      for (int g = 0; g < 24; ++g) {
        float w = psis[o*24 + g];
        float d = wigYs[(l*3 + (g >> 3))*NM1 + mi];
        int pa = g & 7;
        int rr = (-(m*pa)) % 8; if (rr < 0) rr += 8;
        float2 ph = ph8[rr];
        re = fmaf(w, d*ph.x, re); im = fmaf(w, d*ph.y, im);
      }
      Psi1p[i] = make_float2(re, im);
    }
    return;
  }

  if (bid < PREP_BASE) {
    // ---- psi2 (120 blocks) ----
    const int j = bid - (BATCH + 1);
    const int io0 = (j/NL2)*P2IO, l = j%NL2;
    float2* Ds   = (float2*)smem;              // 2928 f2
    float*  Ws   = smem + 5856;                // 960 f
    float2* ph24 = (float2*)(smem + 6816);     // 24 f2
    const int tio = t/31, tmn = t%31;
    const int mn0 = tmn*4;
    if (t < 24) {
      float s, c; sincosf(2.f*PI_F*(float)t/24.f, &s, &c);
      ph24[t] = make_float2(c, s);
    }
    __syncthreads();
    float2 acc[5][4];
    #pragma unroll
    for (int i = 0; i < 5; ++i)
      #pragma unroll
      for (int jj = 0; jj < 4; ++jj) acc[i][jj] = make_float2(0.f, 0.f);

    for (int gc = 0; gc < 144; gc += P2GC) {
      for (int i = t; i < P2GC*121; i += 256) {
        int g = i/121, mn = i%121;
        int p = gc + g;
        int m = mn/NM2 - 5, n = mn%NM2 - 5;
        float d = wigD2[(l*3 + p/48)*121 + mn];
        int pa = (p/6)%8, pg = p%6;
        int rr24 = (-(3*m*pa + 4*n*pg)) % 24; if (rr24 < 0) rr24 += 24;
        float2 ph = ph24[rr24];
        Ds[g*122 + mn] = make_float2(d*ph.x, d*ph.y);
      }
      for (int i = t; i < P2IO*P2GC; i += 256) {
        int io = i/P2GC, g = i%P2GC;
        Ws[i] = psi2[(io0 + io)*144 + gc + g];
      }
      __syncthreads();
      if (tio < 8) {
        for (int g = 0; g < P2GC; ++g) {
          float4 d01 = *(const float4*)&Ds[g*122 + mn0];
          float4 d23 = *(const float4*)&Ds[g*122 + mn0 + 2];
          float w0 = Ws[(tio*5 + 0)*P2GC + g];
          float w1 = Ws[(tio*5 + 1)*P2GC + g];
          float w2 = Ws[(tio*5 + 2)*P2GC + g];
          float w3 = Ws[(tio*5 + 3)*P2GC + g];
          float w4 = Ws[(tio*5 + 4)*P2GC + g];
          float dx[4] = {d01.x, d01.z, d23.x, d23.z};
          float dy[4] = {d01.y, d01.w, d23.y, d23.w};
          float wv[5] = {w0, w1, w2, w3, w4};
          #pragma unroll
          for (int i = 0; i < 5; ++i)
            #pragma unroll
            for (int jj = 0; jj < 4; ++jj) {
              acc[i][jj].x = fmaf(wv[i], dx[jj], acc[i][jj].x);
              acc[i][jj].y = fmaf(wv[i], dy[jj], acc[i][jj].y);
            }
        }
      }
      __syncthreads();
    }
    if (tio < 8) {
      #pragma unroll
      for (int i = 0; i < 5; ++i) {
        int io = io0 + tio*5 + i;
        int ii = io/F2C, oo = io%F2C;
        #pragma unroll
        for (int jj = 0; jj < 4; ++jj) {
          int mn = mn0 + jj;
          if (mn < 121) {
            int k = mn/NM2, n = mn%NM2;
            Bm[(size_t)l*GEMM_K*GEMM_N + (ii*NM2 + k)*GEMM_N + oo*NM2 + n] = acc[i][jj];
          }
        }
      }
    }
    return;
  }

  // ---- heavy consts branch (222 blocks): d1wc, d12wc, d2w ----
  {
    float* lf     = smem;        // 41
    float* dhw10l = smem + 48;   // 20
    if (t < 41) lf[t] = (float)lgamma((double)t + 1.0);
    else if (t >= 64 && t < 84) dhw10l[t-64] = dh_w_f(10, t-64);
    __syncthreads();
    int idx = (bid - PREP_BASE)*256 + t;
    if (idx < N_D1WC) {
      int l = idx/4000; int r = idx%4000; int b = r/200; int r2 = r%200;
      int mp = r2/20, nn = r2%20;
      d1wc[idx] = (nn < NM1) ? (float)(2*l+1) * wigdf(lf, l, mp, nn-9, dh_beta_f(10,b)) : 0.f;
      return;
    }
    idx -= N_D1WC;
    if (idx < N_D12WC) {
      int l2 = idx/1320; int r = idx%1320; int b = r/66; int r2 = r%66;
      int m2p = r2/11, n2i = r2%11;
      d12wc[idx] = dhw10l[b] * wigdf(lf, l2, m2p, n2i-5, dh_beta_f(10,b));
      return;
    }
    idx -= N_D12WC;
    if (idx < N_D2W) {
      int l = idx/(NB2*NM2*NM2); int r = idx%(NB2*NM2*NM2); int j = r/(NM2*NM2); int rr = r%(NM2*NM2);
      int m = rr/NM2 - 5, n = rr%NM2 - 5;
      d2w[idx] = (float)(2*l+1) * wigdf(lf, l, m, n, dh_beta_f(6,j));
      return;
    }
  }
}

// ---------------- K4: fused stage 1 (radix-2 folded ph2/ph3/ph4/ph5) ----------------
__global__ __launch_bounds__(256) void k_stage1(const float2* __restrict__ X,
                                                const float2* __restrict__ Psi1,
                                                const float* __restrict__ d1wc,
                                                const float* __restrict__ d12wc,
                                                const float2* __restrict__ Tg,
                                                float2* __restrict__ Am) {
  __shared__ float2 Xs[NL1*NMP1];
  __shared__ float2 Ps[NL1*NM1];
  __shared__ __align__(16) float2 XPp[NL1*NMP1*20];
  __shared__ __align__(16) float2 Etab[978];
  __shared__ __align__(16) float2 bufA[NBC*200];
  __shared__ __align__(16) float2 bufB[NBC*220];
  __shared__ float2 yfs[NBC*NMP2*NM2];
  __shared__ float2 Fxa[NL2*NMP2*NM2];

  const int z = blockIdx.x, o = blockIdx.y, t = threadIdx.x;
  const float2* EsynTp = Etab;
  const float2* EsynA  = Etab + 418;
  const float2* EanaA  = Etab + 618;
  const float2* EanaG  = Etab + 738;

  for (int i = t; i < 978; i += 256) {
    float2 v;
    if (i < 418) {
      int n = i/TTS, g = i%TTS;
      v = (g < NB1) ? Tg[TW_SYNT + n*NB1 + g] : make_float2(0.f, 0.f);
    } else {
      v = Tg[TW_SYNA + (i - 418)];
    }
    Etab[i] = v;
  }
  for (int i = t; i < NL1*NMP1; i += 256) {
    int l = i/NMP1, mp = i%NMP1;
    Xs[i] = X[(l*BATCH + z)*NMP1 + mp];
  }
  for (int i = t; i < NL1*NM1; i += 256) {
    int l = i/NM1, mi = i%NM1;
    Ps[i] = Psi1[(l*F1C + o)*NM1 + mi];
  }
  for (int i = t; i < NL2*NMP2*NM2; i += 256) Fxa[i] = make_float2(0.f, 0.f);
  __syncthreads();

  for (int i = t; i < NL1*NMP1*20; i += 256) {
    int n = i % 20; int r = i/20; int mp = r % NMP1; int l = r/NMP1;
    float2 v = make_float2(0.f, 0.f);
    if (n < NM1) {
      float2 xa = Xs[l*NMP1+mp], pp = Ps[l*NM1+n];
      v = make_float2(xa.x*pp.x - xa.y*pp.y, xa.x*pp.y + xa.y*pp.x);
    }
    XPp[i] = v;
  }
  __syncthreads();

  float2* Fh = bufA;
  float2* Tt = bufB;
  float*  yb = (float*)bufA;
  float2* Uu = bufB;

  for (int c = 0; c < NB1/NBC; ++c) {
    const int b0 = c*NBC;
    // ph1: Fh[bb][mp][n0..n0+3] = sum_l XPp * d1wc
    for (int i = t; i < NBC*NMP1*5; i += 256) {
      int q = i % 5; int r = i/5; int mp = r % NMP1; int bb = r/NMP1;
      int n0 = q*4;
      const float* dw = &d1wc[((b0+bb)*NMP1 + mp)*20 + n0];
      const float2* xp = &XPp[mp*20 + n0];
      float2 a0 = {0.f,0.f}, a1 = {0.f,0.f}, a2 = {0.f,0.f}, a3 = {0.f,0.f};
      #pragma unroll
      for (int l = 0; l < NL1; ++l) {
        float4 w4 = *(const float4*)&dw[l*4000];
        float4 xa = *(const float4*)&xp[l*(NMP1*20)];
        float4 xb = *(const float4*)&xp[l*(NMP1*20) + 2];
        a0.x = fmaf(w4.x, xa.x, a0.x); a0.y = fmaf(w4.x, xa.y, a0.y);
        a1.x = fmaf(w4.y, xa.z, a1.x); a1.y = fmaf(w4.y, xa.w, a1.y);
        a2.x = fmaf(w4.z, xb.x, a2.x); a2.y = fmaf(w4.z, xb.y, a2.y);
        a3.x = fmaf(w4.w, xb.z, a3.x); a3.y = fmaf(w4.w, xb.w, a3.y);
      }
      float2* fr = &Fh[(bb*NMP1 + mp)*NM1 + n0];
      fr[0] = a0; fr[1] = a1; fr[2] = a2;
      if (n0 + 3 < NM1) fr[3] = a3;
    }
    __syncthreads();
    // ph2 (radix-2 fold): compute Tt[g0..g0+1] and Tt[g0+10..g0+11]
    for (int i = t; i < NBC*NMP1*5; i += 256) {
      int q = i % 5; int r = i / 5; int mp = r % NMP1; int bb = r / NMP1;
      int g0 = q*2;
      const float2* fh = &Fh[(bb*NMP1 + mp)*NM1];
      float pe0x=0.f,pe0y=0.f,pe1x=0.f,pe1y=0.f;
      float po0x=0.f,po0y=0.f,po1x=0.f,po1y=0.f;
      #pragma unroll
      for (int n = 0; n < NM1; ++n) {
        float2 f = fh[n];
        float4 e = *(const float4*)&EsynTp[n*TTS + g0];
        float cr0 = f.x*e.x - f.y*e.y, ci0 = f.x*e.y + f.y*e.x;
        float cr1 = f.x*e.z - f.y*e.w, ci1 = f.x*e.w + f.y*e.z;
        if ((n & 1) == 0) { pe0x += cr0; pe0y += ci0; pe1x += cr1; pe1y += ci1; }
        else              { po0x += cr0; po0y += ci0; po1x += cr1; po1y += ci1; }
      }
      float2* tr = &Tt[(bb*NMP1 + mp)*TTS];
      *(float4*)&tr[g0]      = make_float4(pe0x+po0x, pe0y+po0y, pe1x+po1x, pe1y+po1y);
      *(float4*)&tr[g0+10]   = make_float4(po0x-pe0x, po0y-pe0y, po1x-pe1x, po1y-pe1y);
    }
    __syncthreads();
    // ph3 (radix-2 fold over a): y[a] and y[a+10]
    for (int i = t; i < NBC*10*5; i += 256) {
      int gq = i % 5; int r = i / 5; int a = r % 10; int bb = r / 10;
      int g0 = gq*4;
      float4 t01 = *(const float4*)&Tt[(bb*NMP1)*TTS + g0];
      float4 t23 = *(const float4*)&Tt[(bb*NMP1)*TTS + g0 + 2];
      float se0=0.f,se1=0.f,se2=0.f,se3=0.f, so0=0.f,so1=0.f,so2=0.f,so3=0.f;
      #pragma unroll
      for (int mp = 1; mp < NMP1; ++mp) {
        float4 u01 = *(const float4*)&Tt[(bb*NMP1 + mp)*TTS + g0];
        float4 u23 = *(const float4*)&Tt[(bb*NMP1 + mp)*TTS + g0 + 2];
        float2 e = EsynA[a*NMP1 + mp];
        float c0 = e.x*u01.x - e.y*u01.y;
        float c1 = e.x*u01.z - e.y*u01.w;
        float c2 = e.x*u23.x - e.y*u23.y;
        float c3 = e.x*u23.z - e.y*u23.w;
        if (mp & 1) { so0+=c0; so1+=c1; so2+=c2; so3+=c3; }
        else        { se0+=c0; se1+=c1; se2+=c2; se3+=c3; }
      }
      float* y0 = &yb[(bb*NB1 + a)*NB1 + g0];
      float* y1 = &yb[(bb*NB1 + a + 10)*NB1 + g0];
      y0[0]=fmaxf(fmaf(2.f, se0+so0, t01.x),0.f);
      y0[1]=fmaxf(fmaf(2.f, se1+so1, t01.z),0.f);
      y0[2]=fmaxf(fmaf(2.f, se2+so2, t23.x),0.f);
      y0[3]=fmaxf(fmaf(2.f, se3+so3, t23.z),0.f);
      y1[0]=fmaxf(fmaf(2.f, se0-so0, t01.x),0.f);
      y1[1]=fmaxf(fmaf(2.f, se1-so1, t01.z),0.f);
      y1[2]=fmaxf(fmaf(2.f, se2-so2, t23.x),0.f);
      y1[3]=fmaxf(fmaf(2.f, se3-so3, t23.z),0.f);
    }
    __syncthreads();
    // ph4 (radix-2 fold over a): U[bb][m2p][g] = sum_{a<10}(y[a] + sgn*y[a+10])*EanaA[a][m2p]
    for (int i = t; i < NBC*NMP2*5; i += 256) {
      int gq = i % 5; int r = i / 5; int m2p = r % NMP2; int bb = r / NMP2;
      int g0 = gq*4;
      const float sgn = (m2p & 1) ? -1.f : 1.f;
      float2 u0 = {0.f,0.f}, u1 = {0.f,0.f}, u2 = {0.f,0.f}, u3 = {0.f,0.f};
      #pragma unroll
      for (int aa = 0; aa < 10; ++aa) {
        float4 ya = *(const float4*)&yb[(bb*NB1 + aa)*NB1 + g0];
        float4 ybv = *(const float4*)&yb[(bb*NB1 + aa + 10)*NB1 + g0];
        float v0 = fmaf(sgn, ybv.x, ya.x);
        float v1 = fmaf(sgn, ybv.y, ya.y);
        float v2 = fmaf(sgn, ybv.z, ya.z);
        float v3 = fmaf(sgn, ybv.w, ya.w);
        float2 e = EanaA[aa*NMP2 + m2p];
        u0.x = fmaf(v0, e.x, u0.x); u0.y = fmaf(v0, e.y, u0.y);
        u1.x = fmaf(v1, e.x, u1.x); u1.y = fmaf(v1, e.y, u1.y);
        u2.x = fmaf(v2, e.x, u2.x); u2.y = fmaf(v2, e.y, u2.y);
        u3.x = fmaf(v3, e.x, u3.x); u3.y = fmaf(v3, e.y, u3.y);
      }
      float2* ur = &Uu[(bb*NMP2 + m2p)*TTS + g0];
      ur[0] = u0; ur[1] = u1; ur[2] = u2; ur[3] = u3;
    }
    __syncthreads();
    // ph5 (radix-2 fold over g): even n2i uses U[g]-U[g+10], odd uses U[g]+U[g+10]
    for (int i = t; i < NBC*NMP2*6; i += 256) {
      int p = i % 6; int r = i / 6; int m2p = r % NMP2; int bb = r / NMP2;
      int n0 = p*2;
      const float2* ur = &Uu[(bb*NMP2 + m2p)*TTS];
      float2 acc0 = {0.f,0.f}, acc1 = {0.f,0.f};
      #pragma unroll
      for (int g = 0; g < 10; ++g) {
        float2 ua = ur[g], ub = ur[g+10];
        float2 ud = make_float2(ua.x - ub.x, ua.y - ub.y);
        float2 us = make_float2(ua.x + ub.x, ua.y + ub.y);
        float4 e = *(const float4*)&EanaG[g*12 + n0];
        acc0.x += ud.x*e.x - ud.y*e.y; acc0.y += ud.x*e.y + ud.y*e.x;
        acc1.x += us.x*e.z - us.y*e.w; acc1.y += us.x*e.w + us.y*e.z;
      }
      yfs[(bb*NMP2 + m2p)*NM2 + n0] = acc0;
      if (n0 + 1 < NM2) yfs[(bb*NMP2 + m2p)*NM2 + n0 + 1] = acc1;
    }
    __syncthreads();
    // ph6: Fxa += sum_bb d12wc*yf
    for (int i = t; i < NL2*NMP2*NM2; i += 256) {
      int l2 = i/(NMP2*NM2); int r = i%(NMP2*NM2);
      float2 acc = Fxa[i];
      #pragma unroll
      for (int bb = 0; bb < NBC; ++bb) {
        float w = d12wc[(l2*NB1 + b0 + bb)*66 + r];
        float2 v = yfs[bb*(NMP2*NM2) + r];
        acc.x = fmaf(w, v.x, acc.x); acc.y = fmaf(w, v.y, acc.y);
      }
      Fxa[i] = acc;
    }
    __syncthreads();
  }
  for (int i = t; i < NL2*NMP2*NM2; i += 256) {
    int l2 = i/(NMP2*NM2); int r = i%(NMP2*NM2);
    int mp = r/NM2, n = r%NM2;
    Am[(size_t)l2*GEMM_MH*GEMM_K + (z*NMP2 + mp)*GEMM_K + o*NM2 + n] = Fxa[i];
  }
}

// ---------------- K5: per-l complex GEMM, split-K ----------------
__global__ __launch_bounds__(256) void k_so3mm(const float2* __restrict__ A,
                                               const float2* __restrict__ B,
                                               float2* __restrict__ C0,
                                               float2* __restrict__ C1) {
  __shared__ float2 As[GM*ASTR];
  __shared__ float2 Bs[GK*GN];
  const int lz = blockIdx.z;
  const int l = lz >> 1, half = lz & 1;
  const int kbeg = half ? 120 : 0, klim = half ? 220 : 120;
  const int row0 = blockIdx.x*GM, col0 = blockIdx.y*GN;
  const int t = threadIdx.x;
  const float2* Ag = A + (size_t)l*GEMM_MH*GEMM_K;
  const float2* Bg = B + (size_t)l*GEMM_K*GEMM_N;
  float2* Cg = (half ? C1 : C0) + (size_t)l*GEMM_MH*GEMM_N;
  const int tn = t & 15, tm = t >> 4;
  float2 acc[4][4];
  #pragma unroll
  for (int i = 0; i < 4; ++i)
    #pragma unroll
    for (int j = 0; j < 4; ++j) acc[i][j] = make_float2(0.f, 0.f);

  for (int k0 = kbeg; k0 < klim; k0 += GK) {
    for (int i = t; i < GM*GK; i += 256) {
      int r = i/GK, kk = i%GK;
      As[r*ASTR + kk] = Ag[(size_t)(row0 + r)*GEMM_K + k0 + kk];
    }
    for (int i = t; i < GK*GN; i += 256) {
      int kk = i/GN, cc = i%GN;
      int col = col0 + cc;
      float2 v = (col < GEMM_N) ? Bg[(size_t)(k0 + kk)*GEMM_N + col] : make_float2(0.f, 0.f);
      Bs[(kk*4 + (cc & 3))*16 + (cc >> 2)] = v;
    }
    __syncthreads();
    #pragma unroll
    for (int kk = 0; kk < GK; ++kk) {
      float2 a[4], b[4];
      #pragma unroll
      for (int i = 0; i < 4; ++i) a[i] = As[(tm*4 + i)*ASTR + kk];
      #pragma unroll
      for (int j = 0; j < 4; ++j) b[j] = Bs[(kk*4 + j)*16 + tn];
      #pragma unroll
      for (int i = 0; i < 4; ++i)
        #pragma unroll
        for (int j = 0; j < 4; ++j) {
          acc[i][j].x = fmaf(a[i].x, b[j].x, acc[i][j].x);
          acc[i][j].x = fmaf(-a[i].y, b[j].y, acc[i][j].x);
          acc[i][j].y = fmaf(a[i].x, b[j].y, acc[i][j].y);
          acc[i][j].y = fmaf(a[i].y, b[j].x, acc[i][j].y);
        }
    }
    __syncthreads();
  }
  #pragma unroll
  for (int i = 0; i < 4; ++i) {
    int r = row0 + tm*4 + i;
    int c0 = col0 + tn*4;
    if (c0 < GEMM_N) {
      float4 v0 = make_float4(acc[i][0].x, acc[i][0].y, acc[i][1].x, acc[i][1].y);
      float4 v1 = make_float4(acc[i][2].x, acc[i][2].y, acc[i][3].x, acc[i][3].y);
      *(float4*)&Cg[(size_t)r*GEMM_N + c0] = v0;
      *(float4*)&Cg[(size_t)r*GEMM_N + c0 + 2] = v1;
    }
  }
}

// ---------------- K6: fused stage 2 tail (radix-2 folded ph2/ph3) ----------------
__global__ __launch_bounds__(256) void k_stage2(const float2* __restrict__ C0,
                                                const float2* __restrict__ C1,
                                                const float* __restrict__ d2w,
                                                const float* __restrict__ w2n,
                                                const float2* __restrict__ Tg,
                                                float* __restrict__ feat) {
  __shared__ float2 Fos[NL2*NM2*NM2];
  __shared__ float2 Fh2[NB2*NM2*NM2];
  __shared__ float2 T2[NB2*NB2*NM2];
  __shared__ float2 Esyn2[NB2*NM2];
  __shared__ float w2s[NB2];
  __shared__ float wred[4];
  const int z = blockIdx.x, o = blockIdx.y, t = threadIdx.x;
  for (int i = t; i < NB2*NM2; i += 256) Esyn2[i] = Tg[TW_S2 + i];
  if (t < NB2) w2s[t] = w2n[t];
  for (int i = t; i < NL2*NM2*NM2; i += 256) {
    int l = i/(NM2*NM2); int mn = i%(NM2*NM2);
    int m = mn/NM2, n = mn%NM2;
    float2 v;
    if (m >= 5) {
      size_t idx = (size_t)l*GEMM_MH*GEMM_N + (size_t)(z*NMP2 + m - 5)*GEMM_N + o*NM2 + n;
      float2 a = C0[idx], b2 = C1[idx];
      v = make_float2(a.x + b2.x, a.y + b2.y);
    } else {
      size_t idx = (size_t)l*GEMM_MH*GEMM_N + (size_t)(z*NMP2 + 5 - m)*GEMM_N + o*NM2 + (10 - n);
      float2 a = C0[idx], b2 = C1[idx];
      float s = ((m - n) & 1) ? -1.f : 1.f;
      v = make_float2(s*(a.x + b2.x), -s*(a.y + b2.y));
    }
    Fos[i] = v;
  }
  __syncthreads();
  for (int i = t; i < NB2*NM2*NM2; i += 256) {
    int b = i/(NM2*NM2); int mn = i%(NM2*NM2);
    float re = 0.f, im = 0.f;
    #pragma unroll
    for (int l = 0; l < NL2; ++l) {
      float w = d2w[(l*NB2 + b)*(NM2*NM2) + mn];
      float2 v = Fos[l*(NM2*NM2) + mn];
      re = fmaf(w, v.x, re); im = fmaf(w, v.y, im);
    }
    Fh2[i] = make_float2(re, im);
  }
  __syncthreads();
  for (int i = t; i < NB2*6*NM2; i += 256) {
    int ni = i % NM2; int r = i / NM2; int aa = r % 6; int b = r / 6;
    const float2* fh = &Fh2[b*(NM2*NM2) + ni];
    float ex = 0.f, ey = 0.f, ox = 0.f, oy = 0.f;
    #pragma unroll
    for (int mi = 0; mi < NM2; ++mi) {
      float2 f = fh[mi*NM2]; float2 e = Esyn2[aa*NM2+mi];
      float cr = e.x*f.x - e.y*f.y;
      float ci = e.x*f.y + e.y*f.x;
      if (mi & 1) { ox += cr; oy += ci; }
      else        { ex += cr; ey += ci; }
    }
    T2[(b*NB2 + aa)*NM2 + ni]     = make_float2(ex + ox, ey + oy);
    T2[(b*NB2 + aa + 6)*NM2 + ni] = make_float2(ox - ex, oy - ey);
  }
  __syncthreads();
  float accT = 0.f;
  for (int i = t; i < NB2*NB2*6; i += 256) {
    int g = i % 6; int r = i / 6; int aa = r % NB2; int b = r / NB2;
    const float2* trow = &T2[(b*NB2 + aa)*NM2];
    float se = 0.f, so = 0.f;
    #pragma unroll
    for (int ni = 0; ni < NM2; ++ni) {
      float2 tv = trow[ni]; float2 e = Esyn2[g*NM2+ni];
      float cc = e.x*tv.x - e.y*tv.y;
      if (ni & 1) so += cc; else se += cc;
    }
    accT += w2s[b]*(fmaxf(se + so, 0.f) + fmaxf(so - se, 0.f));
  }
  #pragma unroll
  for (int off = 32; off > 0; off >>= 1) accT += __shfl_down(accT, off);
  if ((t & 63) == 0) wred[t >> 6] = accT;
  __syncthreads();
  if (t == 0) feat[z*F2C + o] = (wred[0]+wred[1]+wred[2]+wred[3]) / (float)(NB2*NB2);
}

// ---------------- K7: linear head ----------------
__global__ void k_head(const float* __restrict__ feat, const float* __restrict__ w_lin,
                       const float* __restrict__ b_lin, float* __restrict__ out) {
  int idx = blockIdx.x*blockDim.x + threadIdx.x;
  if (idx >= BATCH*10) return;
  int z = idx/10, f = idx%10;
  float acc = b_lin[f];
  for (int o = 0; o < F2C; ++o) acc = fmaf(feat[z*F2C + o], w_lin[f*F2C + o], acc);
  out[idx] = acc;
}

extern "C" void kernel_launch(void* const* d_in, const int* in_sizes, int n_in,
                              void* d_out, int out_size, void* d_ws, size_t ws_size,
                              hipStream_t stream) {
  const float* x     = (const float*)d_in[0];
  const float* psi1  = (const float*)d_in[1];
  const float* psi2  = (const float*)d_in[2];
  const float* w_lin = (const float*)d_in[3];
  const float* b_lin = (const float*)d_in[4];
  float* out = (float*)d_out;
  float* ws  = (float*)d_ws;

  size_t off = 0;
  auto alloc = [&](size_t nfloats) { size_t o = off; off += (nfloats + 15) & ~(size_t)15; return o; };
  float2* Tglob = (float2*)(ws + alloc(2*TW_TOT));
  float*  d1wc  = ws + alloc(N_D1WC);
  float*  d12wc = ws + alloc(N_D12WC);
  float*  wigY  = ws + alloc(N_WIGY);
  float*  wigD2 = ws + alloc(N_WIGD2);
  float*  d2w   = ws + alloc(N_D2W);
  float*  wd_s2c= ws + alloc(N_WDS2C);
  float*  w2n   = ws + alloc(N_W2N);
  float2* X     = (float2*)(ws + alloc(2*(size_t)NL1*BATCH*NMP1));
  float2* Psi1p = (float2*)(ws + alloc(2*(size_t)NL1*F1C*NM1));
  float2* Bmat  = (float2*)(ws + alloc(2*(size_t)NL2*GEMM_K*GEMM_N));
  float2* Amat  = (float2*)(ws + alloc(2*(size_t)NL2*GEMM_MH*GEMM_K));
  float2* Cmat0 = (float2*)(ws + alloc(2*(size_t)NL2*GEMM_MH*GEMM_N));
  float2* Cmat1 = (float2*)(ws + alloc(2*(size_t)NL2*GEMM_MH*GEMM_N));
  float*  featp = ws + alloc((size_t)BATCH*F2C);
  if (ws_size < off*sizeof(float)) return;

  k_consts1<<<(N_CSMALL + 255)/256, 256, 0, stream>>>(Tglob, wigY, wigD2, wd_s2c, w2n);
  k_prep<<<PREP_BASE + NBLK_CPREP, 256, 0, stream>>>(x, wd_s2c, Tglob, wigY, wigD2,
                                                     psi1, psi2, X, Psi1p, Bmat,
                                                     d1wc, d12wc, d2w);
  k_stage1<<<dim3(BATCH, F1C), 256, 0, stream>>>(X, Psi1p, d1wc, d12wc, Tglob, Amat);
  k_so3mm<<<dim3(GEMM_MH/GM, (GEMM_N + GN - 1)/GN, 2*NL2), 256, 0, stream>>>(Amat, Bmat, Cmat0, Cmat1);
  k_stage2<<<dim3(BATCH, F2C), 256, 0, stream>>>(Cmat0, Cmat1, d2w, w2n, Tglob, featp);
  k_head<<<(BATCH*10 + 255)/256, 256, 0, stream>>>(featp, w_lin, b_lin, out);
}